// Round 1
// baseline (2516.397 us; speedup 1.0000x reference)
//
#include <hip/hip_runtime.h>
#include <hip/hip_bf16.h>
#include <float.h>

#define B_ 2
#define N_ 8192
#define C_ 128
#define K_ 16
#define G_ 8
#define CPG 16
#define NK_ (N_*K_)
#define BN_ (B_*N_)
#define BNK_ (B_*NK_)
#define CN_ (C_*N_)
#define NEG 0.1f
#define EPSV 1e-5f

__device__ __forceinline__ float leakyf(float x){ return x >= 0.f ? x : NEG*x; }

// ---------------- pack xyz -> float4 ----------------
__global__ __launch_bounds__(256) void pack_kernel(const float* __restrict__ xyz, float4* __restrict__ pt4){
  int e = blockIdx.x*256 + threadIdx.x;
  int b = e >> 13, n = e & (N_-1);
  const float* xb = xyz + b*3*N_;
  pt4[e] = make_float4(xb[n], xb[N_+n], xb[2*N_+n], 0.f);
}

// ---------------- transpose W_att1 ----------------
__global__ __launch_bounds__(256) void transpose_kernel(const float* __restrict__ W, float* __restrict__ WT){
  for (int i = threadIdx.x; i < C_*C_; i += 256){
    int r = i >> 7, c = i & (C_-1);
    WT[c*C_ + r] = W[i];
  }
}

// ---------------- KNN: wave per query, fp64 distances ----------------
#define KNN_TPB 512
#define KNN_CHUNK 2048
__global__ __launch_bounds__(KNN_TPB) void knn_kernel(const float4* __restrict__ pt4, int* __restrict__ idxo){
  __shared__ float4 sp[KNN_CHUNK];
  int lane = threadIdx.x & 63, wid = threadIdx.x >> 6;
  int qg = blockIdx.x*(KNN_TPB/64) + wid;
  int b = qg >> 13, n = qg & (N_-1);
  const float4* pts = pt4 + b*N_;
  float4 qp = pts[n];
  double qx = qp.x, qy = qp.y, qz = qp.z;
  double qsq = qx*qx + qy*qy + qz*qz;
  double myd = DBL_MAX; int myi = 0x7fffffff;     // lanes 0..15 hold sorted top-16
  double thr = DBL_MAX; int thri = 0x7fffffff;
  for (int c0 = 0; c0 < N_; c0 += KNN_CHUNK){
    __syncthreads();
    #pragma unroll
    for (int t = 0; t < KNN_CHUNK/KNN_TPB; t++){
      int i = t*KNN_TPB + threadIdx.x;
      sp[i] = pts[c0 + i];
    }
    __syncthreads();
    for (int j0 = 0; j0 < KNN_CHUNK; j0 += 64){
      float4 pp = sp[j0 + lane];
      double px = pp.x, py = pp.y, pz = pp.z;
      double psq = px*px + py*py + pz*pz;
      double dot = qx*px + qy*py + qz*pz;
      double d2 = qsq + psq - 2.0*dot;
      int jj = c0 + j0 + lane;
      bool cand = (d2 < thr) || (d2 == thr && jj < thri);
      unsigned long long m = __ballot(cand);
      while (m){
        int src = __ffsll((unsigned long long)m) - 1;
        m &= m - 1;
        double dn = __shfl(d2, src, 64);
        int in_ = c0 + j0 + src;
        if ((dn < thr) || (dn == thr && in_ < thri)){
          bool less = (dn < myd) || (dn == myd && in_ < myi);
          unsigned long long bm = __ballot(less) & 0xFFFFull;
          int pos = __ffsll((unsigned long long)bm) - 1;
          double pd = __shfl_up(myd, 1, 64);
          int pi = __shfl_up(myi, 1, 64);
          if (lane < 16){
            if (lane > pos){ myd = pd; myi = pi; }
            else if (lane == pos){ myd = dn; myi = in_; }
          }
          thr = __shfl(myd, 15, 64);
          thri = __shfl(myi, 15, 64);
        }
      }
    }
  }
  if (lane < 16) idxo[qg*K_ + lane] = myi;
}

// ---------------- conv1: new_feat = W_pre @ feat + b ----------------
__global__ __launch_bounds__(256) void conv_pre_kernel(const float* __restrict__ feat,
    const float* __restrict__ W, const float* __restrict__ bias, float* __restrict__ nf){
  int p = blockIdx.x*256 + threadIdx.x;
  int b = p >> 13, n = p & (N_-1);
  const float* xin = feat + b*CN_ + n;
  float x[C_];
  #pragma unroll
  for (int c = 0; c < C_; c++) x[c] = xin[c*N_];
  float* op = nf + b*CN_ + n;
  for (int o = 0; o < C_; o++){
    const float* wr = W + o*C_;
    float a0=0.f,a1=0.f,a2=0.f,a3=0.f;
    #pragma unroll
    for (int c = 0; c < C_; c += 4){
      a0 += wr[c]*x[c];   a1 += wr[c+1]*x[c+1];
      a2 += wr[c+2]*x[c+2]; a3 += wr[c+3]*x[c+3];
    }
    op[o*N_] = bias[o] + ((a0+a1)+(a2+a3));
  }
}

// ---------------- fused q,k,v convs ----------------
__global__ __launch_bounds__(256) void conv_qkv_kernel(const float* __restrict__ nf,
    const float* __restrict__ Wq, const float* __restrict__ bq,
    const float* __restrict__ Wk, const float* __restrict__ bk,
    const float* __restrict__ Wv, const float* __restrict__ bv,
    float* __restrict__ qf, float* __restrict__ kf, float* __restrict__ vf){
  int p = blockIdx.x*256 + threadIdx.x;
  int b = p >> 13, n = p & (N_-1);
  const float* xin = nf + b*CN_ + n;
  float x[C_];
  #pragma unroll
  for (int c = 0; c < C_; c++) x[c] = xin[c*N_];
  for (int o = 0; o < C_; o++){
    const float* wq = Wq + o*C_;
    const float* wk = Wk + o*C_;
    const float* wv = Wv + o*C_;
    float q0=0,q1=0,k0=0,k1=0,v0=0,v1=0;
    #pragma unroll
    for (int c = 0; c < C_; c += 2){
      q0 += wq[c]*x[c]; q1 += wq[c+1]*x[c+1];
      k0 += wk[c]*x[c]; k1 += wk[c+1]*x[c+1];
      v0 += wv[c]*x[c]; v1 += wv[c+1]*x[c+1];
    }
    qf[b*CN_ + o*N_ + n] = bq[o] + q0 + q1;
    kf[b*CN_ + o*N_ + n] = bk[o] + k0 + k1;
    vf[b*CN_ + o*N_ + n] = bv[o] + v0 + v1;
  }
}

// ---------------- pos_pre group stats ----------------
__global__ __launch_bounds__(256) void pos_stats_kernel(const float4* __restrict__ pt4,
    const int* __restrict__ idx, const float* __restrict__ W1, const float* __restrict__ b1,
    float* __restrict__ gsum, float* __restrict__ gssq){
  __shared__ float ls[G_], lss[G_];
  if (threadIdx.x < G_){ ls[threadIdx.x] = 0.f; lss[threadIdx.x] = 0.f; }
  __syncthreads();
  int p = blockIdx.x*256 + threadIdx.x;
  int b = p >> 17;
  int r = p & (NK_-1);
  int n = r >> 4;
  int j = idx[p];
  float4 pj = pt4[b*N_ + j], pn = pt4[b*N_ + n];
  float rx = pj.x - pn.x, ry = pj.y - pn.y, rz = pj.z - pn.z;
  #pragma unroll
  for (int g = 0; g < G_; g++){
    float s = 0.f, ss = 0.f;
    #pragma unroll
    for (int ci = 0; ci < CPG; ci++){
      int c = g*CPG + ci;
      float v = b1[c] + W1[3*c]*rx + W1[3*c+1]*ry + W1[3*c+2]*rz;
      s += v; ss += v*v;
    }
    #pragma unroll
    for (int mk = 32; mk; mk >>= 1){ s += __shfl_xor(s, mk, 64); ss += __shfl_xor(ss, mk, 64); }
    if ((threadIdx.x & 63) == 0){ atomicAdd(&ls[g], s); atomicAdd(&lss[g], ss); }
  }
  __syncthreads();
  if (threadIdx.x < G_){
    atomicAdd(&gsum[b*G_ + threadIdx.x], ls[threadIdx.x]);
    atomicAdd(&gssq[b*G_ + threadIdx.x], lss[threadIdx.x]);
  }
}

// ---------------- finalize mean/rstd ----------------
__global__ void finalize_stats_kernel(const float* __restrict__ s, const float* __restrict__ ss,
    float* __restrict__ mean, float* __restrict__ rstd, float invcnt){
  int i = threadIdx.x;
  if (i < B_*G_){
    float m = s[i]*invcnt;
    float v = ss[i]*invcnt - m*m;
    v = fmaxf(v, 0.f);
    mean[i] = m;
    rstd[i] = rsqrtf(v + EPSV);
  }
}

// ---------------- fused: posGN -> W_pos2 -> (q-k+pos) -> W_att1 (+stats) ----------------
__global__ __launch_bounds__(256, 1) void att1_kernel(const float4* __restrict__ pt4,
    const int* __restrict__ idx,
    const float* __restrict__ W1, const float* __restrict__ b1,
    const float* __restrict__ pmean, const float* __restrict__ prstd,
    const float* __restrict__ g1, const float* __restrict__ be1,
    const float* __restrict__ W2, const float* __restrict__ b2,
    const float* __restrict__ Wa1T, const float* __restrict__ ba1,
    const float* __restrict__ qf, const float* __restrict__ kf,
    __hip_bfloat16* __restrict__ att1, float* __restrict__ gsum, float* __restrict__ gssq){
  __shared__ float ls[G_], lss[G_];
  if (threadIdx.x < G_){ ls[threadIdx.x]=0.f; lss[threadIdx.x]=0.f; }
  __syncthreads();
  int p = blockIdx.x*256 + threadIdx.x;
  int b = p >> 17;
  int r = p & (NK_-1);
  int n = r >> 4;
  int j = idx[p];
  float4 pj = pt4[b*N_ + j], pn = pt4[b*N_ + n];
  float rx = pj.x - pn.x, ry = pj.y - pn.y, rz = pj.z - pn.z;
  float posn[C_];
  #pragma unroll
  for (int c = 0; c < C_; c++){
    float v = b1[c] + W1[3*c]*rx + W1[3*c+1]*ry + W1[3*c+2]*rz;
    int g = c >> 4;
    v = (v - pmean[b*G_ + g]) * prstd[b*G_ + g];
    v = v*g1[c] + be1[c];
    posn[c] = leakyf(v);
  }
  float acc[C_];
  #pragma unroll
  for (int oo = 0; oo < C_; oo++) acc[oo] = ba1[oo];
  const float* qp = qf + b*CN_ + n;
  const float* kp = kf + b*CN_ + j;
  for (int o = 0; o < C_; o++){
    const float* wr = W2 + o*C_;
    float a0=0,a1=0,a2=0,a3=0;
    #pragma unroll
    for (int c = 0; c < C_; c += 4){
      a0 += wr[c]*posn[c];     a1 += wr[c+1]*posn[c+1];
      a2 += wr[c+2]*posn[c+2]; a3 += wr[c+3]*posn[c+3];
    }
    float av = qp[o*N_] - kp[o*N_] + b2[o] + ((a0+a1)+(a2+a3));
    const float* wt = Wa1T + o*C_;
    #pragma unroll
    for (int oo = 0; oo < C_; oo++) acc[oo] += wt[oo]*av;
  }
  float s = 0.f, ssum = 0.f;
  #pragma unroll
  for (int oo = 0; oo < C_; oo++){
    float a = acc[oo];
    att1[oo*BNK_ + p] = __float2bfloat16(a);
    s += a; ssum += a*a;
    if ((oo & 15) == 15){
      #pragma unroll
      for (int mk = 32; mk; mk >>= 1){ s += __shfl_xor(s, mk, 64); ssum += __shfl_xor(ssum, mk, 64); }
      if ((threadIdx.x & 63) == 0){ atomicAdd(&ls[oo >> 4], s); atomicAdd(&lss[oo >> 4], ssum); }
      s = 0.f; ssum = 0.f;
    }
  }
  __syncthreads();
  if (threadIdx.x < G_){
    atomicAdd(&gsum[b*G_ + threadIdx.x], ls[threadIdx.x]);
    atomicAdd(&gssq[b*G_ + threadIdx.x], lss[threadIdx.x]);
  }
}

// ---------------- fused: attGN -> W_att2 -> softmax(k) -> sum(att*v)+nf ----------------
__global__ __launch_bounds__(256) void att2_kernel(const __hip_bfloat16* __restrict__ att1,
    const float* __restrict__ amean, const float* __restrict__ arstd,
    const float* __restrict__ ga, const float* __restrict__ bea,
    const float* __restrict__ Wa2, const float* __restrict__ ba2,
    const float* __restrict__ vf, const float* __restrict__ nf,
    const int* __restrict__ idx, float* __restrict__ outpre){
  int p = blockIdx.x*256 + threadIdx.x;
  int b = p >> 17;
  int r = p & (NK_-1);
  int n = r >> 4;
  int j = idx[p];
  int lane = threadIdx.x & 63;
  float attn[C_];
  #pragma unroll
  for (int c = 0; c < C_; c++){
    float a = __bfloat162float(att1[c*BNK_ + p]);
    int g = c >> 4;
    a = (a - amean[b*G_ + g]) * arstd[b*G_ + g];
    a = a*ga[c] + bea[c];
    attn[c] = leakyf(a);
  }
  const float* vp = vf + b*CN_ + j;
  const float* nfp = nf + b*CN_ + n;
  float* op = outpre + b*CN_ + n;
  for (int o = 0; o < C_; o++){
    const float* wr = Wa2 + o*C_;
    float a0=0,a1=0,a2=0,a3=0;
    #pragma unroll
    for (int c = 0; c < C_; c += 4){
      a0 += wr[c]*attn[c];     a1 += wr[c+1]*attn[c+1];
      a2 += wr[c+2]*attn[c+2]; a3 += wr[c+3]*attn[c+3];
    }
    float a = ba2[o] + ((a0+a1)+(a2+a3));
    float mx = a;
    #pragma unroll
    for (int mk = 8; mk; mk >>= 1) mx = fmaxf(mx, __shfl_xor(mx, mk, 64));
    float e = __expf(a - mx);
    float sm = e;
    #pragma unroll
    for (int mk = 8; mk; mk >>= 1) sm += __shfl_xor(sm, mk, 64);
    float pv = (e/sm) * vp[o*N_];
    #pragma unroll
    for (int mk = 8; mk; mk >>= 1) pv += __shfl_xor(pv, mk, 64);
    if ((lane & 15) == 0) op[o*N_] = pv + nfp[o*N_];
  }
}

// ---------------- post conv + stats ----------------
__global__ __launch_bounds__(256) void post_kernel(const float* __restrict__ xin0,
    const float* __restrict__ W, const float* __restrict__ bias,
    float* __restrict__ out1, float* __restrict__ gsum, float* __restrict__ gssq){
  __shared__ float ls[G_], lss[G_];
  if (threadIdx.x < G_){ ls[threadIdx.x]=0.f; lss[threadIdx.x]=0.f; }
  __syncthreads();
  int p = blockIdx.x*256 + threadIdx.x;
  int b = p >> 13, n = p & (N_-1);
  const float* xin = xin0 + b*CN_ + n;
  float x[C_];
  #pragma unroll
  for (int c = 0; c < C_; c++) x[c] = xin[c*N_];
  float* op = out1 + b*CN_ + n;
  float s=0.f, ss=0.f;
  for (int o = 0; o < C_; o++){
    const float* wr = W + o*C_;
    float a0=0,a1=0,a2=0,a3=0;
    #pragma unroll
    for (int c = 0; c < C_; c += 4){
      a0 += wr[c]*x[c];   a1 += wr[c+1]*x[c+1];
      a2 += wr[c+2]*x[c+2]; a3 += wr[c+3]*x[c+3];
    }
    float a = bias[o] + ((a0+a1)+(a2+a3));
    op[o*N_] = a;
    s += a; ss += a*a;
    if ((o & 15) == 15){
      float s2=s, ss2=ss;
      #pragma unroll
      for (int mk = 32; mk; mk >>= 1){ s2 += __shfl_xor(s2, mk, 64); ss2 += __shfl_xor(ss2, mk, 64); }
      if ((threadIdx.x & 63) == 0){ atomicAdd(&ls[o>>4], s2); atomicAdd(&lss[o>>4], ss2); }
      s = 0.f; ss = 0.f;
    }
  }
  __syncthreads();
  if (threadIdx.x < G_){
    atomicAdd(&gsum[b*G_ + threadIdx.x], ls[threadIdx.x]);
    atomicAdd(&gssq[b*G_ + threadIdx.x], lss[threadIdx.x]);
  }
}

// ---------------- final GN + leaky ----------------
__global__ __launch_bounds__(256) void final_kernel(const float* __restrict__ out1,
    const float* __restrict__ mean, const float* __restrict__ rstd,
    const float* __restrict__ g, const float* __restrict__ be, float* __restrict__ out){
  int e = blockIdx.x*256 + threadIdx.x;
  int b = e >> 20;
  int c = (e >> 13) & (C_-1);
  int gi = b*G_ + (c >> 4);
  float v = (out1[e] - mean[gi]) * rstd[gi];
  v = v*g[c] + be[c];
  out[e] = leakyf(v);
}

extern "C" void kernel_launch(void* const* d_in, const int* in_sizes, int n_in,
                              void* d_out, int out_size, void* d_ws, size_t ws_size,
                              hipStream_t stream) {
  const float* xyz    = (const float*)d_in[0];
  const float* feat   = (const float*)d_in[1];
  const float* W_pre  = (const float*)d_in[2];
  const float* b_pre  = (const float*)d_in[3];
  const float* W_pos1 = (const float*)d_in[4];
  const float* b_pos1 = (const float*)d_in[5];
  const float* g_pos1 = (const float*)d_in[6];
  const float* be_pos1= (const float*)d_in[7];
  const float* W_pos2 = (const float*)d_in[8];
  const float* b_pos2 = (const float*)d_in[9];
  const float* W_q    = (const float*)d_in[10];
  const float* b_q    = (const float*)d_in[11];
  const float* W_k    = (const float*)d_in[12];
  const float* b_k    = (const float*)d_in[13];
  const float* W_v    = (const float*)d_in[14];
  const float* b_v    = (const float*)d_in[15];
  const float* W_att1 = (const float*)d_in[16];
  const float* b_att1 = (const float*)d_in[17];
  const float* g_att1 = (const float*)d_in[18];
  const float* be_att1= (const float*)d_in[19];
  const float* W_att2 = (const float*)d_in[20];
  const float* b_att2 = (const float*)d_in[21];
  const float* W_post = (const float*)d_in[22];
  const float* b_post = (const float*)d_in[23];
  const float* g_post = (const float*)d_in[24];
  const float* be_post= (const float*)d_in[25];

  char* w = (char*)d_ws;
  float4* pt4 = (float4*)w;            w += sizeof(float4)*BN_;
  int* idx = (int*)w;                  w += sizeof(int)*BNK_;
  float* Wa1T = (float*)w;             w += sizeof(float)*C_*C_;
  float* nf = (float*)w;               w += sizeof(float)*B_*CN_;
  float* qf = (float*)w;               w += sizeof(float)*B_*CN_;
  float* kf = (float*)w;               w += sizeof(float)*B_*CN_;
  float* vf = (float*)w;               w += sizeof(float)*B_*CN_;
  float* outpre = (float*)w;           w += sizeof(float)*B_*CN_;
  float* out1 = (float*)w;             w += sizeof(float)*B_*CN_;
  __hip_bfloat16* att1 = (__hip_bfloat16*)w; w += (size_t)2*C_*BNK_;
  float* stats = (float*)w;            w += 1024;

  float* pos_sum = stats +  0, *pos_ssq = stats + 16, *pos_mean = stats + 32, *pos_rstd = stats + 48;
  float* att_sum = stats + 64, *att_ssq = stats + 80, *att_mean = stats + 96, *att_rstd = stats +112;
  float* post_sum= stats +128, *post_ssq= stats +144, *post_mean= stats +160, *post_rstd= stats +176;

  hipMemsetAsync(stats, 0, 1024, stream);

  pack_kernel<<<BN_/256, 256, 0, stream>>>(xyz, pt4);
  transpose_kernel<<<1, 256, 0, stream>>>(W_att1, Wa1T);
  knn_kernel<<<BN_/(KNN_TPB/64), KNN_TPB, 0, stream>>>(pt4, idx);
  conv_pre_kernel<<<BN_/256, 256, 0, stream>>>(feat, W_pre, b_pre, nf);
  conv_qkv_kernel<<<BN_/256, 256, 0, stream>>>(nf, W_q, b_q, W_k, b_k, W_v, b_v, qf, kf, vf);
  pos_stats_kernel<<<BNK_/256, 256, 0, stream>>>(pt4, idx, W_pos1, b_pos1, pos_sum, pos_ssq);
  finalize_stats_kernel<<<1, 16, 0, stream>>>(pos_sum, pos_ssq, pos_mean, pos_rstd, 1.0f/(float)(CPG*NK_));
  att1_kernel<<<BNK_/256, 256, 0, stream>>>(pt4, idx, W_pos1, b_pos1, pos_mean, pos_rstd, g_pos1, be_pos1,
      W_pos2, b_pos2, Wa1T, b_att1, qf, kf, att1, att_sum, att_ssq);
  finalize_stats_kernel<<<1, 16, 0, stream>>>(att_sum, att_ssq, att_mean, att_rstd, 1.0f/(float)(CPG*NK_));
  att2_kernel<<<BNK_/256, 256, 0, stream>>>(att1, att_mean, att_rstd, g_att1, be_att1, W_att2, b_att2,
      vf, nf, idx, outpre);
  post_kernel<<<BN_/256, 256, 0, stream>>>(outpre, W_post, b_post, out1, post_sum, post_ssq);
  finalize_stats_kernel<<<1, 16, 0, stream>>>(post_sum, post_ssq, post_mean, post_rstd, 1.0f/(float)(CPG*N_));
  final_kernel<<<(B_*CN_)/256, 256, 0, stream>>>(out1, post_mean, post_rstd, g_post, be_post, (float*)d_out);
}

// Round 2
// 966.193 us; speedup vs baseline: 2.6044x; 2.6044x over previous
//
#include <hip/hip_runtime.h>
#include <hip/hip_bf16.h>
#include <float.h>

#define B_ 2
#define N_ 8192
#define C_ 128
#define K_ 16
#define G_ 8
#define NK_ (N_*K_)     // 131072
#define BN_ (B_*N_)     // 16384
#define BNK_ (B_*NK_)   // 262144
#define CN_ (C_*N_)
#define NEG 0.1f
#define EPSV 1e-5f

typedef __attribute__((ext_vector_type(4))) float f32x4;
typedef __attribute__((ext_vector_type(8))) short s16x8;
typedef __attribute__((ext_vector_type(4))) short s16x4;

__device__ __forceinline__ float leakyf(float x){ return x >= 0.f ? x : NEG*x; }
__device__ __forceinline__ short f2b(float x){
  union { __hip_bfloat16 b; short s; } u; u.b = __float2bfloat16(x); return u.s;
}
__device__ __forceinline__ float b2f(short s){
  union { __hip_bfloat16 b; short s; } u; u.s = s; return __bfloat162float(u.b);
}

// ---------------- pack xyz -> float4 ----------------
__global__ __launch_bounds__(256) void pack_kernel(const float* __restrict__ xyz, float4* __restrict__ pt4){
  int e = blockIdx.x*256 + threadIdx.x;
  int b = e >> 13, n = e & (N_-1);
  const float* xb = xyz + b*3*N_;
  pt4[e] = make_float4(xb[n], xb[N_+n], xb[2*N_+n], 0.f);
}

// ---------------- KNN: wave per query, fp64 distances ----------------
#define KNN_TPB 512
#define KNN_CHUNK 2048
__global__ __launch_bounds__(KNN_TPB) void knn_kernel(const float4* __restrict__ pt4, int* __restrict__ idxo){
  __shared__ float4 sp[KNN_CHUNK];
  int lane = threadIdx.x & 63, wid = threadIdx.x >> 6;
  int qg = blockIdx.x*(KNN_TPB/64) + wid;
  int b = qg >> 13, n = qg & (N_-1);
  const float4* pts = pt4 + b*N_;
  float4 qp = pts[n];
  double qx = qp.x, qy = qp.y, qz = qp.z;
  double qsq = qx*qx + qy*qy + qz*qz;
  double myd = DBL_MAX; int myi = 0x7fffffff;
  double thr = DBL_MAX; int thri = 0x7fffffff;
  for (int c0 = 0; c0 < N_; c0 += KNN_CHUNK){
    __syncthreads();
    #pragma unroll
    for (int t = 0; t < KNN_CHUNK/KNN_TPB; t++){
      int i = t*KNN_TPB + threadIdx.x;
      sp[i] = pts[c0 + i];
    }
    __syncthreads();
    for (int j0 = 0; j0 < KNN_CHUNK; j0 += 64){
      float4 pp = sp[j0 + lane];
      double px = pp.x, py = pp.y, pz = pp.z;
      double psq = px*px + py*py + pz*pz;
      double dot = qx*px + qy*py + qz*pz;
      double d2 = qsq + psq - 2.0*dot;
      int jj = c0 + j0 + lane;
      bool cand = (d2 < thr) || (d2 == thr && jj < thri);
      unsigned long long m = __ballot(cand);
      while (m){
        int src = __ffsll((unsigned long long)m) - 1;
        m &= m - 1;
        double dn = __shfl(d2, src, 64);
        int in_ = c0 + j0 + src;
        if ((dn < thr) || (dn == thr && in_ < thri)){
          bool less = (dn < myd) || (dn == myd && in_ < myi);
          unsigned long long bm = __ballot(less) & 0xFFFFull;
          int pos = __ffsll((unsigned long long)bm) - 1;
          double pd = __shfl_up(myd, 1, 64);
          int pi = __shfl_up(myi, 1, 64);
          if (lane < 16){
            if (lane > pos){ myd = pd; myi = pi; }
            else if (lane == pos){ myd = dn; myi = in_; }
          }
          thr = __shfl(myd, 15, 64);
          thri = __shfl(myi, 15, 64);
        }
      }
    }
  }
  if (lane < 16) idxo[qg*K_ + lane] = myi;
}

// ---------------- feat -> bf16 point-major ----------------
__global__ __launch_bounds__(256) void featb_kernel(const float* __restrict__ feat, ushort* __restrict__ fb){
  int p = blockIdx.x*256 + threadIdx.x;
  int b = p >> 13, n = p & (N_-1);
  const float* xin = feat + b*CN_ + n;
  #pragma unroll
  for (int c0 = 0; c0 < C_; c0 += 8){
    s16x8 o8;
    #pragma unroll
    for (int i = 0; i < 8; i++) o8[i] = f2b(xin[(size_t)(c0+i)*N_]);
    *(s16x8*)(fb + (size_t)p*C_ + c0) = o8;
  }
}

// ---------------- pos_pre group stats (fp32, exact-ish) ----------------
__global__ __launch_bounds__(256) void pos_stats_kernel(const float4* __restrict__ pt4,
    const int* __restrict__ idx, const float* __restrict__ W1, const float* __restrict__ b1,
    float* __restrict__ gsum, float* __restrict__ gssq){
  __shared__ float ls[G_], lss[G_];
  if (threadIdx.x < G_){ ls[threadIdx.x] = 0.f; lss[threadIdx.x] = 0.f; }
  __syncthreads();
  int p = blockIdx.x*256 + threadIdx.x;
  int b = p >> 17;
  int r = p & (NK_-1);
  int n = r >> 4;
  int j = idx[p];
  float4 pj = pt4[b*N_ + j], pn = pt4[b*N_ + n];
  float rx = pj.x - pn.x, ry = pj.y - pn.y, rz = pj.z - pn.z;
  #pragma unroll
  for (int g = 0; g < G_; g++){
    float s = 0.f, ss = 0.f;
    #pragma unroll
    for (int ci = 0; ci < 16; ci++){
      int c = g*16 + ci;
      float v = b1[c] + W1[3*c]*rx + W1[3*c+1]*ry + W1[3*c+2]*rz;
      s += v; ss += v*v;
    }
    #pragma unroll
    for (int mk = 32; mk; mk >>= 1){ s += __shfl_xor(s, mk, 64); ss += __shfl_xor(ss, mk, 64); }
    if ((threadIdx.x & 63) == 0){ atomicAdd(&ls[g], s); atomicAdd(&lss[g], ss); }
  }
  __syncthreads();
  if (threadIdx.x < G_){
    atomicAdd(&gsum[b*G_ + threadIdx.x], ls[threadIdx.x]);
    atomicAdd(&gssq[b*G_ + threadIdx.x], lss[threadIdx.x]);
  }
}

__global__ void finalize_stats_kernel(const float* __restrict__ s, const float* __restrict__ ss,
    float* __restrict__ mean, float* __restrict__ rstd, float invcnt){
  int i = threadIdx.x;
  if (i < B_*G_){
    float m = s[i]*invcnt;
    float v = ss[i]*invcnt - m*m;
    v = fmaxf(v, 0.f);
    mean[i] = m;
    rstd[i] = rsqrtf(v + EPSV);
  }
}

// ---------------- posb: pos1 conv -> GN -> leaky -> bf16 PM ----------------
__global__ __launch_bounds__(256) void posb_kernel(const float4* __restrict__ pt4,
    const int* __restrict__ idx, const float* __restrict__ W1, const float* __restrict__ b1,
    const float* __restrict__ pmean, const float* __restrict__ prstd,
    const float* __restrict__ g1, const float* __restrict__ be1, ushort* __restrict__ posb){
  int p = blockIdx.x*256 + threadIdx.x;
  int b = p >> 17;
  int r = p & (NK_-1);
  int n = r >> 4;
  int j = idx[p];
  float4 pj = pt4[b*N_ + j], pn = pt4[b*N_ + n];
  float rx = pj.x - pn.x, ry = pj.y - pn.y, rz = pj.z - pn.z;
  #pragma unroll
  for (int c0 = 0; c0 < C_; c0 += 8){
    s16x8 o8;
    #pragma unroll
    for (int i = 0; i < 8; i++){
      int c = c0 + i; int g = c >> 4;
      float v = b1[c] + W1[3*c]*rx + W1[3*c+1]*ry + W1[3*c+2]*rz;
      v = (v - pmean[b*G_ + g]) * prstd[b*G_ + g];
      v = v*g1[c] + be1[c];
      o8[i] = f2b(leakyf(v));
    }
    *(s16x8*)(posb + (size_t)p*C_ + c0) = o8;
  }
}

// ---------------- attn pointwise: GN(att1s) -> leaky -> bf16 PM ----------------
__global__ __launch_bounds__(256) void attnb_kernel(const ushort* __restrict__ att1s,
    const float* __restrict__ amean, const float* __restrict__ arstd,
    const float* __restrict__ ga, const float* __restrict__ bea, ushort* __restrict__ attnb){
  int p = blockIdx.x*256 + threadIdx.x;
  int b = p >> 17;
  #pragma unroll
  for (int c0 = 0; c0 < C_; c0 += 8){
    s16x8 h = *(const s16x8*)(att1s + (size_t)p*C_ + c0);
    s16x8 o8;
    #pragma unroll
    for (int i = 0; i < 8; i++){
      int c = c0 + i; int g = c >> 4;
      float v = (b2f(h[i]) - amean[b*G_ + g]) * arstd[b*G_ + g];
      v = v*ga[c] + bea[c];
      o8[i] = f2b(leakyf(v));
    }
    *(s16x8*)(attnb + (size_t)p*C_ + c0) = o8;
  }
}

// ---------------- MFMA GEMM: Y[128 x P] = W[128x128] * X[P x 128]^T ----------------
// X bf16 point-major. A-frags (weights) in registers. B direct from global.
#define EPI_PM 0
#define EPI_QK 1
#define EPI_STATS_PM 2
#define EPI_CM 3
#define EPI_STATS_F32CM 4

template<int EPI>
__global__ __launch_bounds__(256, 2) void gemm_kernel(
    const s16x8* __restrict__ X, const float* __restrict__ W, const float* __restrict__ bias,
    int ptiles_per_batch, int pts_per_batch, void* __restrict__ Y,
    const ushort* __restrict__ qb, const ushort* __restrict__ kb,
    const int* __restrict__ idx, float* __restrict__ gsum, float* __restrict__ gssq)
{
  int l = threadIdx.x & 63;
  int wid = threadIdx.x >> 6;
  int lm = l & 15, lh = l >> 4;
  int bb = blockIdx.y;

  // A fragments: afr[t][s], o = 16t + lm, c = 32s + lh*8 + i
  s16x8 afr[8][4];
  #pragma unroll
  for (int t = 0; t < 8; t++){
    #pragma unroll
    for (int s = 0; s < 4; s++){
      const float* wr = W + (size_t)(16*t + lm)*C_ + 32*s + lh*8;
      float4 w0 = *(const float4*)wr;
      float4 w1 = *(const float4*)(wr+4);
      s16x8 a;
      a[0]=f2b(w0.x); a[1]=f2b(w0.y); a[2]=f2b(w0.z); a[3]=f2b(w0.w);
      a[4]=f2b(w1.x); a[5]=f2b(w1.y); a[6]=f2b(w1.z); a[7]=f2b(w1.w);
      afr[t][s] = a;
    }
  }
  float gs[8], gq[8];
  #pragma unroll
  for (int t = 0; t < 8; t++){ gs[t] = 0.f; gq[t] = 0.f; }

  int nwaves = gridDim.x * 4;
  int gw = blockIdx.x*4 + wid;
  for (int tile = gw; tile < ptiles_per_batch; tile += nwaves){
    int p0 = bb*pts_per_batch + tile*16;
    int p  = p0 + lm;
    const s16x8* xr = X + (size_t)p*16;
    s16x8 bf0 = xr[lh], bf1 = xr[4+lh], bf2 = xr[8+lh], bf3 = xr[12+lh];
    f32x4 acc[8];
    #pragma unroll
    for (int t = 0; t < 8; t++) acc[t] = *(const f32x4*)(bias + 16*t + lh*4);  // bias in C-init
    #pragma unroll
    for (int t = 0; t < 8; t++) acc[t] = __builtin_amdgcn_mfma_f32_16x16x32_bf16(afr[t][0], bf0, acc[t], 0,0,0);
    #pragma unroll
    for (int t = 0; t < 8; t++) acc[t] = __builtin_amdgcn_mfma_f32_16x16x32_bf16(afr[t][1], bf1, acc[t], 0,0,0);
    #pragma unroll
    for (int t = 0; t < 8; t++) acc[t] = __builtin_amdgcn_mfma_f32_16x16x32_bf16(afr[t][2], bf2, acc[t], 0,0,0);
    #pragma unroll
    for (int t = 0; t < 8; t++) acc[t] = __builtin_amdgcn_mfma_f32_16x16x32_bf16(afr[t][3], bf3, acc[t], 0,0,0);

    if constexpr (EPI == EPI_QK){
      int n_ = tile;
      const ushort* qrow = qb + (size_t)(bb*N_ + n_)*C_;
      int j = idx[p];
      const ushort* krow = kb + (size_t)(bb*N_ + j)*C_;
      ushort* yp = (ushort*)Y + (size_t)p*C_;
      #pragma unroll
      for (int t = 0; t < 8; t++){
        int o0 = 16*t + lh*4;
        s16x4 q4 = *(const s16x4*)(qrow + o0);
        s16x4 k4 = *(const s16x4*)(krow + o0);
        s16x4 r4;
        #pragma unroll
        for (int r = 0; r < 4; r++) r4[r] = f2b(acc[t][r] + b2f(q4[r]) - b2f(k4[r]));
        *(s16x4*)(yp + o0) = r4;
      }
    } else if constexpr (EPI == EPI_PM){
      ushort* yp = (ushort*)Y + (size_t)p*C_;
      #pragma unroll
      for (int t = 0; t < 8; t++){
        int o0 = 16*t + lh*4;
        s16x4 r4;
        #pragma unroll
        for (int r = 0; r < 4; r++) r4[r] = f2b(acc[t][r]);
        *(s16x4*)(yp + o0) = r4;
      }
    } else if constexpr (EPI == EPI_STATS_PM){
      ushort* yp = (ushort*)Y + (size_t)p*C_;
      #pragma unroll
      for (int t = 0; t < 8; t++){
        int o0 = 16*t + lh*4;
        s16x4 r4;
        #pragma unroll
        for (int r = 0; r < 4; r++){
          float v = acc[t][r];
          r4[r] = f2b(v);
          gs[t] += v; gq[t] += v*v;
        }
        *(s16x4*)(yp + o0) = r4;
      }
    } else if constexpr (EPI == EPI_CM){
      ushort* yb = (ushort*)Y;
      #pragma unroll
      for (int t = 0; t < 8; t++){
        int o0 = 16*t + lh*4;
        #pragma unroll
        for (int r = 0; r < 4; r++) yb[(size_t)(o0+r)*BNK_ + p] = f2b(acc[t][r]);
      }
    } else {  // EPI_STATS_F32CM
      float* yf = (float*)Y;
      #pragma unroll
      for (int t = 0; t < 8; t++){
        int o0 = 16*t + lh*4;
        #pragma unroll
        for (int r = 0; r < 4; r++){
          float v = acc[t][r];
          yf[(size_t)(o0+r)*BN_ + p] = v;
          gs[t] += v; gq[t] += v*v;
        }
      }
    }
  }

  if constexpr (EPI == EPI_STATS_PM || EPI == EPI_STATS_F32CM){
    #pragma unroll
    for (int t = 0; t < 8; t++){
      float s = gs[t], q = gq[t];
      #pragma unroll
      for (int mk = 32; mk; mk >>= 1){ s += __shfl_xor(s, mk, 64); q += __shfl_xor(q, mk, 64); }
      if (l == 0){ atomicAdd(&gsum[bb*G_ + t], s); atomicAdd(&gssq[bb*G_ + t], q); }
    }
  }
}

// ---------------- att2b: softmax over k + PV gather + residual ----------------
__global__ __launch_bounds__(256) void att2b_kernel(const ushort* __restrict__ a2s,
    const ushort* __restrict__ vb, const ushort* __restrict__ nfb,
    const int* __restrict__ idx, ushort* __restrict__ outb){
  __shared__ int sidx[64*17];
  int n0 = blockIdx.x*64;
  for (int i = threadIdx.x; i < 1024; i += 256) sidx[(i>>4)*17 + (i&15)] = idx[n0*16 + i];
  __syncthreads();
  int nl = threadIdx.x & 63;
  int gn = n0 + nl;
  int b = gn >> 13;
  int o0 = (blockIdx.y*4 + (threadIdx.x>>6))*4;
  size_t pbase = (size_t)gn*16;
  float a[4][16];
  #pragma unroll
  for (int r = 0; r < 4; r++){
    const ushort* ap = a2s + (size_t)(o0+r)*BNK_ + pbase;
    s16x8 h0 = *(const s16x8*)ap;
    s16x8 h1 = *(const s16x8*)(ap+8);
    #pragma unroll
    for (int i = 0; i < 8; i++){ a[r][i] = b2f(h0[i]); a[r][8+i] = b2f(h1[i]); }
  }
  float w[4][16];
  #pragma unroll
  for (int r = 0; r < 4; r++){
    float m = a[r][0];
    #pragma unroll
    for (int k = 1; k < 16; k++) m = fmaxf(m, a[r][k]);
    float s = 0.f;
    #pragma unroll
    for (int k = 0; k < 16; k++){ float e = __expf(a[r][k]-m); w[r][k] = e; s += e; }
    float inv = 1.f/s;
    #pragma unroll
    for (int k = 0; k < 16; k++) w[r][k] *= inv;
  }
  float ov[4] = {0.f,0.f,0.f,0.f};
  #pragma unroll
  for (int k = 0; k < 16; k++){
    int j = sidx[nl*17 + k];
    const ushort* vp = vb + ((size_t)(b*N_ + j)*C_ + o0);
    s16x4 v4 = *(const s16x4*)vp;
    #pragma unroll
    for (int r = 0; r < 4; r++) ov[r] += w[r][k]*b2f(v4[r]);
  }
  s16x4 n4 = *(const s16x4*)(nfb + (size_t)gn*C_ + o0);
  s16x4 o4;
  #pragma unroll
  for (int r = 0; r < 4; r++) o4[r] = f2b(ov[r] + b2f(n4[r]));
  *(s16x4*)(outb + (size_t)gn*C_ + o0) = o4;
}

// ---------------- final GN + leaky (out1 col-major [C][BN]) ----------------
__global__ __launch_bounds__(256) void final_kernel(const float* __restrict__ out1,
    const float* __restrict__ mean, const float* __restrict__ rstd,
    const float* __restrict__ g, const float* __restrict__ be, float* __restrict__ out){
  int e = blockIdx.x*256 + threadIdx.x;
  int b = e >> 20;
  int c = (e >> 13) & (C_-1);
  int n = e & (N_-1);
  int gi = b*G_ + (c >> 4);
  float v = (out1[(size_t)c*BN_ + b*N_ + n] - mean[gi]) * rstd[gi];
  v = v*g[c] + be[c];
  out[e] = leakyf(v);
}

extern "C" void kernel_launch(void* const* d_in, const int* in_sizes, int n_in,
                              void* d_out, int out_size, void* d_ws, size_t ws_size,
                              hipStream_t stream) {
  const float* xyz    = (const float*)d_in[0];
  const float* feat   = (const float*)d_in[1];
  const float* W_pre  = (const float*)d_in[2];
  const float* b_pre  = (const float*)d_in[3];
  const float* W_pos1 = (const float*)d_in[4];
  const float* b_pos1 = (const float*)d_in[5];
  const float* g_pos1 = (const float*)d_in[6];
  const float* be_pos1= (const float*)d_in[7];
  const float* W_pos2 = (const float*)d_in[8];
  const float* b_pos2 = (const float*)d_in[9];
  const float* W_q    = (const float*)d_in[10];
  const float* b_q    = (const float*)d_in[11];
  const float* W_k    = (const float*)d_in[12];
  const float* b_k    = (const float*)d_in[13];
  const float* W_v    = (const float*)d_in[14];
  const float* b_v    = (const float*)d_in[15];
  const float* W_att1 = (const float*)d_in[16];
  const float* b_att1 = (const float*)d_in[17];
  const float* g_att1 = (const float*)d_in[18];
  const float* be_att1= (const float*)d_in[19];
  const float* W_att2 = (const float*)d_in[20];
  const float* b_att2 = (const float*)d_in[21];
  const float* W_post = (const float*)d_in[22];
  const float* b_post = (const float*)d_in[23];
  const float* g_post = (const float*)d_in[24];
  const float* be_post= (const float*)d_in[25];

  char* w = (char*)d_ws;
  float4* pt4 = (float4*)w;            w += sizeof(float4)*BN_;          // 256KB
  int* idx = (int*)w;                  w += sizeof(int)*BNK_;            // 1MB
  ushort* fb   = (ushort*)w;           w += (size_t)2*BN_*C_;            // 4MB
  ushort* nfb  = (ushort*)w;           w += (size_t)2*BN_*C_;
  ushort* qb   = (ushort*)w;           w += (size_t)2*BN_*C_;
  ushort* kb   = (ushort*)w;           w += (size_t)2*BN_*C_;
  ushort* vb   = (ushort*)w;           w += (size_t)2*BN_*C_;
  ushort* outb = (ushort*)w;           w += (size_t)2*BN_*C_;
  float* out1  = (float*)w;            w += (size_t)4*BN_*C_;            // 8MB
  ushort* bufA = (ushort*)w;           w += (size_t)2*BNK_*C_;           // 64MB
  ushort* bufB = (ushort*)w;           w += (size_t)2*BNK_*C_;           // 64MB
  float* stats = (float*)w;            w += 1024;

  float* pos_sum = stats +  0, *pos_ssq = stats + 16, *pos_mean = stats + 32, *pos_rstd = stats + 48;
  float* att_sum = stats + 64, *att_ssq = stats + 80, *att_mean = stats + 96, *att_rstd = stats +112;
  float* post_sum= stats +128, *post_ssq= stats +144, *post_mean= stats +160, *post_rstd= stats +176;

  hipMemsetAsync(stats, 0, 1024, stream);

  pack_kernel<<<BN_/256, 256, 0, stream>>>(xyz, pt4);
  knn_kernel<<<BN_/(KNN_TPB/64), KNN_TPB, 0, stream>>>(pt4, idx);
  featb_kernel<<<BN_/256, 256, 0, stream>>>(feat, fb);

  dim3 gBN(128, 2), gBNK(256, 2);
  // nf = W_pre*feat + b
  gemm_kernel<EPI_PM><<<gBN, 256, 0, stream>>>((const s16x8*)fb, W_pre, b_pre, N_/16, N_, nfb,
      nullptr, nullptr, nullptr, nullptr, nullptr);
  // q,k,v
  gemm_kernel<EPI_PM><<<gBN, 256, 0, stream>>>((const s16x8*)nfb, W_q, b_q, N_/16, N_, qb,
      nullptr, nullptr, nullptr, nullptr, nullptr);
  gemm_kernel<EPI_PM><<<gBN, 256, 0, stream>>>((const s16x8*)nfb, W_k, b_k, N_/16, N_, kb,
      nullptr, nullptr, nullptr, nullptr, nullptr);
  gemm_kernel<EPI_PM><<<gBN, 256, 0, stream>>>((const s16x8*)nfb, W_v, b_v, N_/16, N_, vb,
      nullptr, nullptr, nullptr, nullptr, nullptr);
  // pos stats -> posb
  pos_stats_kernel<<<BNK_/256, 256, 0, stream>>>(pt4, idx, W_pos1, b_pos1, pos_sum, pos_ssq);
  finalize_stats_kernel<<<1, 16, 0, stream>>>(pos_sum, pos_ssq, pos_mean, pos_rstd, 1.0f/(float)(16.0*NK_));
  posb_kernel<<<BNK_/256, 256, 0, stream>>>(pt4, idx, W_pos1, b_pos1, pos_mean, pos_rstd, g_pos1, be_pos1, bufA);
  // av = W_pos2*pos + b + q - k   (bufA -> bufB)
  gemm_kernel<EPI_QK><<<gBNK, 256, 0, stream>>>((const s16x8*)bufA, W_pos2, b_pos2, NK_/16, NK_, bufB,
      qb, kb, idx, nullptr, nullptr);
  // att1 = W_att1*av + b (+stats)  (bufB -> bufA)
  gemm_kernel<EPI_STATS_PM><<<gBNK, 256, 0, stream>>>((const s16x8*)bufB, W_att1, b_att1, NK_/16, NK_, bufA,
      nullptr, nullptr, nullptr, att_sum, att_ssq);
  finalize_stats_kernel<<<1, 16, 0, stream>>>(att_sum, att_ssq, att_mean, att_rstd, 1.0f/(float)(16.0*NK_));
  // attn = leaky(GN(att1))   (bufA -> bufB)
  attnb_kernel<<<BNK_/256, 256, 0, stream>>>(bufA, att_mean, att_rstd, g_att1, be_att1, bufB);
  // a2s = W_att2*attn + b  col-major  (bufB -> bufA)
  gemm_kernel<EPI_CM><<<gBNK, 256, 0, stream>>>((const s16x8*)bufB, W_att2, b_att2, NK_/16, NK_, bufA,
      nullptr, nullptr, nullptr, nullptr, nullptr);
  // softmax + PV + residual
  att2b_kernel<<<dim3(BN_/64, 8), 256, 0, stream>>>(bufA, vb, nfb, idx, outb);
  // post conv + stats (f32 col-major out1)
  gemm_kernel<EPI_STATS_F32CM><<<gBN, 256, 0, stream>>>((const s16x8*)outb, W_post, b_post, N_/16, N_, out1,
      nullptr, nullptr, nullptr, post_sum, post_ssq);
  finalize_stats_kernel<<<1, 16, 0, stream>>>(post_sum, post_ssq, post_mean, post_rstd, 1.0f/(float)(16.0*N_));
  final_kernel<<<(B_*CN_)/256, 256, 0, stream>>>(out1, post_mean, post_rstd, g_post, be_post, (float*)d_out);
}

// Round 3
// 499.613 us; speedup vs baseline: 5.0367x; 1.9339x over previous
//
#include <hip/hip_runtime.h>
#include <hip/hip_bf16.h>
#include <float.h>

#define B_ 2
#define N_ 8192
#define C_ 128
#define K_ 16
#define G_ 8
#define NK_ (N_*K_)     // 131072
#define BN_ (B_*N_)     // 16384
#define BNK_ (B_*NK_)   // 262144
#define CN_ (C_*N_)
#define NEG 0.1f
#define EPSV 1e-5f

typedef __attribute__((ext_vector_type(4))) float f32x4;
typedef __attribute__((ext_vector_type(8))) short s16x8;
typedef __attribute__((ext_vector_type(4))) short s16x4;

__device__ __forceinline__ float leakyf(float x){ return x >= 0.f ? x : NEG*x; }
__device__ __forceinline__ short f2b(float x){
  union { __hip_bfloat16 b; short s; } u; u.b = __float2bfloat16(x); return u.s;
}
__device__ __forceinline__ float b2f(short s){
  union { __hip_bfloat16 b; short s; } u; u.s = s; return __bfloat162float(u.b);
}

// ---------------- pack xyz -> float4 ----------------
__global__ __launch_bounds__(256) void pack_kernel(const float* __restrict__ xyz, float4* __restrict__ pt4){
  int e = blockIdx.x*256 + threadIdx.x;
  int b = e >> 13, n = e & (N_-1);
  const float* xb = xyz + b*3*N_;
  pt4[e] = make_float4(xb[n], xb[N_+n], xb[2*N_+n], 0.f);
}

// ---------------- KNN: wave per query, fp64 distances (verified; do not touch) ----------------
#define KNN_TPB 512
#define KNN_CHUNK 2048
__global__ __launch_bounds__(KNN_TPB) void knn_kernel(const float4* __restrict__ pt4, int* __restrict__ idxo){
  __shared__ float4 sp[KNN_CHUNK];
  int lane = threadIdx.x & 63, wid = threadIdx.x >> 6;
  int qg = blockIdx.x*(KNN_TPB/64) + wid;
  int b = qg >> 13, n = qg & (N_-1);
  const float4* pts = pt4 + b*N_;
  float4 qp = pts[n];
  double qx = qp.x, qy = qp.y, qz = qp.z;
  double qsq = qx*qx + qy*qy + qz*qz;
  double myd = DBL_MAX; int myi = 0x7fffffff;
  double thr = DBL_MAX; int thri = 0x7fffffff;
  for (int c0 = 0; c0 < N_; c0 += KNN_CHUNK){
    __syncthreads();
    #pragma unroll
    for (int t = 0; t < KNN_CHUNK/KNN_TPB; t++){
      int i = t*KNN_TPB + threadIdx.x;
      sp[i] = pts[c0 + i];
    }
    __syncthreads();
    for (int j0 = 0; j0 < KNN_CHUNK; j0 += 64){
      float4 pp = sp[j0 + lane];
      double px = pp.x, py = pp.y, pz = pp.z;
      double psq = px*px + py*py + pz*pz;
      double dot = qx*px + qy*py + qz*pz;
      double d2 = qsq + psq - 2.0*dot;
      int jj = c0 + j0 + lane;
      bool cand = (d2 < thr) || (d2 == thr && jj < thri);
      unsigned long long m = __ballot(cand);
      while (m){
        int src = __ffsll((unsigned long long)m) - 1;
        m &= m - 1;
        double dn = __shfl(d2, src, 64);
        int in_ = c0 + j0 + src;
        if ((dn < thr) || (dn == thr && in_ < thri)){
          bool less = (dn < myd) || (dn == myd && in_ < myi);
          unsigned long long bm = __ballot(less) & 0xFFFFull;
          int pos = __ffsll((unsigned long long)bm) - 1;
          double pd = __shfl_up(myd, 1, 64);
          int pi = __shfl_up(myi, 1, 64);
          if (lane < 16){
            if (lane > pos){ myd = pd; myi = pi; }
            else if (lane == pos){ myd = dn; myi = in_; }
          }
          thr = __shfl(myd, 15, 64);
          thri = __shfl(myi, 15, 64);
        }
      }
    }
  }
  if (lane < 16) idxo[qg*K_ + lane] = myi;
}

// ---------------- feat -> bf16 point-major ----------------
__global__ __launch_bounds__(256) void featb_kernel(const float* __restrict__ feat, ushort* __restrict__ fb){
  int p = blockIdx.x*256 + threadIdx.x;
  int b = p >> 13, n = p & (N_-1);
  const float* xin = feat + b*CN_ + n;
  #pragma unroll
  for (int c0 = 0; c0 < C_; c0 += 8){
    s16x8 o8;
    #pragma unroll
    for (int i = 0; i < 8; i++) o8[i] = f2b(xin[(size_t)(c0+i)*N_]);
    *(s16x8*)(fb + (size_t)p*C_ + c0) = o8;
  }
}

// ---------------- weight fuse: C = A @ B (fp32 128x128) ----------------
__global__ __launch_bounds__(256) void wfuse_kernel(const float* __restrict__ A, const float* __restrict__ Bm,
    float* __restrict__ Cm){
  int e = blockIdx.x*256 + threadIdx.x;
  int o = e >> 7, c = e & 127;
  float s = 0.f;
  #pragma unroll 8
  for (int m = 0; m < 128; m++) s += A[o*128+m]*Bm[m*128+c];
  Cm[e] = s;
}

// ---------------- bias fuse: out[o] = A[o,:]·v + badd[o] ----------------
__global__ void bfuse_kernel(const float* __restrict__ A, const float* __restrict__ v,
    const float* __restrict__ badd, float* __restrict__ out){
  int o = threadIdx.x;
  float s = badd ? badd[o] : 0.f;
  for (int m = 0; m < 128; m++) s += A[o*128+m]*v[m];
  out[o] = s;
}

// ---------------- pos_pre group stats (raw conv1 output) ----------------
__global__ __launch_bounds__(256) void pos_stats_kernel(const float4* __restrict__ pt4,
    const int* __restrict__ idx, const float* __restrict__ W1, const float* __restrict__ b1,
    float* __restrict__ gsum, float* __restrict__ gssq){
  __shared__ float ls[G_], lss[G_];
  if (threadIdx.x < G_){ ls[threadIdx.x] = 0.f; lss[threadIdx.x] = 0.f; }
  __syncthreads();
  int p = blockIdx.x*256 + threadIdx.x;
  int b = p >> 17;
  int n = p >> 4;             // global n
  int j = idx[p];
  float4 pj = pt4[(b<<13) + j], pn = pt4[n];
  float rx = pj.x - pn.x, ry = pj.y - pn.y, rz = pj.z - pn.z;
  #pragma unroll
  for (int g = 0; g < G_; g++){
    float s = 0.f, ss = 0.f;
    #pragma unroll
    for (int ci = 0; ci < 16; ci++){
      int c = g*16 + ci;
      float v = b1[c] + W1[3*c]*rx + W1[3*c+1]*ry + W1[3*c+2]*rz;
      s += v; ss += v*v;
    }
    #pragma unroll
    for (int mk = 32; mk; mk >>= 1){ s += __shfl_xor(s, mk, 64); ss += __shfl_xor(ss, mk, 64); }
    if ((threadIdx.x & 63) == 0){ atomicAdd(&ls[g], s); atomicAdd(&lss[g], ss); }
  }
  __syncthreads();
  if (threadIdx.x < G_){
    atomicAdd(&gsum[b*G_ + threadIdx.x], ls[threadIdx.x]);
    atomicAdd(&gssq[b*G_ + threadIdx.x], lss[threadIdx.x]);
  }
}

__global__ void finalize_stats_kernel(const float* __restrict__ s, const float* __restrict__ ss,
    float* __restrict__ mean, float* __restrict__ rstd, float invcnt){
  int i = threadIdx.x;
  if (i < B_*G_){
    float m = s[i]*invcnt;
    float v = ss[i]*invcnt - m*m;
    v = fmaxf(v, 0.f);
    mean[i] = m;
    rstd[i] = rsqrtf(v + EPSV);
  }
}

// ---------------- folded GN params ----------------
// posPrm [b][4][128]: sx,sy,sz,so for posn = leaky(sx*rx+sy*ry+sz*rz+so)
__global__ void posparams_kernel(const float* __restrict__ W1, const float* __restrict__ b1,
    const float* __restrict__ g1, const float* __restrict__ be1,
    const float* __restrict__ pmean, const float* __restrict__ prstd, float* __restrict__ prm){
  int i = threadIdx.x;           // 256
  int b = i >> 7, c = i & 127, g = c >> 4;
  float rs = prstd[b*G_+g]*g1[c];
  prm[b*512 +   0 + c] = W1[3*c]*rs;
  prm[b*512 + 128 + c] = W1[3*c+1]*rs;
  prm[b*512 + 256 + c] = W1[3*c+2]*rs;
  prm[b*512 + 384 + c] = (b1[c]-pmean[b*G_+g])*rs + be1[c];
}

// attPrm [b][2][128]: scale, shift for attn = leaky(att1*scale+shift)
__global__ void attparams_kernel(const float* __restrict__ ga, const float* __restrict__ bea,
    const float* __restrict__ amean, const float* __restrict__ arstd, float* __restrict__ prm){
  int i = threadIdx.x;
  int b = i >> 7, c = i & 127, g = c >> 4;
  float sc = ga[c]*arstd[b*G_+g];
  prm[b*256 +   0 + c] = sc;
  prm[b*256 + 128 + c] = bea[c] - amean[b*G_+g]*sc;
}

// ---------------- unified MFMA GEMM: Y[o][p] = W*X + bias, block = 64 pts x 128 out ----------------
#define ST_COPY 0
#define ST_GN   1
#define ST_POS  2
#define EP_PM    0
#define EP_QKS   1
#define EP_F32CM 2

template<int STAGE, int EPI>
__global__ __launch_bounds__(256) void mgemm_kernel(
    const ushort* __restrict__ Xb, const float* __restrict__ W, const float* __restrict__ bias,
    const float* __restrict__ prm, const float4* __restrict__ pt4, const int* __restrict__ idx,
    const ushort* __restrict__ Aq, const ushort* __restrict__ Ak,
    void* __restrict__ Y, float* __restrict__ gsum, float* __restrict__ gssq, int bsh)
{
  __shared__ ushort xs[64*128];
  __shared__ float sblk[16];
  int tid = threadIdx.x;
  int l = tid & 63, wid = tid >> 6;
  int lm = l & 15, lh = l >> 4;
  int p0 = blockIdx.x * 64;
  int b = p0 >> bsh;

  if (tid < 16) sblk[tid] = 0.f;

  // A fragments: wave owns out-channels [wid*32, wid*32+32)
  s16x8 afr[2][4];
  #pragma unroll
  for (int t = 0; t < 2; t++){
    int T = wid*2 + t;
    #pragma unroll
    for (int ks = 0; ks < 4; ks++){
      const float* wr = W + (size_t)(T*16 + lm)*C_ + ks*32 + lh*8;
      float4 w0 = *(const float4*)wr;
      float4 w1 = *(const float4*)(wr+4);
      s16x8 a;
      a[0]=f2b(w0.x); a[1]=f2b(w0.y); a[2]=f2b(w0.z); a[3]=f2b(w0.w);
      a[4]=f2b(w1.x); a[5]=f2b(w1.y); a[6]=f2b(w1.z); a[7]=f2b(w1.w);
      afr[t][ks] = a;
    }
  }

  // ---- staging into LDS, swizzled: xs[row][ (slot^(row&7))*8 .. ] ----
  {
    int row = tid & 63, cc = tid >> 6;
    if constexpr (STAGE == ST_COPY){
      const ushort* src = Xb + (size_t)(p0+row)*C_ + cc*32;
      #pragma unroll
      for (int q = 0; q < 4; q++){
        s16x8 v8 = *(const s16x8*)(src + q*8);
        int sl = (cc*4+q) ^ (row&7);
        *(s16x8*)(xs + row*C_ + sl*8) = v8;
      }
    } else if constexpr (STAGE == ST_GN){
      const ushort* src = Xb + (size_t)(p0+row)*C_ + cc*32;
      const float* sc = prm + b*256;
      const float* sh = prm + b*256 + 128;
      #pragma unroll
      for (int q = 0; q < 4; q++){
        s16x8 v8 = *(const s16x8*)(src + q*8);
        s16x8 o8;
        #pragma unroll
        for (int i = 0; i < 8; i++){
          int c = cc*32 + q*8 + i;
          o8[i] = f2b(leakyf(b2f(v8[i])*sc[c] + sh[c]));
        }
        int sl = (cc*4+q) ^ (row&7);
        *(s16x8*)(xs + row*C_ + sl*8) = o8;
      }
    } else { // ST_POS
      int p = p0 + row;
      int ng = p >> 4;
      int j = idx[p];
      float4 pj = pt4[(b<<13) + j], pn = pt4[ng];
      float rx = pj.x - pn.x, ry = pj.y - pn.y, rz = pj.z - pn.z;
      const float* sx = prm + b*512;
      const float* sy = sx + 128;
      const float* sz = sx + 256;
      const float* so = sx + 384;
      #pragma unroll
      for (int q = 0; q < 4; q++){
        s16x8 o8;
        #pragma unroll
        for (int i = 0; i < 8; i++){
          int c = cc*32 + q*8 + i;
          o8[i] = f2b(leakyf(sx[c]*rx + sy[c]*ry + sz[c]*rz + so[c]));
        }
        int sl = (cc*4+q) ^ (row&7);
        *(s16x8*)(xs + row*C_ + sl*8) = o8;
      }
    }
  }
  __syncthreads();

  // ---- compute ----
  f32x4 acc[2][4];
  #pragma unroll
  for (int t = 0; t < 2; t++){
    f32x4 bs = *(const f32x4*)(bias + (wid*2+t)*16 + lh*4);
    #pragma unroll
    for (int ps = 0; ps < 4; ps++) acc[t][ps] = bs;
  }
  #pragma unroll
  for (int ps = 0; ps < 4; ps++){
    int row = ps*16 + lm;
    s16x8 bf[4];
    #pragma unroll
    for (int ks = 0; ks < 4; ks++){
      int sl = (ks*4+lh) ^ (row&7);
      bf[ks] = *(const s16x8*)(xs + row*C_ + sl*8);
    }
    #pragma unroll
    for (int ks = 0; ks < 4; ks++){
      #pragma unroll
      for (int t = 0; t < 2; t++)
        acc[t][ps] = __builtin_amdgcn_mfma_f32_16x16x32_bf16(afr[t][ks], bf[ks], acc[t][ps], 0,0,0);
    }
  }

  // ---- epilogue ----
  float gs[2] = {0.f,0.f}, gq[2] = {0.f,0.f};
  #pragma unroll
  for (int t = 0; t < 2; t++){
    int T = wid*2 + t;
    int o0 = T*16 + lh*4;
    #pragma unroll
    for (int ps = 0; ps < 4; ps++){
      int p = p0 + ps*16 + lm;
      if constexpr (EPI == EP_PM){
        s16x4 r4;
        #pragma unroll
        for (int r = 0; r < 4; r++) r4[r] = f2b(acc[t][ps][r]);
        *(s16x4*)((ushort*)Y + (size_t)p*C_ + o0) = r4;
      } else if constexpr (EPI == EP_QKS){
        int ng = p >> 4;
        int j = idx[p];
        s16x4 aq4 = *(const s16x4*)(Aq + (size_t)ng*C_ + o0);
        s16x4 ak4 = *(const s16x4*)(Ak + ((size_t)(b<<13)+j)*C_ + o0);
        s16x4 r4;
        #pragma unroll
        for (int r = 0; r < 4; r++){
          float v = acc[t][ps][r] + b2f(aq4[r]) - b2f(ak4[r]);
          r4[r] = f2b(v);
          gs[t] += v; gq[t] += v*v;
        }
        *(s16x4*)((ushort*)Y + (size_t)p*C_ + o0) = r4;
      } else { // EP_F32CM
        float* yf = (float*)Y;
        #pragma unroll
        for (int r = 0; r < 4; r++){
          float v = acc[t][ps][r];
          yf[(size_t)(o0+r)*BN_ + p] = v;
          gs[t] += v; gq[t] += v*v;
        }
      }
    }
  }

  if constexpr (EPI == EP_QKS || EPI == EP_F32CM){
    #pragma unroll
    for (int t = 0; t < 2; t++){
      float s = gs[t], q = gq[t];
      #pragma unroll
      for (int mk = 32; mk; mk >>= 1){ s += __shfl_xor(s, mk, 64); q += __shfl_xor(q, mk, 64); }
      if (l == 0){
        int T = wid*2 + t;
        atomicAdd(&sblk[T], s); atomicAdd(&sblk[8+T], q);
      }
    }
    __syncthreads();
    if (tid < 8){
      atomicAdd(&gsum[b*G_ + tid], sblk[tid]);
      atomicAdd(&gssq[b*G_ + tid], sblk[8+tid]);
    }
  }
}

// ---------------- att2: softmax over k (no max-sub; logits bounded) + PV + residual ----------------
__global__ __launch_bounds__(256) void att2b_kernel(const ushort* __restrict__ a2s,
    const ushort* __restrict__ vb, const ushort* __restrict__ nfb,
    const int* __restrict__ idx, ushort* __restrict__ outb){
  int tid = blockIdx.x*256 + threadIdx.x;
  int n = tid >> 4;          // global n
  int cc = tid & 15;
  int b = n >> 13;
  const int* ir = idx + (size_t)n*16;
  float sum[8], pv[8];
  #pragma unroll
  for (int i = 0; i < 8; i++){ sum[i] = 0.f; pv[i] = 0.f; }
  const ushort* ab = a2s + (size_t)n*16*C_ + cc*8;
  #pragma unroll
  for (int k = 0; k < 16; k++){
    s16x8 l8 = *(const s16x8*)(ab + k*C_);
    int j = ir[k];
    s16x8 v8 = *(const s16x8*)(vb + ((size_t)(b<<13)+j)*C_ + cc*8);
    #pragma unroll
    for (int i = 0; i < 8; i++){
      float e = __expf(b2f(l8[i]));
      sum[i] += e;
      pv[i] += e*b2f(v8[i]);
    }
  }
  s16x8 n8 = *(const s16x8*)(nfb + (size_t)n*C_ + cc*8);
  s16x8 o8;
  #pragma unroll
  for (int i = 0; i < 8; i++) o8[i] = f2b(pv[i]/sum[i] + b2f(n8[i]));
  *(s16x8*)(outb + (size_t)n*C_ + cc*8) = o8;
}

// ---------------- final GN + leaky (out1 col-major [C][BN]) ----------------
__global__ __launch_bounds__(256) void final_kernel(const float* __restrict__ out1,
    const float* __restrict__ mean, const float* __restrict__ rstd,
    const float* __restrict__ g, const float* __restrict__ be, float* __restrict__ out){
  int e = blockIdx.x*256 + threadIdx.x;
  int b = e >> 20;
  int c = (e >> 13) & (C_-1);
  int n = e & (N_-1);
  int gi = b*G_ + (c >> 4);
  float v = (out1[(size_t)c*BN_ + b*N_ + n] - mean[gi]) * rstd[gi];
  v = v*g[c] + be[c];
  out[e] = leakyf(v);
}

extern "C" void kernel_launch(void* const* d_in, const int* in_sizes, int n_in,
                              void* d_out, int out_size, void* d_ws, size_t ws_size,
                              hipStream_t stream) {
  const float* xyz    = (const float*)d_in[0];
  const float* feat   = (const float*)d_in[1];
  const float* W_pre  = (const float*)d_in[2];
  const float* b_pre  = (const float*)d_in[3];
  const float* W_pos1 = (const float*)d_in[4];
  const float* b_pos1 = (const float*)d_in[5];
  const float* g_pos1 = (const float*)d_in[6];
  const float* be_pos1= (const float*)d_in[7];
  const float* W_pos2 = (const float*)d_in[8];
  const float* b_pos2 = (const float*)d_in[9];
  const float* W_q    = (const float*)d_in[10];
  const float* b_q    = (const float*)d_in[11];
  const float* W_k    = (const float*)d_in[12];
  const float* b_k    = (const float*)d_in[13];
  const float* W_v    = (const float*)d_in[14];
  const float* b_v    = (const float*)d_in[15];
  const float* W_att1 = (const float*)d_in[16];
  const float* b_att1 = (const float*)d_in[17];
  const float* g_att1 = (const float*)d_in[18];
  const float* be_att1= (const float*)d_in[19];
  const float* W_att2 = (const float*)d_in[20];
  const float* b_att2 = (const float*)d_in[21];
  const float* W_post = (const float*)d_in[22];
  const float* b_post = (const float*)d_in[23];
  const float* g_post = (const float*)d_in[24];
  const float* be_post= (const float*)d_in[25];

  char* w = (char*)d_ws;
  float4* pt4 = (float4*)w;            w += sizeof(float4)*BN_;
  int* idx = (int*)w;                  w += sizeof(int)*BNK_;
  ushort* fb   = (ushort*)w;           w += (size_t)2*BN_*C_;
  ushort* nfb  = (ushort*)w;           w += (size_t)2*BN_*C_;
  ushort* vb   = (ushort*)w;           w += (size_t)2*BN_*C_;
  ushort* Aqb  = (ushort*)w;           w += (size_t)2*BN_*C_;
  ushort* Akb  = (ushort*)w;           w += (size_t)2*BN_*C_;
  ushort* outb = (ushort*)w;           w += (size_t)2*BN_*C_;
  float* out1  = (float*)w;            w += (size_t)4*BN_*C_;
  ushort* bufA = (ushort*)w;           w += (size_t)2*BNK_*C_;           // att1 PM
  ushort* bufB = (ushort*)w;           w += (size_t)2*BNK_*C_;           // a2s PM
  float* Wf    = (float*)w;            w += sizeof(float)*C_*C_;
  float* Wqa   = (float*)w;            w += sizeof(float)*C_*C_;
  float* Wka   = (float*)w;            w += sizeof(float)*C_*C_;
  float* bG1   = (float*)w;            w += 512;
  float* bqa   = (float*)w;            w += 512;
  float* bka   = (float*)w;            w += 512;
  float* posPrm= (float*)w;            w += sizeof(float)*1024;
  float* attPrm= (float*)w;            w += sizeof(float)*512;
  float* stats = (float*)w;            w += 1024;

  float* pos_sum = stats +  0, *pos_ssq = stats + 16, *pos_mean = stats + 32, *pos_rstd = stats + 48;
  float* att_sum = stats + 64, *att_ssq = stats + 80, *att_mean = stats + 96, *att_rstd = stats +112;
  float* post_sum= stats +128, *post_ssq= stats +144, *post_mean= stats +160, *post_rstd= stats +176;

  hipMemsetAsync(stats, 0, 1024, stream);

  pack_kernel<<<BN_/256, 256, 0, stream>>>(xyz, pt4);
  knn_kernel<<<BN_/(KNN_TPB/64), KNN_TPB, 0, stream>>>(pt4, idx);
  featb_kernel<<<BN_/256, 256, 0, stream>>>(feat, fb);

  // fused weights / biases
  wfuse_kernel<<<64, 256, 0, stream>>>(W_att1, W_pos2, Wf);
  wfuse_kernel<<<64, 256, 0, stream>>>(W_att1, W_q, Wqa);
  wfuse_kernel<<<64, 256, 0, stream>>>(W_att1, W_k, Wka);
  bfuse_kernel<<<1, 128, 0, stream>>>(W_att1, b_pos2, b_att1, bG1);
  bfuse_kernel<<<1, 128, 0, stream>>>(W_att1, b_q, nullptr, bqa);
  bfuse_kernel<<<1, 128, 0, stream>>>(W_att1, b_k, nullptr, bka);

  // BN-sized GEMMs (256 blocks each)
  mgemm_kernel<ST_COPY,EP_PM><<<BN_/64, 256, 0, stream>>>(fb,  W_pre, b_pre, nullptr, nullptr, nullptr,
      nullptr, nullptr, nfb, nullptr, nullptr, 13);
  mgemm_kernel<ST_COPY,EP_PM><<<BN_/64, 256, 0, stream>>>(nfb, W_v,   b_v,   nullptr, nullptr, nullptr,
      nullptr, nullptr, vb,  nullptr, nullptr, 13);
  mgemm_kernel<ST_COPY,EP_PM><<<BN_/64, 256, 0, stream>>>(nfb, Wqa,   bqa,   nullptr, nullptr, nullptr,
      nullptr, nullptr, Aqb, nullptr, nullptr, 13);
  mgemm_kernel<ST_COPY,EP_PM><<<BN_/64, 256, 0, stream>>>(nfb, Wka,   bka,   nullptr, nullptr, nullptr,
      nullptr, nullptr, Akb, nullptr, nullptr, 13);

  // pos GN stats -> folded params
  pos_stats_kernel<<<BNK_/256, 256, 0, stream>>>(pt4, idx, W_pos1, b_pos1, pos_sum, pos_ssq);
  finalize_stats_kernel<<<1, 16, 0, stream>>>(pos_sum, pos_ssq, pos_mean, pos_rstd, 1.0f/(float)(16.0*NK_));
  posparams_kernel<<<1, 256, 0, stream>>>(W_pos1, b_pos1, g_pos1, be_pos1, pos_mean, pos_rstd, posPrm);

  // G1: att1 = Wf*posn + bG1 + Aq[n] - Ak[j]  (+ stats)  -> bufA
  mgemm_kernel<ST_POS,EP_QKS><<<BNK_/64, 256, 0, stream>>>(nullptr, Wf, bG1, posPrm, pt4, idx,
      Aqb, Akb, bufA, att_sum, att_ssq, 17);
  finalize_stats_kernel<<<1, 16, 0, stream>>>(att_sum, att_ssq, att_mean, att_rstd, 1.0f/(float)(16.0*NK_));
  attparams_kernel<<<1, 256, 0, stream>>>(g_att1, be_att1, att_mean, att_rstd, attPrm);

  // G2: a2s = W_att2*leaky(GN(att1)) + b  -> bufB
  mgemm_kernel<ST_GN,EP_PM><<<BNK_/64, 256, 0, stream>>>(bufA, W_att2, b_att2, attPrm, nullptr, nullptr,
      nullptr, nullptr, bufB, nullptr, nullptr, 17);

  // softmax + PV + residual
  att2b_kernel<<<BN_*16/256, 256, 0, stream>>>(bufB, vb, nfb, idx, outb);

  // post conv + stats (f32 col-major)
  mgemm_kernel<ST_COPY,EP_F32CM><<<BN_/64, 256, 0, stream>>>(outb, W_post, b_post, nullptr, nullptr, nullptr,
      nullptr, nullptr, out1, post_sum, post_ssq, 13);
  finalize_stats_kernel<<<1, 16, 0, stream>>>(post_sum, post_ssq, post_mean, post_rstd, 1.0f/(float)(16.0*N_));
  final_kernel<<<(B_*CN_)/256, 256, 0, stream>>>(out1, post_mean, post_rstd, g_post, be_post, (float*)d_out);
}

// Round 5
// 449.528 us; speedup vs baseline: 5.5979x; 1.1114x over previous
//
#include <hip/hip_runtime.h>
#include <hip/hip_bf16.h>
#include <float.h>

#define B_ 2
#define N_ 8192
#define C_ 128
#define K_ 16
#define G_ 8
#define NK_ (N_*K_)     // 131072
#define BN_ (B_*N_)     // 16384
#define BNK_ (B_*NK_)   // 262144
#define CN_ (C_*N_)
#define NEG 0.1f
#define EPSV 1e-5f

typedef __attribute__((ext_vector_type(4))) float f32x4;
typedef __attribute__((ext_vector_type(8))) short s16x8;
typedef __attribute__((ext_vector_type(4))) short s16x4;

__device__ __forceinline__ float leakyf(float x){ return x >= 0.f ? x : NEG*x; }
__device__ __forceinline__ short f2b(float x){
  union { __hip_bfloat16 b; short s; } u; u.b = __float2bfloat16(x); return u.s;
}
__device__ __forceinline__ float b2f(short s){
  union { __hip_bfloat16 b; short s; } u; u.s = s; return __bfloat162float(u.b);
}

// ---------------- pack xyz -> float4 (w = |p|^2 fp32, filter only) ----------------
__global__ __launch_bounds__(256) void pack_kernel(const float* __restrict__ xyz, float4* __restrict__ pt4){
  int e = blockIdx.x*256 + threadIdx.x;
  int b = e >> 13, n = e & (N_-1);
  const float* xb = xyz + b*3*N_;
  float x = xb[n], y = xb[N_+n], z = xb[2*N_+n];
  pt4[e] = make_float4(x, y, z, x*x + y*y + z*z);
}

// ---------------- KNN: wave per query, fp32 prefilter + fp64 exact refine ----------------
#define KNN_TPB 512
#define KNN_CHUNK 2048
#define KNN_MARGIN 1e-2f
__global__ __launch_bounds__(KNN_TPB) void knn_kernel(const float4* __restrict__ pt4, int* __restrict__ idxo){
  __shared__ float4 sp[KNN_CHUNK];
  int lane = threadIdx.x & 63, wid = threadIdx.x >> 6;
  int qg = blockIdx.x*(KNN_TPB/64) + wid;
  int b = qg >> 13, n = qg & (N_-1);
  const float4* pts = pt4 + b*N_;
  float4 qp = pts[n];
  double qx = qp.x, qy = qp.y, qz = qp.z;
  double qsq = qx*qx + qy*qy + qz*qz;
  float qx2 = -2.f*qp.x, qy2 = -2.f*qp.y, qz2 = -2.f*qp.z;
  double myd = DBL_MAX; int myi = 0x7fffffff;     // lanes 0..15: sorted top-16
  double thr = DBL_MAX; int thri = 0x7fffffff;
  float cmpv = FLT_MAX;                            // (float)(thr - qsq) + margin
  for (int c0 = 0; c0 < N_; c0 += KNN_CHUNK){
    __syncthreads();
    #pragma unroll
    for (int t = 0; t < KNN_CHUNK/KNN_TPB; t++){
      int i = t*KNN_TPB + threadIdx.x;
      sp[i] = pts[c0 + i];
    }
    __syncthreads();
    for (int j0 = 0; j0 < KNN_CHUNK; j0 += 64){
      float4 pp = sp[j0 + lane];
      // monotone fp32 filter: f = |p|^2 - 2 q.p   (qsq folded into cmpv)
      float f = fmaf(pp.x, qx2, fmaf(pp.y, qy2, fmaf(pp.z, qz2, pp.w)));
      unsigned long long m = __ballot(f < cmpv);
      if (m){
        // exact fp64 distance for survivor lanes
        double px = pp.x, py = pp.y, pz = pp.z;
        double psq = px*px + py*py + pz*pz;
        double dot = qx*px + qy*py + qz*pz;
        double d2 = qsq + psq - 2.0*dot;
        while (m){
          int src = __ffsll((unsigned long long)m) - 1;
          m &= m - 1;
          double dn = __shfl(d2, src, 64);
          int in_ = c0 + j0 + src;
          if ((dn < thr) || (dn == thr && in_ < thri)){
            bool less = (dn < myd) || (dn == myd && in_ < myi);
            unsigned long long bm = __ballot(less) & 0xFFFFull;
            if (bm){   // candidate still beats current 16th (thr may be stale)
              int pos = __ffsll((unsigned long long)bm) - 1;
              double pd = __shfl_up(myd, 1, 64);
              int pi = __shfl_up(myi, 1, 64);
              if (lane < 16){
                if (lane > pos){ myd = pd; myi = pi; }
                else if (lane == pos){ myd = dn; myi = in_; }
              }
            }
          }
        }
        // refresh threshold once per survivor-group (stale thr is conservative)
        thr = __shfl(myd, 15, 64);
        thri = __shfl(myi, 15, 64);
        cmpv = (float)(thr - qsq) + KNN_MARGIN;
      }
    }
  }
  if (lane < 16) idxo[qg*K_ + lane] = myi;
}

// ---------------- feat -> bf16 point-major ----------------
__global__ __launch_bounds__(256) void featb_kernel(const float* __restrict__ feat, ushort* __restrict__ fb){
  int p = blockIdx.x*256 + threadIdx.x;
  int b = p >> 13, n = p & (N_-1);
  const float* xin = feat + b*CN_ + n;
  #pragma unroll
  for (int c0 = 0; c0 < C_; c0 += 8){
    s16x8 o8;
    #pragma unroll
    for (int i = 0; i < 8; i++) o8[i] = f2b(xin[(size_t)(c0+i)*N_]);
    *(s16x8*)(fb + (size_t)p*C_ + c0) = o8;
  }
}

// ---------------- weight fuse: C = A @ B (fp32 128x128) ----------------
__global__ __launch_bounds__(256) void wfuse_kernel(const float* __restrict__ A, const float* __restrict__ Bm,
    float* __restrict__ Cm){
  int e = blockIdx.x*256 + threadIdx.x;
  int o = e >> 7, c = e & 127;
  float s = 0.f;
  #pragma unroll 8
  for (int m = 0; m < 128; m++) s += A[o*128+m]*Bm[m*128+c];
  Cm[e] = s;
}

// ---------------- bias fuse: out[o] = A[o,:]·v + badd[o] ----------------
__global__ void bfuse_kernel(const float* __restrict__ A, const float* __restrict__ v,
    const float* __restrict__ badd, float* __restrict__ out){
  int o = threadIdx.x;
  float s = badd ? badd[o] : 0.f;
  for (int m = 0; m < 128; m++) s += A[o*128+m]*v[m];
  out[o] = s;
}

// ---------------- pos_pre group stats (raw conv1 output) ----------------
__global__ __launch_bounds__(256) void pos_stats_kernel(const float4* __restrict__ pt4,
    const int* __restrict__ idx, const float* __restrict__ W1, const float* __restrict__ b1,
    float* __restrict__ gsum, float* __restrict__ gssq){
  __shared__ float ls[G_], lss[G_];
  if (threadIdx.x < G_){ ls[threadIdx.x] = 0.f; lss[threadIdx.x] = 0.f; }
  __syncthreads();
  int p = blockIdx.x*256 + threadIdx.x;
  int b = p >> 17;
  int n = p >> 4;             // global n
  int j = idx[p];
  float4 pj = pt4[(b<<13) + j], pn = pt4[n];
  float rx = pj.x - pn.x, ry = pj.y - pn.y, rz = pj.z - pn.z;
  #pragma unroll
  for (int g = 0; g < G_; g++){
    float s = 0.f, ss = 0.f;
    #pragma unroll
    for (int ci = 0; ci < 16; ci++){
      int c = g*16 + ci;
      float v = b1[c] + W1[3*c]*rx + W1[3*c+1]*ry + W1[3*c+2]*rz;
      s += v; ss += v*v;
    }
    #pragma unroll
    for (int mk = 32; mk; mk >>= 1){ s += __shfl_xor(s, mk, 64); ss += __shfl_xor(ss, mk, 64); }
    if ((threadIdx.x & 63) == 0){ atomicAdd(&ls[g], s); atomicAdd(&lss[g], ss); }
  }
  __syncthreads();
  if (threadIdx.x < G_){
    atomicAdd(&gsum[b*G_ + threadIdx.x], ls[threadIdx.x]);
    atomicAdd(&gssq[b*G_ + threadIdx.x], lss[threadIdx.x]);
  }
}

__global__ void finalize_stats_kernel(const float* __restrict__ s, const float* __restrict__ ss,
    float* __restrict__ mean, float* __restrict__ rstd, float invcnt){
  int i = threadIdx.x;
  if (i < B_*G_){
    float m = s[i]*invcnt;
    float v = ss[i]*invcnt - m*m;
    v = fmaxf(v, 0.f);
    mean[i] = m;
    rstd[i] = rsqrtf(v + EPSV);
  }
}

// ---------------- folded GN params ----------------
__global__ void posparams_kernel(const float* __restrict__ W1, const float* __restrict__ b1,
    const float* __restrict__ g1, const float* __restrict__ be1,
    const float* __restrict__ pmean, const float* __restrict__ prstd, float* __restrict__ prm){
  int i = threadIdx.x;           // 256
  int b = i >> 7, c = i & 127, g = c >> 4;
  float rs = prstd[b*G_+g]*g1[c];
  prm[b*512 +   0 + c] = W1[3*c]*rs;
  prm[b*512 + 128 + c] = W1[3*c+1]*rs;
  prm[b*512 + 256 + c] = W1[3*c+2]*rs;
  prm[b*512 + 384 + c] = (b1[c]-pmean[b*G_+g])*rs + be1[c];
}

__global__ void attparams_kernel(const float* __restrict__ ga, const float* __restrict__ bea,
    const float* __restrict__ amean, const float* __restrict__ arstd, float* __restrict__ prm){
  int i = threadIdx.x;
  int b = i >> 7, c = i & 127, g = c >> 4;
  float sc = ga[c]*arstd[b*G_+g];
  prm[b*256 +   0 + c] = sc;
  prm[b*256 + 128 + c] = bea[c] - amean[b*G_+g]*sc;
}

// ---------------- unified MFMA GEMM: Y[o][p] = W*X + bias, block = 64 pts x 128 out ----------------
#define ST_COPY 0
#define ST_GN   1
#define ST_POS  2
#define EP_PM    0
#define EP_QKS   1
#define EP_F32CM 2

template<int STAGE, int EPI>
__global__ __launch_bounds__(256) void mgemm_kernel(
    const ushort* __restrict__ Xb, const float* __restrict__ W, const float* __restrict__ bias,
    const float* __restrict__ prm, const float4* __restrict__ pt4, const int* __restrict__ idx,
    const ushort* __restrict__ Aq, const ushort* __restrict__ Ak,
    void* __restrict__ Y, float* __restrict__ gsum, float* __restrict__ gssq, int bsh)
{
  __shared__ ushort xs[64*128];
  __shared__ float sblk[16];
  int tid = threadIdx.x;
  int l = tid & 63, wid = tid >> 6;
  int lm = l & 15, lh = l >> 4;
  int p0 = blockIdx.x * 64;
  int b = p0 >> bsh;

  if (tid < 16) sblk[tid] = 0.f;

  // A fragments: wave owns out-channels [wid*32, wid*32+32)
  s16x8 afr[2][4];
  #pragma unroll
  for (int t = 0; t < 2; t++){
    int T = wid*2 + t;
    #pragma unroll
    for (int ks = 0; ks < 4; ks++){
      const float* wr = W + (size_t)(T*16 + lm)*C_ + ks*32 + lh*8;
      float4 w0 = *(const float4*)wr;
      float4 w1 = *(const float4*)(wr+4);
      s16x8 a;
      a[0]=f2b(w0.x); a[1]=f2b(w0.y); a[2]=f2b(w0.z); a[3]=f2b(w0.w);
      a[4]=f2b(w1.x); a[5]=f2b(w1.y); a[6]=f2b(w1.z); a[7]=f2b(w1.w);
      afr[t][ks] = a;
    }
  }

  // ---- staging into LDS, swizzled: xs[row][ (slot^(row&7))*8 .. ] ----
  {
    int row = tid & 63, cc = tid >> 6;
    if constexpr (STAGE == ST_COPY){
      const ushort* src = Xb + (size_t)(p0+row)*C_ + cc*32;
      #pragma unroll
      for (int q = 0; q < 4; q++){
        s16x8 v8 = *(const s16x8*)(src + q*8);
        int sl = (cc*4+q) ^ (row&7);
        *(s16x8*)(xs + row*C_ + sl*8) = v8;
      }
    } else if constexpr (STAGE == ST_GN){
      const ushort* src = Xb + (size_t)(p0+row)*C_ + cc*32;
      const float* sc = prm + b*256;
      const float* sh = prm + b*256 + 128;
      #pragma unroll
      for (int q = 0; q < 4; q++){
        s16x8 v8 = *(const s16x8*)(src + q*8);
        s16x8 o8;
        #pragma unroll
        for (int i = 0; i < 8; i++){
          int c = cc*32 + q*8 + i;
          o8[i] = f2b(leakyf(b2f(v8[i])*sc[c] + sh[c]));
        }
        int sl = (cc*4+q) ^ (row&7);
        *(s16x8*)(xs + row*C_ + sl*8) = o8;
      }
    } else { // ST_POS
      int p = p0 + row;
      int ng = p >> 4;
      int j = idx[p];
      float4 pj = pt4[(b<<13) + j], pn = pt4[ng];
      float rx = pj.x - pn.x, ry = pj.y - pn.y, rz = pj.z - pn.z;
      const float* sx = prm + b*512;
      const float* sy = sx + 128;
      const float* sz = sx + 256;
      const float* so = sx + 384;
      #pragma unroll
      for (int q = 0; q < 4; q++){
        s16x8 o8;
        #pragma unroll
        for (int i = 0; i < 8; i++){
          int c = cc*32 + q*8 + i;
          o8[i] = f2b(leakyf(sx[c]*rx + sy[c]*ry + sz[c]*rz + so[c]));
        }
        int sl = (cc*4+q) ^ (row&7);
        *(s16x8*)(xs + row*C_ + sl*8) = o8;
      }
    }
  }
  __syncthreads();

  // ---- compute ----
  f32x4 acc[2][4];
  #pragma unroll
  for (int t = 0; t < 2; t++){
    f32x4 bs = *(const f32x4*)(bias + (wid*2+t)*16 + lh*4);
    #pragma unroll
    for (int ps = 0; ps < 4; ps++) acc[t][ps] = bs;
  }
  #pragma unroll
  for (int ps = 0; ps < 4; ps++){
    int row = ps*16 + lm;
    s16x8 bf[4];
    #pragma unroll
    for (int ks = 0; ks < 4; ks++){
      int sl = (ks*4+lh) ^ (row&7);
      bf[ks] = *(const s16x8*)(xs + row*C_ + sl*8);
    }
    #pragma unroll
    for (int ks = 0; ks < 4; ks++){
      #pragma unroll
      for (int t = 0; t < 2; t++)
        acc[t][ps] = __builtin_amdgcn_mfma_f32_16x16x32_bf16(afr[t][ks], bf[ks], acc[t][ps], 0,0,0);
    }
  }

  // ---- epilogue ----
  float gs[2] = {0.f,0.f}, gq[2] = {0.f,0.f};
  #pragma unroll
  for (int t = 0; t < 2; t++){
    int T = wid*2 + t;
    int o0 = T*16 + lh*4;
    #pragma unroll
    for (int ps = 0; ps < 4; ps++){
      int p = p0 + ps*16 + lm;
      if constexpr (EPI == EP_PM){
        s16x4 r4;
        #pragma unroll
        for (int r = 0; r < 4; r++) r4[r] = f2b(acc[t][ps][r]);
        *(s16x4*)((ushort*)Y + (size_t)p*C_ + o0) = r4;
      } else if constexpr (EPI == EP_QKS){
        int ng = p >> 4;
        int j = idx[p];
        s16x4 aq4 = *(const s16x4*)(Aq + (size_t)ng*C_ + o0);
        s16x4 ak4 = *(const s16x4*)(Ak + ((size_t)(b<<13)+j)*C_ + o0);
        s16x4 r4;
        #pragma unroll
        for (int r = 0; r < 4; r++){
          float v = acc[t][ps][r] + b2f(aq4[r]) - b2f(ak4[r]);
          r4[r] = f2b(v);
          gs[t] += v; gq[t] += v*v;
        }
        *(s16x4*)((ushort*)Y + (size_t)p*C_ + o0) = r4;
      } else { // EP_F32CM
        float* yf = (float*)Y;
        #pragma unroll
        for (int r = 0; r < 4; r++){
          float v = acc[t][ps][r];
          yf[(size_t)(o0+r)*BN_ + p] = v;
          gs[t] += v; gq[t] += v*v;
        }
      }
    }
  }

  if constexpr (EPI == EP_QKS || EPI == EP_F32CM){
    #pragma unroll
    for (int t = 0; t < 2; t++){
      float s = gs[t], q = gq[t];
      #pragma unroll
      for (int mk = 32; mk; mk >>= 1){ s += __shfl_xor(s, mk, 64); q += __shfl_xor(q, mk, 64); }
      if (l == 0){
        int T = wid*2 + t;
        atomicAdd(&sblk[T], s); atomicAdd(&sblk[8+T], q);
      }
    }
    __syncthreads();
    if (tid < 8){
      atomicAdd(&gsum[b*G_ + tid], sblk[tid]);
      atomicAdd(&gssq[b*G_ + tid], sblk[8+tid]);
    }
  }
}

// ---------------- att2: softmax over k (no max-sub; logits bounded) + PV + residual ----------------
__global__ __launch_bounds__(256) void att2b_kernel(const ushort* __restrict__ a2s,
    const ushort* __restrict__ vb, const ushort* __restrict__ nfb,
    const int* __restrict__ idx, ushort* __restrict__ outb){
  int tid = blockIdx.x*256 + threadIdx.x;
  int n = tid >> 4;          // global n
  int cc = tid & 15;
  int b = n >> 13;
  const int* ir = idx + (size_t)n*16;
  float sum[8], pv[8];
  #pragma unroll
  for (int i = 0; i < 8; i++){ sum[i] = 0.f; pv[i] = 0.f; }
  const ushort* ab = a2s + (size_t)n*16*C_ + cc*8;
  #pragma unroll
  for (int k = 0; k < 16; k++){
    s16x8 l8 = *(const s16x8*)(ab + k*C_);
    int j = ir[k];
    s16x8 v8 = *(const s16x8*)(vb + ((size_t)(b<<13)+j)*C_ + cc*8);
    #pragma unroll
    for (int i = 0; i < 8; i++){
      float e = __expf(b2f(l8[i]));
      sum[i] += e;
      pv[i] += e*b2f(v8[i]);
    }
  }
  s16x8 n8 = *(const s16x8*)(nfb + (size_t)n*C_ + cc*8);
  s16x8 o8;
  #pragma unroll
  for (int i = 0; i < 8; i++) o8[i] = f2b(pv[i]/sum[i] + b2f(n8[i]));
  *(s16x8*)(outb + (size_t)n*C_ + cc*8) = o8;
}

// ---------------- final GN + leaky (out1 col-major [C][BN]) ----------------
__global__ __launch_bounds__(256) void final_kernel(const float* __restrict__ out1,
    const float* __restrict__ mean, const float* __restrict__ rstd,
    const float* __restrict__ g, const float* __restrict__ be, float* __restrict__ out){
  int e = blockIdx.x*256 + threadIdx.x;
  int b = e >> 20;
  int c = (e >> 13) & (C_-1);
  int n = e & (N_-1);
  int gi = b*G_ + (c >> 4);
  float v = (out1[(size_t)c*BN_ + b*N_ + n] - mean[gi]) * rstd[gi];
  v = v*g[c] + be[c];
  out[e] = leakyf(v);
}

extern "C" void kernel_launch(void* const* d_in, const int* in_sizes, int n_in,
                              void* d_out, int out_size, void* d_ws, size_t ws_size,
                              hipStream_t stream) {
  const float* xyz    = (const float*)d_in[0];
  const float* feat   = (const float*)d_in[1];
  const float* W_pre  = (const float*)d_in[2];
  const float* b_pre  = (const float*)d_in[3];
  const float* W_pos1 = (const float*)d_in[4];
  const float* b_pos1 = (const float*)d_in[5];
  const float* g_pos1 = (const float*)d_in[6];
  const float* be_pos1= (const float*)d_in[7];
  const float* W_pos2 = (const float*)d_in[8];
  const float* b_pos2 = (const float*)d_in[9];
  const float* W_q    = (const float*)d_in[10];
  const float* b_q    = (const float*)d_in[11];
  const float* W_k    = (const float*)d_in[12];
  const float* b_k    = (const float*)d_in[13];
  const float* W_v    = (const float*)d_in[14];
  const float* b_v    = (const float*)d_in[15];
  const float* W_att1 = (const float*)d_in[16];
  const float* b_att1 = (const float*)d_in[17];
  const float* g_att1 = (const float*)d_in[18];
  const float* be_att1= (const float*)d_in[19];
  const float* W_att2 = (const float*)d_in[20];
  const float* b_att2 = (const float*)d_in[21];
  const float* W_post = (const float*)d_in[22];
  const float* b_post = (const float*)d_in[23];
  const float* g_post = (const float*)d_in[24];
  const float* be_post= (const float*)d_in[25];

  char* w = (char*)d_ws;
  float4* pt4 = (float4*)w;            w += sizeof(float4)*BN_;
  int* idx = (int*)w;                  w += sizeof(int)*BNK_;
  ushort* fb   = (ushort*)w;           w += (size_t)2*BN_*C_;
  ushort* nfb  = (ushort*)w;           w += (size_t)2*BN_*C_;
  ushort* vb   = (ushort*)w;           w += (size_t)2*BN_*C_;
  ushort* Aqb  = (ushort*)w;           w += (size_t)2*BN_*C_;
  ushort* Akb  = (ushort*)w;           w += (size_t)2*BN_*C_;
  ushort* outb = (ushort*)w;           w += (size_t)2*BN_*C_;
  float* out1  = (float*)w;            w += (size_t)4*BN_*C_;
  ushort* bufA = (ushort*)w;           w += (size_t)2*BNK_*C_;           // att1 PM
  ushort* bufB = (ushort*)w;           w += (size_t)2*BNK_*C_;           // a2s PM
  float* Wf    = (float*)w;            w += sizeof(float)*C_*C_;
  float* Wqa   = (float*)w;            w += sizeof(float)*C_*C_;
  float* Wka   = (float*)w;            w += sizeof(float)*C_*C_;
  float* bG1   = (float*)w;            w += 512;
  float* bqa   = (float*)w;            w += 512;
  float* bka   = (float*)w;            w += 512;
  float* posPrm= (float*)w;            w += sizeof(float)*1024;
  float* attPrm= (float*)w;            w += sizeof(float)*512;
  float* stats = (float*)w;            w += 1024;

  float* pos_sum = stats +  0, *pos_ssq = stats + 16, *pos_mean = stats + 32, *pos_rstd = stats + 48;
  float* att_sum = stats + 64, *att_ssq = stats + 80, *att_mean = stats + 96, *att_rstd = stats +112;
  float* post_sum= stats +128, *post_ssq= stats +144, *post_mean= stats +160, *post_rstd= stats +176;

  hipMemsetAsync(stats, 0, 1024, stream);

  pack_kernel<<<BN_/256, 256, 0, stream>>>(xyz, pt4);
  knn_kernel<<<BN_/(KNN_TPB/64), KNN_TPB, 0, stream>>>(pt4, idx);
  featb_kernel<<<BN_/256, 256, 0, stream>>>(feat, fb);

  // fused weights / biases
  wfuse_kernel<<<64, 256, 0, stream>>>(W_att1, W_pos2, Wf);
  wfuse_kernel<<<64, 256, 0, stream>>>(W_att1, W_q, Wqa);
  wfuse_kernel<<<64, 256, 0, stream>>>(W_att1, W_k, Wka);
  bfuse_kernel<<<1, 128, 0, stream>>>(W_att1, b_pos2, b_att1, bG1);
  bfuse_kernel<<<1, 128, 0, stream>>>(W_att1, b_q, nullptr, bqa);
  bfuse_kernel<<<1, 128, 0, stream>>>(W_att1, b_k, nullptr, bka);

  // BN-sized GEMMs (256 blocks each)
  mgemm_kernel<ST_COPY,EP_PM><<<BN_/64, 256, 0, stream>>>(fb,  W_pre, b_pre, nullptr, nullptr, nullptr,
      nullptr, nullptr, nfb, nullptr, nullptr, 13);
  mgemm_kernel<ST_COPY,EP_PM><<<BN_/64, 256, 0, stream>>>(nfb, W_v,   b_v,   nullptr, nullptr, nullptr,
      nullptr, nullptr, vb,  nullptr, nullptr, 13);
  mgemm_kernel<ST_COPY,EP_PM><<<BN_/64, 256, 0, stream>>>(nfb, Wqa,   bqa,   nullptr, nullptr, nullptr,
      nullptr, nullptr, Aqb, nullptr, nullptr, 13);
  mgemm_kernel<ST_COPY,EP_PM><<<BN_/64, 256, 0, stream>>>(nfb, Wka,   bka,   nullptr, nullptr, nullptr,
      nullptr, nullptr, Akb, nullptr, nullptr, 13);

  // pos GN stats -> folded params
  pos_stats_kernel<<<BNK_/256, 256, 0, stream>>>(pt4, idx, W_pos1, b_pos1, pos_sum, pos_ssq);
  finalize_stats_kernel<<<1, 16, 0, stream>>>(pos_sum, pos_ssq, pos_mean, pos_rstd, 1.0f/(float)(16.0*NK_));
  posparams_kernel<<<1, 256, 0, stream>>>(W_pos1, b_pos1, g_pos1, be_pos1, pos_mean, pos_rstd, posPrm);

  // G1: att1 = Wf*posn + bG1 + Aq[n] - Ak[j]  (+ stats)  -> bufA
  mgemm_kernel<ST_POS,EP_QKS><<<BNK_/64, 256, 0, stream>>>(nullptr, Wf, bG1, posPrm, pt4, idx,
      Aqb, Akb, bufA, att_sum, att_ssq, 17);
  finalize_stats_kernel<<<1, 16, 0, stream>>>(att_sum, att_ssq, att_mean, att_rstd, 1.0f/(float)(16.0*NK_));
  attparams_kernel<<<1, 256, 0, stream>>>(g_att1, be_att1, att_mean, att_rstd, attPrm);

  // G2: a2s = W_att2*leaky(GN(att1)) + b  -> bufB
  mgemm_kernel<ST_GN,EP_PM><<<BNK_/64, 256, 0, stream>>>(bufA, W_att2, b_att2, attPrm, nullptr, nullptr,
      nullptr, nullptr, bufB, nullptr, nullptr, 17);

  // softmax + PV + residual
  att2b_kernel<<<BN_*16/256, 256, 0, stream>>>(bufB, vb, nfb, idx, outb);

  // post conv + stats (f32 col-major)
  mgemm_kernel<ST_COPY,EP_F32CM><<<BN_/64, 256, 0, stream>>>(outb, W_post, b_post, nullptr, nullptr, nullptr,
      nullptr, nullptr, out1, post_sum, post_ssq, 13);
  finalize_stats_kernel<<<1, 16, 0, stream>>>(post_sum, post_ssq, post_mean, post_rstd, 1.0f/(float)(16.0*N_));
  final_kernel<<<(B_*CN_)/256, 256, 0, stream>>>(out1, post_mean, post_rstd, g_post, be_post, (float*)d_out);
}

// Round 6
// 430.901 us; speedup vs baseline: 5.8399x; 1.0432x over previous
//
#include <hip/hip_runtime.h>
#include <hip/hip_bf16.h>
#include <float.h>

#define B_ 2
#define N_ 8192
#define C_ 128
#define K_ 16
#define G_ 8
#define NK_ (N_*K_)     // 131072
#define BN_ (B_*N_)     // 16384
#define BNK_ (B_*NK_)   // 262144
#define CN_ (C_*N_)
#define NEG 0.1f
#define EPSV 1e-5f

typedef __attribute__((ext_vector_type(4))) float f32x4;
typedef __attribute__((ext_vector_type(8))) short s16x8;
typedef __attribute__((ext_vector_type(4))) short s16x4;

__device__ __forceinline__ float leakyf(float x){ return x >= 0.f ? x : NEG*x; }
__device__ __forceinline__ short f2b(float x){
  union { __hip_bfloat16 b; short s; } u; u.b = __float2bfloat16(x); return u.s;
}
__device__ __forceinline__ float b2f(short s){
  union { __hip_bfloat16 b; short s; } u; u.s = s; return __bfloat162float(u.b);
}

// row_shr:1 within 16-lane rows (list lives in lanes 0..15 -> row-local)
__device__ __forceinline__ int dpp_shr1_i(int x){
  return __builtin_amdgcn_update_dpp(x, x, 0x111, 0xF, 0xF, false);
}
__device__ __forceinline__ double dpp_shr1_d(double x){
  union { double d; int i[2]; } u; u.d = x;
  u.i[0] = dpp_shr1_i(u.i[0]);
  u.i[1] = dpp_shr1_i(u.i[1]);
  return u.d;
}
__device__ __forceinline__ double readlane_d(double x, int l){
  union { double d; int i[2]; } u; u.d = x;
  union { double d; int i[2]; } r;
  r.i[0] = __builtin_amdgcn_readlane(u.i[0], l);
  r.i[1] = __builtin_amdgcn_readlane(u.i[1], l);
  return r.d;
}

// ---------------- pack xyz -> float4 (w = |p|^2 fp32, filter only) ----------------
__global__ __launch_bounds__(256) void pack_kernel(const float* __restrict__ xyz, float4* __restrict__ pt4){
  int e = blockIdx.x*256 + threadIdx.x;
  int b = e >> 13, n = e & (N_-1);
  const float* xb = xyz + b*3*N_;
  float x = xb[n], y = xb[N_+n], z = xb[2*N_+n];
  pt4[e] = make_float4(x, y, z, x*x + y*y + z*z);
}

// ---------------- KNN: wave per query, fp32 prefilter + fp64 exact refine ----------------
#define KNN_TPB 512
#define KNN_CHUNK 2048
#define KNN_MARGIN 1e-2f
__global__ __launch_bounds__(KNN_TPB) void knn_kernel(const float4* __restrict__ pt4, int* __restrict__ idxo){
  __shared__ float4 sp[KNN_CHUNK];
  int lane = threadIdx.x & 63, wid = threadIdx.x >> 6;
  int qg = blockIdx.x*(KNN_TPB/64) + wid;
  int b = qg >> 13, n = qg & (N_-1);
  const float4* pts = pt4 + b*N_;
  float4 qp = pts[n];
  double qx = qp.x, qy = qp.y, qz = qp.z;
  double qsq = qx*qx + qy*qy + qz*qz;
  float qx2 = -2.f*qp.x, qy2 = -2.f*qp.y, qz2 = -2.f*qp.z;
  double myd = DBL_MAX; int myi = 0x7fffffff;     // lanes 0..15: sorted top-16
  double thr = DBL_MAX; int thri = 0x7fffffff;
  float cmpv = FLT_MAX;                            // (float)(thr - qsq) + margin

  auto process = [&](unsigned long long m, double d2v, int base){
    while (m){
      int src = __ffsll(m) - 1; m &= m - 1;
      double dn = readlane_d(d2v, src);
      int in_ = base + src;
      if ((dn < thr) || (dn == thr && in_ < thri)){
        bool less = (dn < myd) || (dn == myd && in_ < myi);
        unsigned long long bm = __ballot(less) & 0xFFFFull;
        if (bm){   // candidate still beats current 16th (thr may be stale)
          int pos = __ffsll(bm) - 1;
          double pd = dpp_shr1_d(myd);
          int pi = dpp_shr1_i(myi);
          if (lane < 16){
            if (lane > pos){ myd = pd; myi = pi; }
            else if (lane == pos){ myd = dn; myi = in_; }
          }
        }
      }
    }
  };

  for (int c0 = 0; c0 < N_; c0 += KNN_CHUNK){
    __syncthreads();
    #pragma unroll
    for (int t = 0; t < KNN_CHUNK/KNN_TPB; t++){
      int i = t*KNN_TPB + threadIdx.x;
      sp[i] = pts[c0 + i];
    }
    __syncthreads();
    for (int j0 = 0; j0 < KNN_CHUNK; j0 += 128){
      float4 pA = sp[j0 + lane];
      float4 pB = sp[j0 + 64 + lane];
      float fA = fmaf(pA.x, qx2, fmaf(pA.y, qy2, fmaf(pA.z, qz2, pA.w)));
      float fB = fmaf(pB.x, qx2, fmaf(pB.y, qy2, fmaf(pB.z, qz2, pB.w)));
      unsigned long long mA = __ballot(fA < cmpv);
      unsigned long long mB = __ballot(fB < cmpv);
      if (mA | mB){
        if (mA){
          double px = pA.x, py = pA.y, pz = pA.z;
          double psq = px*px + py*py + pz*pz;
          double dot = qx*px + qy*py + qz*pz;
          double d2 = qsq + psq - 2.0*dot;
          process(mA, d2, c0 + j0);
        }
        if (mB){
          double px = pB.x, py = pB.y, pz = pB.z;
          double psq = px*px + py*py + pz*pz;
          double dot = qx*px + qy*py + qz*pz;
          double d2 = qsq + psq - 2.0*dot;
          process(mB, d2, c0 + j0 + 64);
        }
        // refresh threshold once per survivor-group (stale thr is conservative)
        thr = readlane_d(myd, 15);
        thri = __builtin_amdgcn_readlane(myi, 15);
        cmpv = (float)(thr - qsq) + KNN_MARGIN;
      }
    }
  }
  if (lane < 16) idxo[qg*K_ + lane] = myi;
}

// ---------------- feat -> bf16 point-major ----------------
__global__ __launch_bounds__(256) void featb_kernel(const float* __restrict__ feat, ushort* __restrict__ fb){
  int p = blockIdx.x*256 + threadIdx.x;
  int b = p >> 13, n = p & (N_-1);
  const float* xin = feat + b*CN_ + n;
  #pragma unroll
  for (int c0 = 0; c0 < C_; c0 += 8){
    s16x8 o8;
    #pragma unroll
    for (int i = 0; i < 8; i++) o8[i] = f2b(xin[(size_t)(c0+i)*N_]);
    *(s16x8*)(fb + (size_t)p*C_ + c0) = o8;
  }
}

// ---------------- setup: fused weights (3 x 128^3) + fused biases ----------------
__global__ __launch_bounds__(256) void setup_kernel(const float* __restrict__ W_att1,
    const float* __restrict__ W_pos2, const float* __restrict__ W_q, const float* __restrict__ W_k,
    const float* __restrict__ b_pos2, const float* __restrict__ b_att1,
    const float* __restrict__ b_q, const float* __restrict__ b_k,
    float* __restrict__ Wf, float* __restrict__ Wqa, float* __restrict__ Wka,
    float* __restrict__ bG1, float* __restrict__ bqa, float* __restrict__ bka){
  int bx = blockIdx.x;
  if (bx < 192){
    int which = bx >> 6;
    const float* Bm = which==0 ? W_pos2 : (which==1 ? W_q : W_k);
    float* Cm = which==0 ? Wf : (which==1 ? Wqa : Wka);
    int e = (bx & 63)*256 + threadIdx.x;
    int o = e >> 7, c = e & 127;
    float s = 0.f;
    #pragma unroll 8
    for (int m = 0; m < 128; m++) s += W_att1[o*128+m]*Bm[m*128+c];
    Cm[e] = s;
  } else {
    for (int t = threadIdx.x; t < 384; t += 256){
      int which = t >> 7, o = t & 127;
      const float* v = which==0 ? b_pos2 : (which==1 ? b_q : b_k);
      float* out = which==0 ? bG1 : (which==1 ? bqa : bka);
      float s = which==0 ? b_att1[o] : 0.f;
      for (int m = 0; m < 128; m++) s += W_att1[o*128+m]*v[m];
      out[o] = s;
    }
  }
}

// ---------------- pos_pre group stats (raw conv1 output) ----------------
__global__ __launch_bounds__(256) void pos_stats_kernel(const float4* __restrict__ pt4,
    const int* __restrict__ idx, const float* __restrict__ W1, const float* __restrict__ b1,
    float* __restrict__ gsum, float* __restrict__ gssq){
  __shared__ float ls[G_], lss[G_];
  if (threadIdx.x < G_){ ls[threadIdx.x] = 0.f; lss[threadIdx.x] = 0.f; }
  __syncthreads();
  int p = blockIdx.x*256 + threadIdx.x;
  int b = p >> 17;
  int n = p >> 4;             // global n
  int j = idx[p];
  float4 pj = pt4[(b<<13) + j], pn = pt4[n];
  float rx = pj.x - pn.x, ry = pj.y - pn.y, rz = pj.z - pn.z;
  #pragma unroll
  for (int g = 0; g < G_; g++){
    float s = 0.f, ss = 0.f;
    #pragma unroll
    for (int ci = 0; ci < 16; ci++){
      int c = g*16 + ci;
      float v = b1[c] + W1[3*c]*rx + W1[3*c+1]*ry + W1[3*c+2]*rz;
      s += v; ss += v*v;
    }
    #pragma unroll
    for (int mk = 32; mk; mk >>= 1){ s += __shfl_xor(s, mk, 64); ss += __shfl_xor(ss, mk, 64); }
    if ((threadIdx.x & 63) == 0){ atomicAdd(&ls[g], s); atomicAdd(&lss[g], ss); }
  }
  __syncthreads();
  if (threadIdx.x < G_){
    atomicAdd(&gsum[b*G_ + threadIdx.x], ls[threadIdx.x]);
    atomicAdd(&gssq[b*G_ + threadIdx.x], lss[threadIdx.x]);
  }
}

// ---------------- pos finalize + folded GN params ----------------
__global__ void posfin_kernel(const float* __restrict__ gsum, const float* __restrict__ gssq,
    const float* __restrict__ W1, const float* __restrict__ b1,
    const float* __restrict__ g1, const float* __restrict__ be1, float* __restrict__ prm, float invcnt){
  __shared__ float sm[16], sr[16];
  int i = threadIdx.x;
  if (i < 16){
    float m = gsum[i]*invcnt;
    float v = gssq[i]*invcnt - m*m;
    v = fmaxf(v, 0.f);
    sm[i] = m; sr[i] = rsqrtf(v + EPSV);
  }
  __syncthreads();
  int b = i >> 7, c = i & 127, g = c >> 4;
  float rs = sr[b*G_+g]*g1[c];
  prm[b*512 +   0 + c] = W1[3*c]*rs;
  prm[b*512 + 128 + c] = W1[3*c+1]*rs;
  prm[b*512 + 256 + c] = W1[3*c+2]*rs;
  prm[b*512 + 384 + c] = (b1[c]-sm[b*G_+g])*rs + be1[c];
}

// ---------------- att finalize + folded scale/shift ----------------
__global__ void attfin_kernel(const float* __restrict__ gsum, const float* __restrict__ gssq,
    const float* __restrict__ ga, const float* __restrict__ bea, float* __restrict__ prm, float invcnt){
  __shared__ float sm[16], sr[16];
  int i = threadIdx.x;
  if (i < 16){
    float m = gsum[i]*invcnt;
    float v = gssq[i]*invcnt - m*m;
    v = fmaxf(v, 0.f);
    sm[i] = m; sr[i] = rsqrtf(v + EPSV);
  }
  __syncthreads();
  int b = i >> 7, c = i & 127, g = c >> 4;
  float sc = ga[c]*sr[b*G_+g];
  prm[b*256 +   0 + c] = sc;
  prm[b*256 + 128 + c] = bea[c] - sm[b*G_+g]*sc;
}

// ---------------- unified MFMA GEMM body: Y[o][p] = W*X + bias, 64 pts x 128 out ----------------
#define ST_COPY 0
#define ST_GN   1
#define ST_POS  2
#define EP_PM    0
#define EP_QKS   1
#define EP_F32CM 2

template<int STAGE, int EPI>
__device__ __forceinline__ void mgemm_body(ushort* xs, float* sblk,
    const ushort* __restrict__ Xb, const float* __restrict__ W, const float* __restrict__ bias,
    const float* __restrict__ prm, const float4* __restrict__ pt4, const int* __restrict__ idx,
    const ushort* __restrict__ Aq, const ushort* __restrict__ Ak,
    void* __restrict__ Y, float* __restrict__ gsum, float* __restrict__ gssq, int bsh, int bx)
{
  int tid = threadIdx.x;
  int l = tid & 63, wid = tid >> 6;
  int lm = l & 15, lh = l >> 4;
  int p0 = bx * 64;
  int b = p0 >> bsh;

  if (tid < 16) sblk[tid] = 0.f;

  // A fragments: wave owns out-channels [wid*32, wid*32+32)
  s16x8 afr[2][4];
  #pragma unroll
  for (int t = 0; t < 2; t++){
    int T = wid*2 + t;
    #pragma unroll
    for (int ks = 0; ks < 4; ks++){
      const float* wr = W + (size_t)(T*16 + lm)*C_ + ks*32 + lh*8;
      float4 w0 = *(const float4*)wr;
      float4 w1 = *(const float4*)(wr+4);
      s16x8 a;
      a[0]=f2b(w0.x); a[1]=f2b(w0.y); a[2]=f2b(w0.z); a[3]=f2b(w0.w);
      a[4]=f2b(w1.x); a[5]=f2b(w1.y); a[6]=f2b(w1.z); a[7]=f2b(w1.w);
      afr[t][ks] = a;
    }
  }

  // ---- staging into LDS, swizzled: xs[row][ (slot^(row&7))*8 .. ] ----
  {
    int row = tid & 63, cc = tid >> 6;
    if constexpr (STAGE == ST_COPY){
      const ushort* src = Xb + (size_t)(p0+row)*C_ + cc*32;
      #pragma unroll
      for (int q = 0; q < 4; q++){
        s16x8 v8 = *(const s16x8*)(src + q*8);
        int sl = (cc*4+q) ^ (row&7);
        *(s16x8*)(xs + row*C_ + sl*8) = v8;
      }
    } else if constexpr (STAGE == ST_GN){
      const ushort* src = Xb + (size_t)(p0+row)*C_ + cc*32;
      const float* sc = prm + b*256;
      const float* sh = prm + b*256 + 128;
      #pragma unroll
      for (int q = 0; q < 4; q++){
        s16x8 v8 = *(const s16x8*)(src + q*8);
        s16x8 o8;
        #pragma unroll
        for (int i = 0; i < 8; i++){
          int c = cc*32 + q*8 + i;
          o8[i] = f2b(leakyf(b2f(v8[i])*sc[c] + sh[c]));
        }
        int sl = (cc*4+q) ^ (row&7);
        *(s16x8*)(xs + row*C_ + sl*8) = o8;
      }
    } else { // ST_POS
      int p = p0 + row;
      int ng = p >> 4;
      int j = idx[p];
      float4 pj = pt4[(b<<13) + j], pn = pt4[ng];
      float rx = pj.x - pn.x, ry = pj.y - pn.y, rz = pj.z - pn.z;
      const float* sx = prm + b*512;
      const float* sy = sx + 128;
      const float* sz = sx + 256;
      const float* so = sx + 384;
      #pragma unroll
      for (int q = 0; q < 4; q++){
        s16x8 o8;
        #pragma unroll
        for (int i = 0; i < 8; i++){
          int c = cc*32 + q*8 + i;
          o8[i] = f2b(leakyf(sx[c]*rx + sy[c]*ry + sz[c]*rz + so[c]));
        }
        int sl = (cc*4+q) ^ (row&7);
        *(s16x8*)(xs + row*C_ + sl*8) = o8;
      }
    }
  }
  __syncthreads();

  // ---- compute ----
  f32x4 acc[2][4];
  #pragma unroll
  for (int t = 0; t < 2; t++){
    f32x4 bs = *(const f32x4*)(bias + (wid*2+t)*16 + lh*4);
    #pragma unroll
    for (int ps = 0; ps < 4; ps++) acc[t][ps] = bs;
  }
  #pragma unroll
  for (int ps = 0; ps < 4; ps++){
    int row = ps*16 + lm;
    s16x8 bf[4];
    #pragma unroll
    for (int ks = 0; ks < 4; ks++){
      int sl = (ks*4+lh) ^ (row&7);
      bf[ks] = *(const s16x8*)(xs + row*C_ + sl*8);
    }
    #pragma unroll
    for (int ks = 0; ks < 4; ks++){
      #pragma unroll
      for (int t = 0; t < 2; t++)
        acc[t][ps] = __builtin_amdgcn_mfma_f32_16x16x32_bf16(afr[t][ks], bf[ks], acc[t][ps], 0,0,0);
    }
  }

  // ---- epilogue ----
  float gs[2] = {0.f,0.f}, gq[2] = {0.f,0.f};
  #pragma unroll
  for (int t = 0; t < 2; t++){
    int T = wid*2 + t;
    int o0 = T*16 + lh*4;
    #pragma unroll
    for (int ps = 0; ps < 4; ps++){
      int p = p0 + ps*16 + lm;
      if constexpr (EPI == EP_PM){
        s16x4 r4;
        #pragma unroll
        for (int r = 0; r < 4; r++) r4[r] = f2b(acc[t][ps][r]);
        *(s16x4*)((ushort*)Y + (size_t)p*C_ + o0) = r4;
      } else if constexpr (EPI == EP_QKS){
        int ng = p >> 4;
        int j = idx[p];
        s16x4 aq4 = *(const s16x4*)(Aq + (size_t)ng*C_ + o0);
        s16x4 ak4 = *(const s16x4*)(Ak + ((size_t)(b<<13)+j)*C_ + o0);
        s16x4 r4;
        #pragma unroll
        for (int r = 0; r < 4; r++){
          float v = acc[t][ps][r] + b2f(aq4[r]) - b2f(ak4[r]);
          r4[r] = f2b(v);
          gs[t] += v; gq[t] += v*v;
        }
        *(s16x4*)((ushort*)Y + (size_t)p*C_ + o0) = r4;
      } else { // EP_F32CM
        float* yf = (float*)Y;
        #pragma unroll
        for (int r = 0; r < 4; r++){
          float v = acc[t][ps][r];
          yf[(size_t)(o0+r)*BN_ + p] = v;
          gs[t] += v; gq[t] += v*v;
        }
      }
    }
  }

  if constexpr (EPI == EP_QKS || EPI == EP_F32CM){
    #pragma unroll
    for (int t = 0; t < 2; t++){
      float s = gs[t], q = gq[t];
      #pragma unroll
      for (int mk = 32; mk; mk >>= 1){ s += __shfl_xor(s, mk, 64); q += __shfl_xor(q, mk, 64); }
      if (l == 0){
        int T = wid*2 + t;
        atomicAdd(&sblk[T], s); atomicAdd(&sblk[8+T], q);
      }
    }
    __syncthreads();
    if (tid < 8){
      atomicAdd(&gsum[b*G_ + tid], sblk[tid]);
      atomicAdd(&gssq[b*G_ + tid], sblk[8+tid]);
    }
  }
}

template<int STAGE, int EPI>
__global__ __launch_bounds__(256) void mgemm_kernel(
    const ushort* __restrict__ Xb, const float* __restrict__ W, const float* __restrict__ bias,
    const float* __restrict__ prm, const float4* __restrict__ pt4, const int* __restrict__ idx,
    const ushort* __restrict__ Aq, const ushort* __restrict__ Ak,
    void* __restrict__ Y, float* __restrict__ gsum, float* __restrict__ gssq, int bsh)
{
  __shared__ ushort xs[64*128];
  __shared__ float sblk[16];
  mgemm_body<STAGE,EPI>(xs, sblk, Xb, W, bias, prm, pt4, idx, Aq, Ak, Y, gsum, gssq, bsh, blockIdx.x);
}

// v / Aq / Ak in one launch (gridDim.y = 3)
__global__ __launch_bounds__(256) void qkv_kernel(const ushort* __restrict__ nfb,
    const float* __restrict__ Wv, const float* __restrict__ bv,
    const float* __restrict__ Wqa, const float* __restrict__ bqa,
    const float* __restrict__ Wka, const float* __restrict__ bka,
    ushort* __restrict__ vb, ushort* __restrict__ Aqb, ushort* __restrict__ Akb)
{
  __shared__ ushort xs[64*128];
  __shared__ float sblk[16];
  if (blockIdx.y == 0)
    mgemm_body<ST_COPY,EP_PM>(xs, sblk, nfb, Wv, bv, nullptr, nullptr, nullptr, nullptr, nullptr, vb, nullptr, nullptr, 13, blockIdx.x);
  else if (blockIdx.y == 1)
    mgemm_body<ST_COPY,EP_PM>(xs, sblk, nfb, Wqa, bqa, nullptr, nullptr, nullptr, nullptr, nullptr, Aqb, nullptr, nullptr, 13, blockIdx.x);
  else
    mgemm_body<ST_COPY,EP_PM>(xs, sblk, nfb, Wka, bka, nullptr, nullptr, nullptr, nullptr, nullptr, Akb, nullptr, nullptr, 13, blockIdx.x);
}

// ---------------- att2: softmax over k (no max-sub; logits bounded) + PV + residual ----------------
__global__ __launch_bounds__(256) void att2b_kernel(const ushort* __restrict__ a2s,
    const ushort* __restrict__ vb, const ushort* __restrict__ nfb,
    const int* __restrict__ idx, ushort* __restrict__ outb){
  int tid = blockIdx.x*256 + threadIdx.x;
  int n = tid >> 4;          // global n
  int cc = tid & 15;
  int b = n >> 13;
  const int* ir = idx + (size_t)n*16;
  float sum[8], pv[8];
  #pragma unroll
  for (int i = 0; i < 8; i++){ sum[i] = 0.f; pv[i] = 0.f; }
  const ushort* ab = a2s + (size_t)n*16*C_ + cc*8;
  #pragma unroll
  for (int k = 0; k < 16; k++){
    s16x8 l8 = *(const s16x8*)(ab + k*C_);
    int j = ir[k];
    s16x8 v8 = *(const s16x8*)(vb + ((size_t)(b<<13)+j)*C_ + cc*8);
    #pragma unroll
    for (int i = 0; i < 8; i++){
      float e = __expf(b2f(l8[i]));
      sum[i] += e;
      pv[i] += e*b2f(v8[i]);
    }
  }
  s16x8 n8 = *(const s16x8*)(nfb + (size_t)n*C_ + cc*8);
  s16x8 o8;
  #pragma unroll
  for (int i = 0; i < 8; i++) o8[i] = f2b(pv[i]/sum[i] + b2f(n8[i]));
  *(s16x8*)(outb + (size_t)n*C_ + cc*8) = o8;
}

// ---------------- final: inline post-finalize + GN + leaky (out1 col-major [C][BN]) ----------------
__global__ __launch_bounds__(256) void final_kernel(const float* __restrict__ out1,
    const float* __restrict__ gsum, const float* __restrict__ gssq,
    const float* __restrict__ g, const float* __restrict__ be, float* __restrict__ out){
  int e = blockIdx.x*256 + threadIdx.x;
  int b = e >> 20;
  int c = (e >> 13) & (C_-1);
  int n = e & (N_-1);
  int gi = b*G_ + (c >> 4);
  const float invcnt = 1.0f/(float)(16*N_);
  float m = gsum[gi]*invcnt;
  float var = gssq[gi]*invcnt - m*m;
  var = fmaxf(var, 0.f);
  float r = rsqrtf(var + EPSV);
  float v = (out1[(size_t)c*BN_ + b*N_ + n] - m) * r;
  v = v*g[c] + be[c];
  out[e] = leakyf(v);
}

extern "C" void kernel_launch(void* const* d_in, const int* in_sizes, int n_in,
                              void* d_out, int out_size, void* d_ws, size_t ws_size,
                              hipStream_t stream) {
  const float* xyz    = (const float*)d_in[0];
  const float* feat   = (const float*)d_in[1];
  const float* W_pre  = (const float*)d_in[2];
  const float* b_pre  = (const float*)d_in[3];
  const float* W_pos1 = (const float*)d_in[4];
  const float* b_pos1 = (const float*)d_in[5];
  const float* g_pos1 = (const float*)d_in[6];
  const float* be_pos1= (const float*)d_in[7];
  const float* W_pos2 = (const float*)d_in[8];
  const float* b_pos2 = (const float*)d_in[9];
  const float* W_q    = (const float*)d_in[10];
  const float* b_q    = (const float*)d_in[11];
  const float* W_k    = (const float*)d_in[12];
  const float* b_k    = (const float*)d_in[13];
  const float* W_v    = (const float*)d_in[14];
  const float* b_v    = (const float*)d_in[15];
  const float* W_att1 = (const float*)d_in[16];
  const float* b_att1 = (const float*)d_in[17];
  const float* g_att1 = (const float*)d_in[18];
  const float* be_att1= (const float*)d_in[19];
  const float* W_att2 = (const float*)d_in[20];
  const float* b_att2 = (const float*)d_in[21];
  const float* W_post = (const float*)d_in[22];
  const float* b_post = (const float*)d_in[23];
  const float* g_post = (const float*)d_in[24];
  const float* be_post= (const float*)d_in[25];

  char* w = (char*)d_ws;
  float4* pt4 = (float4*)w;            w += sizeof(float4)*BN_;
  int* idx = (int*)w;                  w += sizeof(int)*BNK_;
  ushort* fb   = (ushort*)w;           w += (size_t)2*BN_*C_;
  ushort* nfb  = (ushort*)w;           w += (size_t)2*BN_*C_;
  ushort* vb   = (ushort*)w;           w += (size_t)2*BN_*C_;
  ushort* Aqb  = (ushort*)w;           w += (size_t)2*BN_*C_;
  ushort* Akb  = (ushort*)w;           w += (size_t)2*BN_*C_;
  ushort* outb = (ushort*)w;           w += (size_t)2*BN_*C_;
  float* out1  = (float*)w;            w += (size_t)4*BN_*C_;
  ushort* bufA = (ushort*)w;           w += (size_t)2*BNK_*C_;           // att1 PM
  ushort* bufB = (ushort*)w;           w += (size_t)2*BNK_*C_;           // a2s PM
  float* Wf    = (float*)w;            w += sizeof(float)*C_*C_;
  float* Wqa   = (float*)w;            w += sizeof(float)*C_*C_;
  float* Wka   = (float*)w;            w += sizeof(float)*C_*C_;
  float* bG1   = (float*)w;            w += 512;
  float* bqa   = (float*)w;            w += 512;
  float* bka   = (float*)w;            w += 512;
  float* posPrm= (float*)w;            w += sizeof(float)*1024;
  float* attPrm= (float*)w;            w += sizeof(float)*512;
  float* stats = (float*)w;            w += 1024;

  float* pos_sum = stats +  0, *pos_ssq = stats + 16;
  float* att_sum = stats + 64, *att_ssq = stats + 80;
  float* post_sum= stats +128, *post_ssq= stats +144;

  hipMemsetAsync(stats, 0, 1024, stream);

  pack_kernel<<<BN_/256, 256, 0, stream>>>(xyz, pt4);
  knn_kernel<<<BN_/(KNN_TPB/64), KNN_TPB, 0, stream>>>(pt4, idx);
  featb_kernel<<<BN_/256, 256, 0, stream>>>(feat, fb);

  // fused weights / biases (one launch)
  setup_kernel<<<193, 256, 0, stream>>>(W_att1, W_pos2, W_q, W_k, b_pos2, b_att1, b_q, b_k,
      Wf, Wqa, Wka, bG1, bqa, bka);

  // nf = W_pre*feat + b
  mgemm_kernel<ST_COPY,EP_PM><<<BN_/64, 256, 0, stream>>>(fb, W_pre, b_pre, nullptr, nullptr, nullptr,
      nullptr, nullptr, nfb, nullptr, nullptr, 13);
  // v, Aq, Ak (one launch)
  qkv_kernel<<<dim3(BN_/64, 3), 256, 0, stream>>>(nfb, W_v, b_v, Wqa, bqa, Wka, bka, vb, Aqb, Akb);

  // pos GN stats -> folded params
  pos_stats_kernel<<<BNK_/256, 256, 0, stream>>>(pt4, idx, W_pos1, b_pos1, pos_sum, pos_ssq);
  posfin_kernel<<<1, 256, 0, stream>>>(pos_sum, pos_ssq, W_pos1, b_pos1, g_pos1, be_pos1, posPrm,
      1.0f/(float)(16.0*NK_));

  // G1: att1 = Wf*posn + bG1 + Aq[n] - Ak[j]  (+ stats)  -> bufA
  mgemm_kernel<ST_POS,EP_QKS><<<BNK_/64, 256, 0, stream>>>(nullptr, Wf, bG1, posPrm, pt4, idx,
      Aqb, Akb, bufA, att_sum, att_ssq, 17);
  attfin_kernel<<<1, 256, 0, stream>>>(att_sum, att_ssq, g_att1, be_att1, attPrm, 1.0f/(float)(16.0*NK_));

  // G2: a2s = W_att2*leaky(GN(att1)) + b  -> bufB
  mgemm_kernel<ST_GN,EP_PM><<<BNK_/64, 256, 0, stream>>>(bufA, W_att2, b_att2, attPrm, nullptr, nullptr,
      nullptr, nullptr, bufB, nullptr, nullptr, 17);

  // softmax + PV + residual
  att2b_kernel<<<BN_*16/256, 256, 0, stream>>>(bufB, vb, nfb, idx, outb);

  // post conv + stats (f32 col-major)
  mgemm_kernel<ST_COPY,EP_F32CM><<<BN_/64, 256, 0, stream>>>(outb, W_post, b_post, nullptr, nullptr, nullptr,
      nullptr, nullptr, out1, post_sum, post_ssq, 13);
  final_kernel<<<(B_*CN_)/256, 256, 0, stream>>>(out1, post_sum, post_ssq, g_post, be_post, (float*)d_out);
}

// Round 7
// 413.051 us; speedup vs baseline: 6.0922x; 1.0432x over previous
//
#include <hip/hip_runtime.h>
#include <hip/hip_bf16.h>
#include <float.h>

#define B_ 2
#define N_ 8192
#define C_ 128
#define K_ 16
#define G_ 8
#define NK_ (N_*K_)     // 131072
#define BN_ (B_*N_)     // 16384
#define BNK_ (B_*NK_)   // 262144
#define CN_ (C_*N_)
#define NEG 0.1f
#define EPSV 1e-5f

typedef __attribute__((ext_vector_type(4))) float f32x4;
typedef __attribute__((ext_vector_type(8))) short s16x8;
typedef __attribute__((ext_vector_type(4))) short s16x4;

__device__ __forceinline__ float leakyf(float x){ return x >= 0.f ? x : NEG*x; }
__device__ __forceinline__ short f2b(float x){
  union { __hip_bfloat16 b; short s; } u; u.b = __float2bfloat16(x); return u.s;
}
__device__ __forceinline__ float b2f(short s){
  union { __hip_bfloat16 b; short s; } u; u.s = s; return __bfloat162float(u.b);
}

// row_shr:1 within 16-lane rows (list lives in lanes 0..15 -> row-local)
__device__ __forceinline__ int dpp_shr1_i(int x){
  return __builtin_amdgcn_update_dpp(x, x, 0x111, 0xF, 0xF, false);
}
__device__ __forceinline__ double dpp_shr1_d(double x){
  union { double d; int i[2]; } u; u.d = x;
  u.i[0] = dpp_shr1_i(u.i[0]);
  u.i[1] = dpp_shr1_i(u.i[1]);
  return u.d;
}
__device__ __forceinline__ double readlane_d(double x, int l){
  union { double d; int i[2]; } u; u.d = x;
  union { double d; int i[2]; } r;
  r.i[0] = __builtin_amdgcn_readlane(u.i[0], l);
  r.i[1] = __builtin_amdgcn_readlane(u.i[1], l);
  return r.d;
}

// ---------------- pack xyz -> float4 (w = |p|^2 fp32, filter only) ----------------
__global__ __launch_bounds__(256) void pack_kernel(const float* __restrict__ xyz, float4* __restrict__ pt4){
  int e = blockIdx.x*256 + threadIdx.x;
  int b = e >> 13, n = e & (N_-1);
  const float* xb = xyz + b*3*N_;
  float x = xb[n], y = xb[N_+n], z = xb[2*N_+n];
  pt4[e] = make_float4(x, y, z, x*x + y*y + z*z);
}

// ---------------- KNN: wave per query, fp32 prefilter + fp64 exact refine ----------------
// Filter fp32 abs error bound < 7.5e-5 (|terms| <= ~225, see round notes); margin 5e-4 = ~7x safety.
#define KNN_TPB 512
#define KNN_CHUNK 2048
#define KNN_MARGIN 5e-4f
__global__ __launch_bounds__(KNN_TPB) void knn_kernel(const float4* __restrict__ pt4, int* __restrict__ idxo){
  __shared__ float4 sp[KNN_CHUNK];
  int lane = threadIdx.x & 63, wid = threadIdx.x >> 6;
  int qg = blockIdx.x*(KNN_TPB/64) + wid;
  int b = qg >> 13, n = qg & (N_-1);
  const float4* pts = pt4 + b*N_;
  float4 qp = pts[n];
  double qx = qp.x, qy = qp.y, qz = qp.z;
  double qsq = qx*qx + qy*qy + qz*qz;
  float qx2 = -2.f*qp.x, qy2 = -2.f*qp.y, qz2 = -2.f*qp.z;
  double myd = DBL_MAX; int myi = 0x7fffffff;     // lanes 0..15: sorted top-16
  float cmpv = FLT_MAX;                            // (float)(thr - qsq) + margin

  // Insertion ballot bm==0 <=> candidate does not beat current 16th (lane 15),
  // so no separate thr guard is needed; all ordering decisions are exact fp64.
  auto process = [&](unsigned long long m, double d2v, int base){
    while (m){
      int src = __ffsll(m) - 1; m &= m - 1;
      double dn = readlane_d(d2v, src);
      int in_ = base + src;
      bool less = (dn < myd) || (dn == myd && in_ < myi);
      unsigned long long bm = __ballot(less) & 0xFFFFull;
      if (bm){
        int pos = __ffsll(bm) - 1;
        double pd = dpp_shr1_d(myd);
        int pi = dpp_shr1_i(myi);
        if (lane < 16){
          if (lane > pos){ myd = pd; myi = pi; }
          else if (lane == pos){ myd = dn; myi = in_; }
        }
      }
    }
  };

  for (int c0 = 0; c0 < N_; c0 += KNN_CHUNK){
    __syncthreads();
    #pragma unroll
    for (int t = 0; t < KNN_CHUNK/KNN_TPB; t++){
      int i = t*KNN_TPB + threadIdx.x;
      sp[i] = pts[c0 + i];
    }
    __syncthreads();
    for (int j0 = 0; j0 < KNN_CHUNK; j0 += 128){
      float4 pA = sp[j0 + lane];
      float4 pB = sp[j0 + 64 + lane];
      float fA = fmaf(pA.x, qx2, fmaf(pA.y, qy2, fmaf(pA.z, qz2, pA.w)));
      float fB = fmaf(pB.x, qx2, fmaf(pB.y, qy2, fmaf(pB.z, qz2, pB.w)));
      unsigned long long mA = __ballot(fA < cmpv);
      unsigned long long mB = __ballot(fB < cmpv);
      if (mA | mB){
        if (mA){
          double px = pA.x, py = pA.y, pz = pA.z;
          double psq = px*px + py*py + pz*pz;
          double dot = qx*px + qy*py + qz*pz;
          double d2 = qsq + psq - 2.0*dot;
          process(mA, d2, c0 + j0);
        }
        if (mB){
          double px = pB.x, py = pB.y, pz = pB.z;
          double psq = px*px + py*py + pz*pz;
          double dot = qx*px + qy*py + qz*pz;
          double d2 = qsq + psq - 2.0*dot;
          process(mB, d2, c0 + j0 + 64);
        }
        // refresh conservative fp32 filter threshold once per survivor-group
        double thr = readlane_d(myd, 15);
        cmpv = (float)(thr - qsq) + KNN_MARGIN;
      }
    }
  }
  if (lane < 16) idxo[qg*K_ + lane] = myi;
}

// ---------------- feat -> bf16 point-major ----------------
__global__ __launch_bounds__(256) void featb_kernel(const float* __restrict__ feat, ushort* __restrict__ fb){
  int p = blockIdx.x*256 + threadIdx.x;
  int b = p >> 13, n = p & (N_-1);
  const float* xin = feat + b*CN_ + n;
  #pragma unroll
  for (int c0 = 0; c0 < C_; c0 += 8){
    s16x8 o8;
    #pragma unroll
    for (int i = 0; i < 8; i++) o8[i] = f2b(xin[(size_t)(c0+i)*N_]);
    *(s16x8*)(fb + (size_t)p*C_ + c0) = o8;
  }
}

// ---------------- setup: fused weights (3 x 128^3) + fused biases ----------------
__global__ __launch_bounds__(256) void setup_kernel(const float* __restrict__ W_att1,
    const float* __restrict__ W_pos2, const float* __restrict__ W_q, const float* __restrict__ W_k,
    const float* __restrict__ b_pos2, const float* __restrict__ b_att1,
    const float* __restrict__ b_q, const float* __restrict__ b_k,
    float* __restrict__ Wf, float* __restrict__ Wqa, float* __restrict__ Wka,
    float* __restrict__ bG1, float* __restrict__ bqa, float* __restrict__ bka){
  int bx = blockIdx.x;
  if (bx < 192){
    int which = bx >> 6;
    const float* Bm = which==0 ? W_pos2 : (which==1 ? W_q : W_k);
    float* Cm = which==0 ? Wf : (which==1 ? Wqa : Wka);
    int e = (bx & 63)*256 + threadIdx.x;
    int o = e >> 7, c = e & 127;
    float s = 0.f;
    #pragma unroll 8
    for (int m = 0; m < 128; m++) s += W_att1[o*128+m]*Bm[m*128+c];
    Cm[e] = s;
  } else {
    for (int t = threadIdx.x; t < 384; t += 256){
      int which = t >> 7, o = t & 127;
      const float* v = which==0 ? b_pos2 : (which==1 ? b_q : b_k);
      float* out = which==0 ? bG1 : (which==1 ? bqa : bka);
      float s = which==0 ? b_att1[o] : 0.f;
      for (int m = 0; m < 128; m++) s += W_att1[o*128+m]*v[m];
      out[o] = s;
    }
  }
}

// ---------------- pos_pre group stats (raw conv1 output) ----------------
__global__ __launch_bounds__(256) void pos_stats_kernel(const float4* __restrict__ pt4,
    const int* __restrict__ idx, const float* __restrict__ W1, const float* __restrict__ b1,
    float* __restrict__ gsum, float* __restrict__ gssq){
  __shared__ float ls[G_], lss[G_];
  if (threadIdx.x < G_){ ls[threadIdx.x] = 0.f; lss[threadIdx.x] = 0.f; }
  __syncthreads();
  int p = blockIdx.x*256 + threadIdx.x;
  int b = p >> 17;
  int n = p >> 4;             // global n
  int j = idx[p];
  float4 pj = pt4[(b<<13) + j], pn = pt4[n];
  float rx = pj.x - pn.x, ry = pj.y - pn.y, rz = pj.z - pn.z;
  #pragma unroll
  for (int g = 0; g < G_; g++){
    float s = 0.f, ss = 0.f;
    #pragma unroll
    for (int ci = 0; ci < 16; ci++){
      int c = g*16 + ci;
      float v = b1[c] + W1[3*c]*rx + W1[3*c+1]*ry + W1[3*c+2]*rz;
      s += v; ss += v*v;
    }
    #pragma unroll
    for (int mk = 32; mk; mk >>= 1){ s += __shfl_xor(s, mk, 64); ss += __shfl_xor(ss, mk, 64); }
    if ((threadIdx.x & 63) == 0){ atomicAdd(&ls[g], s); atomicAdd(&lss[g], ss); }
  }
  __syncthreads();
  if (threadIdx.x < G_){
    atomicAdd(&gsum[b*G_ + threadIdx.x], ls[threadIdx.x]);
    atomicAdd(&gssq[b*G_ + threadIdx.x], lss[threadIdx.x]);
  }
}

// ---------------- pos finalize + folded GN params ----------------
__global__ void posfin_kernel(const float* __restrict__ gsum, const float* __restrict__ gssq,
    const float* __restrict__ W1, const float* __restrict__ b1,
    const float* __restrict__ g1, const float* __restrict__ be1, float* __restrict__ prm, float invcnt){
  __shared__ float sm[16], sr[16];
  int i = threadIdx.x;
  if (i < 16){
    float m = gsum[i]*invcnt;
    float v = gssq[i]*invcnt - m*m;
    v = fmaxf(v, 0.f);
    sm[i] = m; sr[i] = rsqrtf(v + EPSV);
  }
  __syncthreads();
  int b = i >> 7, c = i & 127, g = c >> 4;
  float rs = sr[b*G_+g]*g1[c];
  prm[b*512 +   0 + c] = W1[3*c]*rs;
  prm[b*512 + 128 + c] = W1[3*c+1]*rs;
  prm[b*512 + 256 + c] = W1[3*c+2]*rs;
  prm[b*512 + 384 + c] = (b1[c]-sm[b*G_+g])*rs + be1[c];
}

// ---------------- att finalize + folded scale/shift ----------------
__global__ void attfin_kernel(const float* __restrict__ gsum, const float* __restrict__ gssq,
    const float* __restrict__ ga, const float* __restrict__ bea, float* __restrict__ prm, float invcnt){
  __shared__ float sm[16], sr[16];
  int i = threadIdx.x;
  if (i < 16){
    float m = gsum[i]*invcnt;
    float v = gssq[i]*invcnt - m*m;
    v = fmaxf(v, 0.f);
    sm[i] = m; sr[i] = rsqrtf(v + EPSV);
  }
  __syncthreads();
  int b = i >> 7, c = i & 127, g = c >> 4;
  float sc = ga[c]*sr[b*G_+g];
  prm[b*256 +   0 + c] = sc;
  prm[b*256 + 128 + c] = bea[c] - sm[b*G_+g]*sc;
}

// ---------------- unified MFMA GEMM body: Y[o][p] = W*X + bias, 64 pts x 128 out ----------------
#define ST_COPY 0
#define ST_GN   1
#define ST_POS  2
#define EP_PM    0
#define EP_QKS   1
#define EP_F32CM 2

template<int STAGE, int EPI>
__device__ __forceinline__ void mgemm_body(ushort* xs, float* sblk,
    const ushort* __restrict__ Xb, const float* __restrict__ W, const float* __restrict__ bias,
    const float* __restrict__ prm, const float4* __restrict__ pt4, const int* __restrict__ idx,
    const ushort* __restrict__ Aq, const ushort* __restrict__ Ak,
    void* __restrict__ Y, float* __restrict__ gsum, float* __restrict__ gssq, int bsh, int bx)
{
  int tid = threadIdx.x;
  int l = tid & 63, wid = tid >> 6;
  int lm = l & 15, lh = l >> 4;
  int p0 = bx * 64;
  int b = p0 >> bsh;

  if (tid < 16) sblk[tid] = 0.f;

  // A fragments: wave owns out-channels [wid*32, wid*32+32)
  s16x8 afr[2][4];
  #pragma unroll
  for (int t = 0; t < 2; t++){
    int T = wid*2 + t;
    #pragma unroll
    for (int ks = 0; ks < 4; ks++){
      const float* wr = W + (size_t)(T*16 + lm)*C_ + ks*32 + lh*8;
      float4 w0 = *(const float4*)wr;
      float4 w1 = *(const float4*)(wr+4);
      s16x8 a;
      a[0]=f2b(w0.x); a[1]=f2b(w0.y); a[2]=f2b(w0.z); a[3]=f2b(w0.w);
      a[4]=f2b(w1.x); a[5]=f2b(w1.y); a[6]=f2b(w1.z); a[7]=f2b(w1.w);
      afr[t][ks] = a;
    }
  }

  // ---- staging into LDS, swizzled: xs[row][ (slot^(row&7))*8 .. ] ----
  {
    int row = tid & 63, cc = tid >> 6;
    if constexpr (STAGE == ST_COPY){
      const ushort* src = Xb + (size_t)(p0+row)*C_ + cc*32;
      #pragma unroll
      for (int q = 0; q < 4; q++){
        s16x8 v8 = *(const s16x8*)(src + q*8);
        int sl = (cc*4+q) ^ (row&7);
        *(s16x8*)(xs + row*C_ + sl*8) = v8;
      }
    } else if constexpr (STAGE == ST_GN){
      const ushort* src = Xb + (size_t)(p0+row)*C_ + cc*32;
      const float* sc = prm + b*256;
      const float* sh = prm + b*256 + 128;
      #pragma unroll
      for (int q = 0; q < 4; q++){
        s16x8 v8 = *(const s16x8*)(src + q*8);
        s16x8 o8;
        #pragma unroll
        for (int i = 0; i < 8; i++){
          int c = cc*32 + q*8 + i;
          o8[i] = f2b(leakyf(b2f(v8[i])*sc[c] + sh[c]));
        }
        int sl = (cc*4+q) ^ (row&7);
        *(s16x8*)(xs + row*C_ + sl*8) = o8;
      }
    } else { // ST_POS
      int p = p0 + row;
      int ng = p >> 4;
      int j = idx[p];
      float4 pj = pt4[(b<<13) + j], pn = pt4[ng];
      float rx = pj.x - pn.x, ry = pj.y - pn.y, rz = pj.z - pn.z;
      const float* sx = prm + b*512;
      const float* sy = sx + 128;
      const float* sz = sx + 256;
      const float* so = sx + 384;
      #pragma unroll
      for (int q = 0; q < 4; q++){
        s16x8 o8;
        #pragma unroll
        for (int i = 0; i < 8; i++){
          int c = cc*32 + q*8 + i;
          o8[i] = f2b(leakyf(sx[c]*rx + sy[c]*ry + sz[c]*rz + so[c]));
        }
        int sl = (cc*4+q) ^ (row&7);
        *(s16x8*)(xs + row*C_ + sl*8) = o8;
      }
    }
  }
  __syncthreads();

  // ---- compute ----
  f32x4 acc[2][4];
  #pragma unroll
  for (int t = 0; t < 2; t++){
    f32x4 bs = *(const f32x4*)(bias + (wid*2+t)*16 + lh*4);
    #pragma unroll
    for (int ps = 0; ps < 4; ps++) acc[t][ps] = bs;
  }
  #pragma unroll
  for (int ps = 0; ps < 4; ps++){
    int row = ps*16 + lm;
    s16x8 bf[4];
    #pragma unroll
    for (int ks = 0; ks < 4; ks++){
      int sl = (ks*4+lh) ^ (row&7);
      bf[ks] = *(const s16x8*)(xs + row*C_ + sl*8);
    }
    #pragma unroll
    for (int ks = 0; ks < 4; ks++){
      #pragma unroll
      for (int t = 0; t < 2; t++)
        acc[t][ps] = __builtin_amdgcn_mfma_f32_16x16x32_bf16(afr[t][ks], bf[ks], acc[t][ps], 0,0,0);
    }
  }

  // ---- epilogue ----
  float gs[2] = {0.f,0.f}, gq[2] = {0.f,0.f};
  #pragma unroll
  for (int t = 0; t < 2; t++){
    int T = wid*2 + t;
    int o0 = T*16 + lh*4;
    #pragma unroll
    for (int ps = 0; ps < 4; ps++){
      int p = p0 + ps*16 + lm;
      if constexpr (EPI == EP_PM){
        s16x4 r4;
        #pragma unroll
        for (int r = 0; r < 4; r++) r4[r] = f2b(acc[t][ps][r]);
        *(s16x4*)((ushort*)Y + (size_t)p*C_ + o0) = r4;
      } else if constexpr (EPI == EP_QKS){
        int ng = p >> 4;
        int j = idx[p];
        s16x4 aq4 = *(const s16x4*)(Aq + (size_t)ng*C_ + o0);
        s16x4 ak4 = *(const s16x4*)(Ak + ((size_t)(b<<13)+j)*C_ + o0);
        s16x4 r4;
        #pragma unroll
        for (int r = 0; r < 4; r++){
          float v = acc[t][ps][r] + b2f(aq4[r]) - b2f(ak4[r]);
          r4[r] = f2b(v);
          gs[t] += v; gq[t] += v*v;
        }
        *(s16x4*)((ushort*)Y + (size_t)p*C_ + o0) = r4;
      } else { // EP_F32CM
        float* yf = (float*)Y;
        #pragma unroll
        for (int r = 0; r < 4; r++){
          float v = acc[t][ps][r];
          yf[(size_t)(o0+r)*BN_ + p] = v;
          gs[t] += v; gq[t] += v*v;
        }
      }
    }
  }

  if constexpr (EPI == EP_QKS || EPI == EP_F32CM){
    #pragma unroll
    for (int t = 0; t < 2; t++){
      float s = gs[t], q = gq[t];
      #pragma unroll
      for (int mk = 32; mk; mk >>= 1){ s += __shfl_xor(s, mk, 64); q += __shfl_xor(q, mk, 64); }
      if (l == 0){
        int T = wid*2 + t;
        atomicAdd(&sblk[T], s); atomicAdd(&sblk[8+T], q);
      }
    }
    __syncthreads();
    if (tid < 8){
      atomicAdd(&gsum[b*G_ + tid], sblk[tid]);
      atomicAdd(&gssq[b*G_ + tid], sblk[8+tid]);
    }
  }
}

template<int STAGE, int EPI>
__global__ __launch_bounds__(256) void mgemm_kernel(
    const ushort* __restrict__ Xb, const float* __restrict__ W, const float* __restrict__ bias,
    const float* __restrict__ prm, const float4* __restrict__ pt4, const int* __restrict__ idx,
    const ushort* __restrict__ Aq, const ushort* __restrict__ Ak,
    void* __restrict__ Y, float* __restrict__ gsum, float* __restrict__ gssq, int bsh)
{
  __shared__ ushort xs[64*128];
  __shared__ float sblk[16];
  mgemm_body<STAGE,EPI>(xs, sblk, Xb, W, bias, prm, pt4, idx, Aq, Ak, Y, gsum, gssq, bsh, blockIdx.x);
}

// v / Aq / Ak in one launch (gridDim.y = 3)
__global__ __launch_bounds__(256) void qkv_kernel(const ushort* __restrict__ nfb,
    const float* __restrict__ Wv, const float* __restrict__ bv,
    const float* __restrict__ Wqa, const float* __restrict__ bqa,
    const float* __restrict__ Wka, const float* __restrict__ bka,
    ushort* __restrict__ vb, ushort* __restrict__ Aqb, ushort* __restrict__ Akb)
{
  __shared__ ushort xs[64*128];
  __shared__ float sblk[16];
  if (blockIdx.y == 0)
    mgemm_body<ST_COPY,EP_PM>(xs, sblk, nfb, Wv, bv, nullptr, nullptr, nullptr, nullptr, nullptr, vb, nullptr, nullptr, 13, blockIdx.x);
  else if (blockIdx.y == 1)
    mgemm_body<ST_COPY,EP_PM>(xs, sblk, nfb, Wqa, bqa, nullptr, nullptr, nullptr, nullptr, nullptr, Aqb, nullptr, nullptr, 13, blockIdx.x);
  else
    mgemm_body<ST_COPY,EP_PM>(xs, sblk, nfb, Wka, bka, nullptr, nullptr, nullptr, nullptr, nullptr, Akb, nullptr, nullptr, 13, blockIdx.x);
}

// ---------------- att2: softmax over k (no max-sub; logits bounded) + PV + residual ----------------
__global__ __launch_bounds__(256) void att2b_kernel(const ushort* __restrict__ a2s,
    const ushort* __restrict__ vb, const ushort* __restrict__ nfb,
    const int* __restrict__ idx, ushort* __restrict__ outb){
  int tid = blockIdx.x*256 + threadIdx.x;
  int n = tid >> 4;          // global n
  int cc = tid & 15;
  int b = n >> 13;
  const int* ir = idx + (size_t)n*16;
  float sum[8], pv[8];
  #pragma unroll
  for (int i = 0; i < 8; i++){ sum[i] = 0.f; pv[i] = 0.f; }
  const ushort* ab = a2s + (size_t)n*16*C_ + cc*8;
  #pragma unroll
  for (int k = 0; k < 16; k++){
    s16x8 l8 = *(const s16x8*)(ab + k*C_);
    int j = ir[k];
    s16x8 v8 = *(const s16x8*)(vb + ((size_t)(b<<13)+j)*C_ + cc*8);
    #pragma unroll
    for (int i = 0; i < 8; i++){
      float e = __expf(b2f(l8[i]));
      sum[i] += e;
      pv[i] += e*b2f(v8[i]);
    }
  }
  s16x8 n8 = *(const s16x8*)(nfb + (size_t)n*C_ + cc*8);
  s16x8 o8;
  #pragma unroll
  for (int i = 0; i < 8; i++) o8[i] = f2b(pv[i]/sum[i] + b2f(n8[i]));
  *(s16x8*)(outb + (size_t)n*C_ + cc*8) = o8;
}

// ---------------- final: inline post-finalize + GN + leaky (out1 col-major [C][BN]) ----------------
__global__ __launch_bounds__(256) void final_kernel(const float* __restrict__ out1,
    const float* __restrict__ gsum, const float* __restrict__ gssq,
    const float* __restrict__ g, const float* __restrict__ be, float* __restrict__ out){
  int e = blockIdx.x*256 + threadIdx.x;
  int b = e >> 20;
  int c = (e >> 13) & (C_-1);
  int n = e & (N_-1);
  int gi = b*G_ + (c >> 4);
  const float invcnt = 1.0f/(float)(16*N_);
  float m = gsum[gi]*invcnt;
  float var = gssq[gi]*invcnt - m*m;
  var = fmaxf(var, 0.f);
  float r = rsqrtf(var + EPSV);
  float v = (out1[(size_t)c*BN_ + b*N_ + n] - m) * r;
  v = v*g[c] + be[c];
  out[e] = leakyf(v);
}

extern "C" void kernel_launch(void* const* d_in, const int* in_sizes, int n_in,
                              void* d_out, int out_size, void* d_ws, size_t ws_size,
                              hipStream_t stream) {
  const float* xyz    = (const float*)d_in[0];
  const float* feat   = (const float*)d_in[1];
  const float* W_pre  = (const float*)d_in[2];
  const float* b_pre  = (const float*)d_in[3];
  const float* W_pos1 = (const float*)d_in[4];
  const float* b_pos1 = (const float*)d_in[5];
  const float* g_pos1 = (const float*)d_in[6];
  const float* be_pos1= (const float*)d_in[7];
  const float* W_pos2 = (const float*)d_in[8];
  const float* b_pos2 = (const float*)d_in[9];
  const float* W_q    = (const float*)d_in[10];
  const float* b_q    = (const float*)d_in[11];
  const float* W_k    = (const float*)d_in[12];
  const float* b_k    = (const float*)d_in[13];
  const float* W_v    = (const float*)d_in[14];
  const float* b_v    = (const float*)d_in[15];
  const float* W_att1 = (const float*)d_in[16];
  const float* b_att1 = (const float*)d_in[17];
  const float* g_att1 = (const float*)d_in[18];
  const float* be_att1= (const float*)d_in[19];
  const float* W_att2 = (const float*)d_in[20];
  const float* b_att2 = (const float*)d_in[21];
  const float* W_post = (const float*)d_in[22];
  const float* b_post = (const float*)d_in[23];
  const float* g_post = (const float*)d_in[24];
  const float* be_post= (const float*)d_in[25];

  char* w = (char*)d_ws;
  float4* pt4 = (float4*)w;            w += sizeof(float4)*BN_;
  int* idx = (int*)w;                  w += sizeof(int)*BNK_;
  ushort* fb   = (ushort*)w;           w += (size_t)2*BN_*C_;
  ushort* nfb  = (ushort*)w;           w += (size_t)2*BN_*C_;
  ushort* vb   = (ushort*)w;           w += (size_t)2*BN_*C_;
  ushort* Aqb  = (ushort*)w;           w += (size_t)2*BN_*C_;
  ushort* Akb  = (ushort*)w;           w += (size_t)2*BN_*C_;
  ushort* outb = (ushort*)w;           w += (size_t)2*BN_*C_;
  float* out1  = (float*)w;            w += (size_t)4*BN_*C_;
  ushort* bufA = (ushort*)w;           w += (size_t)2*BNK_*C_;           // att1 PM
  ushort* bufB = (ushort*)w;           w += (size_t)2*BNK_*C_;           // a2s PM
  float* Wf    = (float*)w;            w += sizeof(float)*C_*C_;
  float* Wqa   = (float*)w;            w += sizeof(float)*C_*C_;
  float* Wka   = (float*)w;            w += sizeof(float)*C_*C_;
  float* bG1   = (float*)w;            w += 512;
  float* bqa   = (float*)w;            w += 512;
  float* bka   = (float*)w;            w += 512;
  float* posPrm= (float*)w;            w += sizeof(float)*1024;
  float* attPrm= (float*)w;            w += sizeof(float)*512;
  float* stats = (float*)w;            w += 1024;

  float* pos_sum = stats +  0, *pos_ssq = stats + 16;
  float* att_sum = stats + 64, *att_ssq = stats + 80;
  float* post_sum= stats +128, *post_ssq= stats +144;

  hipMemsetAsync(stats, 0, 1024, stream);

  pack_kernel<<<BN_/256, 256, 0, stream>>>(xyz, pt4);
  knn_kernel<<<BN_/(KNN_TPB/64), KNN_TPB, 0, stream>>>(pt4, idx);
  featb_kernel<<<BN_/256, 256, 0, stream>>>(feat, fb);

  // fused weights / biases (one launch)
  setup_kernel<<<193, 256, 0, stream>>>(W_att1, W_pos2, W_q, W_k, b_pos2, b_att1, b_q, b_k,
      Wf, Wqa, Wka, bG1, bqa, bka);

  // nf = W_pre*feat + b
  mgemm_kernel<ST_COPY,EP_PM><<<BN_/64, 256, 0, stream>>>(fb, W_pre, b_pre, nullptr, nullptr, nullptr,
      nullptr, nullptr, nfb, nullptr, nullptr, 13);
  // v, Aq, Ak (one launch)
  qkv_kernel<<<dim3(BN_/64, 3), 256, 0, stream>>>(nfb, W_v, b_v, Wqa, bqa, Wka, bka, vb, Aqb, Akb);

  // pos GN stats -> folded params
  pos_stats_kernel<<<BNK_/256, 256, 0, stream>>>(pt4, idx, W_pos1, b_pos1, pos_sum, pos_ssq);
  posfin_kernel<<<1, 256, 0, stream>>>(pos_sum, pos_ssq, W_pos1, b_pos1, g_pos1, be_pos1, posPrm,
      1.0f/(float)(16.0*NK_));

  // G1: att1 = Wf*posn + bG1 + Aq[n] - Ak[j]  (+ stats)  -> bufA
  mgemm_kernel<ST_POS,EP_QKS><<<BNK_/64, 256, 0, stream>>>(nullptr, Wf, bG1, posPrm, pt4, idx,
      Aqb, Akb, bufA, att_sum, att_ssq, 17);
  attfin_kernel<<<1, 256, 0, stream>>>(att_sum, att_ssq, g_att1, be_att1, attPrm, 1.0f/(float)(16.0*NK_));

  // G2: a2s = W_att2*leaky(GN(att1)) + b  -> bufB
  mgemm_kernel<ST_GN,EP_PM><<<BNK_/64, 256, 0, stream>>>(bufA, W_att2, b_att2, attPrm, nullptr, nullptr,
      nullptr, nullptr, bufB, nullptr, nullptr, 17);

  // softmax + PV + residual
  att2b_kernel<<<BN_*16/256, 256, 0, stream>>>(bufB, vb, nfb, idx, outb);

  // post conv + stats (f32 col-major)
  mgemm_kernel<ST_COPY,EP_F32CM><<<BN_/64, 256, 0, stream>>>(outb, W_post, b_post, nullptr, nullptr, nullptr,
      nullptr, nullptr, out1, post_sum, post_ssq, 13);
  final_kernel<<<(B_*CN_)/256, 256, 0, stream>>>(out1, post_sum, post_ssq, g_post, be_post, (float*)d_out);
}

// Round 8
// 368.423 us; speedup vs baseline: 6.8302x; 1.1211x over previous
//
#include <hip/hip_runtime.h>
#include <hip/hip_bf16.h>
#include <float.h>

#define B_ 2
#define N_ 8192
#define C_ 128
#define K_ 16
#define G_ 8
#define NK_ (N_*K_)     // 131072
#define BN_ (B_*N_)     // 16384
#define BNK_ (B_*NK_)   // 262144
#define CN_ (C_*N_)
#define NEG 0.1f
#define EPSV 1e-5f

typedef __attribute__((ext_vector_type(4))) float f32x4;
typedef __attribute__((ext_vector_type(8))) short s16x8;
typedef __attribute__((ext_vector_type(4))) short s16x4;

__device__ __forceinline__ float leakyf(float x){ return x >= 0.f ? x : NEG*x; }
__device__ __forceinline__ short f2b(float x){
  union { __hip_bfloat16 b; short s; } u; u.b = __float2bfloat16(x); return u.s;
}
__device__ __forceinline__ float b2f(short s){
  union { __hip_bfloat16 b; short s; } u; u.s = s; return __bfloat162float(u.b);
}

// row_shr:1 within 16-lane rows (list lives in lanes 0..15 -> row-local)
__device__ __forceinline__ int dpp_shr1_i(int x){
  return __builtin_amdgcn_update_dpp(x, x, 0x111, 0xF, 0xF, false);
}
__device__ __forceinline__ double dpp_shr1_d(double x){
  union { double d; int i[2]; } u; u.d = x;
  u.i[0] = dpp_shr1_i(u.i[0]);
  u.i[1] = dpp_shr1_i(u.i[1]);
  return u.d;
}
__device__ __forceinline__ double readlane_d(double x, int l){
  union { double d; int i[2]; } u; u.d = x;
  union { double d; int i[2]; } r;
  r.i[0] = __builtin_amdgcn_readlane(u.i[0], l);
  r.i[1] = __builtin_amdgcn_readlane(u.i[1], l);
  return r.d;
}

// ---------------- pack xyz -> float4 (w = |p|^2 fp32, filter only) ----------------
__global__ __launch_bounds__(256) void pack_kernel(const float* __restrict__ xyz, float4* __restrict__ pt4){
  int e = blockIdx.x*256 + threadIdx.x;
  int b = e >> 13, n = e & (N_-1);
  const float* xb = xyz + b*3*N_;
  float x = xb[n], y = xb[N_+n], z = xb[2*N_+n];
  pt4[e] = make_float4(x, y, z, x*x + y*y + z*z);
}

// ---------------- KNN: wave per query, fp32 prefilter + fp64 exact refine ----------------
// Filter fp32 abs error bound < 7.5e-5; margin 2e-4 = ~2.7x safety.
#define KNN_TPB 512
#define KNN_CHUNK 2048
#define KNN_MARGIN 2e-4f
__global__ __launch_bounds__(KNN_TPB) void knn_kernel(const float4* __restrict__ pt4, int* __restrict__ idxo){
  __shared__ float4 sp[KNN_CHUNK];
  int lane = threadIdx.x & 63, wid = threadIdx.x >> 6;
  int qg = blockIdx.x*(KNN_TPB/64) + wid;
  int b = qg >> 13, n = qg & (N_-1);
  const float4* pts = pt4 + b*N_;
  float4 qp = pts[n];
  double qx = qp.x, qy = qp.y, qz = qp.z;
  double qsq = qx*qx + qy*qy + qz*qz;
  float qx2 = -2.f*qp.x, qy2 = -2.f*qp.y, qz2 = -2.f*qp.z;
  double myd; int myi;
  float cmpv;

  // ---- warmup: exact top-16 of first 64 candidates via 64-lane bitonic sort ----
  {
    float4 pp = pts[lane];
    double px = pp.x, py = pp.y, pz = pp.z;
    double psq = px*px + py*py + pz*pz;
    double dot = qx*px + qy*py + qz*pz;
    double d2l = qsq + psq - 2.0*dot;
    int il = lane;
    #pragma unroll
    for (int k2 = 2; k2 <= 64; k2 <<= 1){
      #pragma unroll
      for (int mm = k2>>1; mm > 0; mm >>= 1){
        double pd = __shfl_xor(d2l, mm, 64);
        int pi = __shfl_xor(il, mm, 64);
        bool up = ((lane & k2) == 0);
        bool lower = ((lane & mm) == 0);
        bool myLess = (d2l < pd) || (d2l == pd && il < pi);
        bool keep = lower ? (up ? myLess : !myLess) : (up ? !myLess : myLess);
        if (!keep){ d2l = pd; il = pi; }
      }
    }
    myd = d2l; myi = il;       // lanes 0..15 hold sorted top-16; higher lanes never read
    double thr0 = readlane_d(myd, 15);
    cmpv = (float)(thr0 - qsq) + KNN_MARGIN;
  }

  // Insertion ballot bm==0 <=> candidate does not beat current 16th (lane 15).
  auto process = [&](unsigned long long m, double d2v, int base){
    while (m){
      int src = __ffsll(m) - 1; m &= m - 1;
      double dn = readlane_d(d2v, src);
      int in_ = base + src;
      bool less = (dn < myd) || (dn == myd && in_ < myi);
      unsigned long long bm = __ballot(less) & 0xFFFFull;
      if (bm){
        int pos = __ffsll(bm) - 1;
        double pd = dpp_shr1_d(myd);
        int pi = dpp_shr1_i(myi);
        if (lane < 16){
          if (lane > pos){ myd = pd; myi = pi; }
          else if (lane == pos){ myd = dn; myi = in_; }
        }
      }
    }
  };

  for (int c0 = 0; c0 < N_; c0 += KNN_CHUNK){
    __syncthreads();
    #pragma unroll
    for (int t = 0; t < KNN_CHUNK/KNN_TPB; t++){
      int i = t*KNN_TPB + threadIdx.x;
      sp[i] = pts[c0 + i];
    }
    __syncthreads();
    for (int j0 = 0; j0 < KNN_CHUNK; j0 += 128){
      float4 pA = sp[j0 + lane];
      float4 pB = sp[j0 + 64 + lane];
      float fA = fmaf(pA.x, qx2, fmaf(pA.y, qy2, fmaf(pA.z, qz2, pA.w)));
      float fB = fmaf(pB.x, qx2, fmaf(pB.y, qy2, fmaf(pB.z, qz2, pB.w)));
      unsigned long long mA = __ballot(fA < cmpv);
      unsigned long long mB = __ballot(fB < cmpv);
      if (c0 == 0 && j0 == 0) mA = 0;     // first 64 handled in warmup
      if (mA | mB){
        if (mA){
          double px = pA.x, py = pA.y, pz = pA.z;
          double psq = px*px + py*py + pz*pz;
          double dot = qx*px + qy*py + qz*pz;
          double d2 = qsq + psq - 2.0*dot;
          process(mA, d2, c0 + j0);
        }
        if (mB){
          double px = pB.x, py = pB.y, pz = pB.z;
          double psq = px*px + py*py + pz*pz;
          double dot = qx*px + qy*py + qz*pz;
          double d2 = qsq + psq - 2.0*dot;
          process(mB, d2, c0 + j0 + 64);
        }
        double thr = readlane_d(myd, 15);
        cmpv = (float)(thr - qsq) + KNN_MARGIN;
      }
    }
  }
  if (lane < 16) idxo[qg*K_ + lane] = myi;
}

// ---------------- feat -> bf16 point-major ----------------
__global__ __launch_bounds__(256) void featb_kernel(const float* __restrict__ feat, ushort* __restrict__ fb){
  int p = blockIdx.x*256 + threadIdx.x;
  int b = p >> 13, n = p & (N_-1);
  const float* xin = feat + b*CN_ + n;
  #pragma unroll
  for (int c0 = 0; c0 < C_; c0 += 8){
    s16x8 o8;
    #pragma unroll
    for (int i = 0; i < 8; i++) o8[i] = f2b(xin[(size_t)(c0+i)*N_]);
    *(s16x8*)(fb + (size_t)p*C_ + c0) = o8;
  }
}

// ---------------- setup: fused weights (3 x 128^3) + fused biases ----------------
__global__ __launch_bounds__(256) void setup_kernel(const float* __restrict__ W_att1,
    const float* __restrict__ W_pos2, const float* __restrict__ W_q, const float* __restrict__ W_k,
    const float* __restrict__ b_pos2, const float* __restrict__ b_att1,
    const float* __restrict__ b_q, const float* __restrict__ b_k,
    float* __restrict__ Wf, float* __restrict__ Wqa, float* __restrict__ Wka,
    float* __restrict__ bG1, float* __restrict__ bqa, float* __restrict__ bka){
  int bx = blockIdx.x;
  if (bx < 192){
    int which = bx >> 6;
    const float* Bm = which==0 ? W_pos2 : (which==1 ? W_q : W_k);
    float* Cm = which==0 ? Wf : (which==1 ? Wqa : Wka);
    int e = (bx & 63)*256 + threadIdx.x;
    int o = e >> 7, c = e & 127;
    float s = 0.f;
    #pragma unroll 8
    for (int m = 0; m < 128; m++) s += W_att1[o*128+m]*Bm[m*128+c];
    Cm[e] = s;
  } else {
    for (int t = threadIdx.x; t < 384; t += 256){
      int which = t >> 7, o = t & 127;
      const float* v = which==0 ? b_pos2 : (which==1 ? b_q : b_k);
      float* out = which==0 ? bG1 : (which==1 ? bqa : bka);
      float s = which==0 ? b_att1[o] : 0.f;
      for (int m = 0; m < 128; m++) s += W_att1[o*128+m]*v[m];
      out[o] = s;
    }
  }
}

// ---------------- pos_pre group stats (raw conv1 output) ----------------
__global__ __launch_bounds__(256) void pos_stats_kernel(const float4* __restrict__ pt4,
    const int* __restrict__ idx, const float* __restrict__ W1, const float* __restrict__ b1,
    float* __restrict__ gsum, float* __restrict__ gssq){
  __shared__ float ls[G_], lss[G_];
  if (threadIdx.x < G_){ ls[threadIdx.x] = 0.f; lss[threadIdx.x] = 0.f; }
  __syncthreads();
  int p = blockIdx.x*256 + threadIdx.x;
  int b = p >> 17;
  int n = p >> 4;             // global n
  int j = idx[p];
  float4 pj = pt4[(b<<13) + j], pn = pt4[n];
  float rx = pj.x - pn.x, ry = pj.y - pn.y, rz = pj.z - pn.z;
  #pragma unroll
  for (int g = 0; g < G_; g++){
    float s = 0.f, ss = 0.f;
    #pragma unroll
    for (int ci = 0; ci < 16; ci++){
      int c = g*16 + ci;
      float v = b1[c] + W1[3*c]*rx + W1[3*c+1]*ry + W1[3*c+2]*rz;
      s += v; ss += v*v;
    }
    #pragma unroll
    for (int mk = 32; mk; mk >>= 1){ s += __shfl_xor(s, mk, 64); ss += __shfl_xor(ss, mk, 64); }
    if ((threadIdx.x & 63) == 0){ atomicAdd(&ls[g], s); atomicAdd(&lss[g], ss); }
  }
  __syncthreads();
  if (threadIdx.x < G_){
    atomicAdd(&gsum[b*G_ + threadIdx.x], ls[threadIdx.x]);
    atomicAdd(&gssq[b*G_ + threadIdx.x], lss[threadIdx.x]);
  }
}

// ---------------- pos finalize + folded GN params ----------------
__global__ void posfin_kernel(const float* __restrict__ gsum, const float* __restrict__ gssq,
    const float* __restrict__ W1, const float* __restrict__ b1,
    const float* __restrict__ g1, const float* __restrict__ be1, float* __restrict__ prm, float invcnt){
  __shared__ float sm[16], sr[16];
  int i = threadIdx.x;
  if (i < 16){
    float m = gsum[i]*invcnt;
    float v = gssq[i]*invcnt - m*m;
    v = fmaxf(v, 0.f);
    sm[i] = m; sr[i] = rsqrtf(v + EPSV);
  }
  __syncthreads();
  int b = i >> 7, c = i & 127, g = c >> 4;
  float rs = sr[b*G_+g]*g1[c];
  prm[b*512 +   0 + c] = W1[3*c]*rs;
  prm[b*512 + 128 + c] = W1[3*c+1]*rs;
  prm[b*512 + 256 + c] = W1[3*c+2]*rs;
  prm[b*512 + 384 + c] = (b1[c]-sm[b*G_+g])*rs + be1[c];
}

// ---------------- att finalize + folded scale/shift ----------------
__global__ void attfin_kernel(const float* __restrict__ gsum, const float* __restrict__ gssq,
    const float* __restrict__ ga, const float* __restrict__ bea, float* __restrict__ prm, float invcnt){
  __shared__ float sm[16], sr[16];
  int i = threadIdx.x;
  if (i < 16){
    float m = gsum[i]*invcnt;
    float v = gssq[i]*invcnt - m*m;
    v = fmaxf(v, 0.f);
    sm[i] = m; sr[i] = rsqrtf(v + EPSV);
  }
  __syncthreads();
  int b = i >> 7, c = i & 127, g = c >> 4;
  float sc = ga[c]*sr[b*G_+g];
  prm[b*256 +   0 + c] = sc;
  prm[b*256 + 128 + c] = bea[c] - sm[b*G_+g]*sc;
}

// ---------------- unified MFMA GEMM body: Y[o][p] = W*X + bias, 64 pts x 128 out ----------------
#define ST_COPY 0
#define ST_GN   1
#define ST_POS  2
#define EP_PM    0
#define EP_QKS   1
#define EP_F32CM 2

template<int STAGE>
__device__ __forceinline__ void stage_x(ushort* xs,
    const ushort* __restrict__ Xb, const float* __restrict__ prm,
    const float4* __restrict__ pt4, const int* __restrict__ idx, int p0, int b)
{
  int tid = threadIdx.x;
  int row = tid & 63, cc = tid >> 6;
  if constexpr (STAGE == ST_COPY){
    const ushort* src = Xb + (size_t)(p0+row)*C_ + cc*32;
    #pragma unroll
    for (int q = 0; q < 4; q++){
      s16x8 v8 = *(const s16x8*)(src + q*8);
      int sl = (cc*4+q) ^ (row&7);
      *(s16x8*)(xs + row*C_ + sl*8) = v8;
    }
  } else if constexpr (STAGE == ST_GN){
    const ushort* src = Xb + (size_t)(p0+row)*C_ + cc*32;
    const float* sc = prm + b*256;
    const float* sh = prm + b*256 + 128;
    #pragma unroll
    for (int q = 0; q < 4; q++){
      s16x8 v8 = *(const s16x8*)(src + q*8);
      s16x8 o8;
      #pragma unroll
      for (int i = 0; i < 8; i++){
        int c = cc*32 + q*8 + i;
        o8[i] = f2b(leakyf(b2f(v8[i])*sc[c] + sh[c]));
      }
      int sl = (cc*4+q) ^ (row&7);
      *(s16x8*)(xs + row*C_ + sl*8) = o8;
    }
  } else { // ST_POS
    int p = p0 + row;
    int ng = p >> 4;
    int j = idx[p];
    float4 pj = pt4[(b<<13) + j], pn = pt4[ng];
    float rx = pj.x - pn.x, ry = pj.y - pn.y, rz = pj.z - pn.z;
    const float* sx = prm + b*512;
    const float* sy = sx + 128;
    const float* sz = sx + 256;
    const float* so = sx + 384;
    #pragma unroll
    for (int q = 0; q < 4; q++){
      s16x8 o8;
      #pragma unroll
      for (int i = 0; i < 8; i++){
        int c = cc*32 + q*8 + i;
        o8[i] = f2b(leakyf(sx[c]*rx + sy[c]*ry + sz[c]*rz + so[c]));
      }
      int sl = (cc*4+q) ^ (row&7);
      *(s16x8*)(xs + row*C_ + sl*8) = o8;
    }
  }
}

__device__ __forceinline__ void load_afr(s16x8 afr[2][4], const float* __restrict__ W, int wid, int lm, int lh){
  #pragma unroll
  for (int t = 0; t < 2; t++){
    int T = wid*2 + t;
    #pragma unroll
    for (int ks = 0; ks < 4; ks++){
      const float* wr = W + (size_t)(T*16 + lm)*C_ + ks*32 + lh*8;
      float4 w0 = *(const float4*)wr;
      float4 w1 = *(const float4*)(wr+4);
      s16x8 a;
      a[0]=f2b(w0.x); a[1]=f2b(w0.y); a[2]=f2b(w0.z); a[3]=f2b(w0.w);
      a[4]=f2b(w1.x); a[5]=f2b(w1.y); a[6]=f2b(w1.z); a[7]=f2b(w1.w);
      afr[t][ks] = a;
    }
  }
}

__device__ __forceinline__ void mfma_tile(f32x4 acc[2][4], const s16x8 afr[2][4],
    const ushort* xs, const float* __restrict__ bias, int wid, int lm, int lh)
{
  #pragma unroll
  for (int t = 0; t < 2; t++){
    f32x4 bs = *(const f32x4*)(bias + (wid*2+t)*16 + lh*4);
    #pragma unroll
    for (int ps = 0; ps < 4; ps++) acc[t][ps] = bs;
  }
  #pragma unroll
  for (int ps = 0; ps < 4; ps++){
    int row = ps*16 + lm;
    s16x8 bf[4];
    #pragma unroll
    for (int ks = 0; ks < 4; ks++){
      int sl = (ks*4+lh) ^ (row&7);
      bf[ks] = *(const s16x8*)(xs + row*C_ + sl*8);
    }
    #pragma unroll
    for (int ks = 0; ks < 4; ks++){
      #pragma unroll
      for (int t = 0; t < 2; t++)
        acc[t][ps] = __builtin_amdgcn_mfma_f32_16x16x32_bf16(afr[t][ks], bf[ks], acc[t][ps], 0,0,0);
    }
  }
}

template<int STAGE, int EPI>
__device__ __forceinline__ void mgemm_body(ushort* xs, float* sblk,
    const ushort* __restrict__ Xb, const float* __restrict__ W, const float* __restrict__ bias,
    const float* __restrict__ prm, const float4* __restrict__ pt4, const int* __restrict__ idx,
    const ushort* __restrict__ Aq, const ushort* __restrict__ Ak,
    void* __restrict__ Y, float* __restrict__ gsum, float* __restrict__ gssq, int bsh, int bx)
{
  int tid = threadIdx.x;
  int l = tid & 63, wid = tid >> 6;
  int lm = l & 15, lh = l >> 4;
  int p0 = bx * 64;
  int b = p0 >> bsh;

  if (tid < 16) sblk[tid] = 0.f;

  s16x8 afr[2][4];
  load_afr(afr, W, wid, lm, lh);
  stage_x<STAGE>(xs, Xb, prm, pt4, idx, p0, b);
  __syncthreads();

  f32x4 acc[2][4];
  mfma_tile(acc, afr, xs, bias, wid, lm, lh);

  // ---- epilogue ----
  float gs[2] = {0.f,0.f}, gq[2] = {0.f,0.f};
  #pragma unroll
  for (int t = 0; t < 2; t++){
    int T = wid*2 + t;
    int o0 = T*16 + lh*4;
    #pragma unroll
    for (int ps = 0; ps < 4; ps++){
      int p = p0 + ps*16 + lm;
      if constexpr (EPI == EP_PM){
        s16x4 r4;
        #pragma unroll
        for (int r = 0; r < 4; r++) r4[r] = f2b(acc[t][ps][r]);
        *(s16x4*)((ushort*)Y + (size_t)p*C_ + o0) = r4;
      } else if constexpr (EPI == EP_QKS){
        int ng = p >> 4;
        int j = idx[p];
        s16x4 aq4 = *(const s16x4*)(Aq + (size_t)ng*C_ + o0);
        s16x4 ak4 = *(const s16x4*)(Ak + ((size_t)(b<<13)+j)*C_ + o0);
        s16x4 r4;
        #pragma unroll
        for (int r = 0; r < 4; r++){
          float v = acc[t][ps][r] + b2f(aq4[r]) - b2f(ak4[r]);
          r4[r] = f2b(v);
          gs[t] += v; gq[t] += v*v;
        }
        *(s16x4*)((ushort*)Y + (size_t)p*C_ + o0) = r4;
      } else { // EP_F32CM
        float* yf = (float*)Y;
        #pragma unroll
        for (int r = 0; r < 4; r++){
          float v = acc[t][ps][r];
          yf[(size_t)(o0+r)*BN_ + p] = v;
          gs[t] += v; gq[t] += v*v;
        }
      }
    }
  }

  if constexpr (EPI == EP_QKS || EPI == EP_F32CM){
    #pragma unroll
    for (int t = 0; t < 2; t++){
      float s = gs[t], q = gq[t];
      #pragma unroll
      for (int mk = 32; mk; mk >>= 1){ s += __shfl_xor(s, mk, 64); q += __shfl_xor(q, mk, 64); }
      if (l == 0){
        int T = wid*2 + t;
        atomicAdd(&sblk[T], s); atomicAdd(&sblk[8+T], q);
      }
    }
    __syncthreads();
    if (tid < 8){
      atomicAdd(&gsum[b*G_ + tid], sblk[tid]);
      atomicAdd(&gssq[b*G_ + tid], sblk[8+tid]);
    }
  }
}

template<int STAGE, int EPI>
__global__ __launch_bounds__(256) void mgemm_kernel(
    const ushort* __restrict__ Xb, const float* __restrict__ W, const float* __restrict__ bias,
    const float* __restrict__ prm, const float4* __restrict__ pt4, const int* __restrict__ idx,
    const ushort* __restrict__ Aq, const ushort* __restrict__ Ak,
    void* __restrict__ Y, float* __restrict__ gsum, float* __restrict__ gssq, int bsh)
{
  __shared__ ushort xs[64*128];
  __shared__ float sblk[16];
  mgemm_body<STAGE,EPI>(xs, sblk, Xb, W, bias, prm, pt4, idx, Aq, Ak, Y, gsum, gssq, bsh, blockIdx.x);
}

// v / Aq / Ak in one launch (gridDim.y = 3)
__global__ __launch_bounds__(256) void qkv_kernel(const ushort* __restrict__ nfb,
    const float* __restrict__ Wv, const float* __restrict__ bv,
    const float* __restrict__ Wqa, const float* __restrict__ bqa,
    const float* __restrict__ Wka, const float* __restrict__ bka,
    ushort* __restrict__ vb, ushort* __restrict__ Aqb, ushort* __restrict__ Akb)
{
  __shared__ ushort xs[64*128];
  __shared__ float sblk[16];
  if (blockIdx.y == 0)
    mgemm_body<ST_COPY,EP_PM>(xs, sblk, nfb, Wv, bv, nullptr, nullptr, nullptr, nullptr, nullptr, vb, nullptr, nullptr, 13, blockIdx.x);
  else if (blockIdx.y == 1)
    mgemm_body<ST_COPY,EP_PM>(xs, sblk, nfb, Wqa, bqa, nullptr, nullptr, nullptr, nullptr, nullptr, Aqb, nullptr, nullptr, 13, blockIdx.x);
  else
    mgemm_body<ST_COPY,EP_PM>(xs, sblk, nfb, Wka, bka, nullptr, nullptr, nullptr, nullptr, nullptr, Akb, nullptr, nullptr, 13, blockIdx.x);
}

// ---------------- fused: GN(att1) -> W_att2 GEMM -> softmax(k) -> PV + residual ----------------
// Block = 64 points (4 queries x 16 neighbors); k = lm within each acc row -> row shuffles.
__global__ __launch_bounds__(256) void fatt_kernel(const ushort* __restrict__ Xb /*att1 PM*/,
    const float* __restrict__ W /*W_att2*/, const float* __restrict__ bias /*b_att2*/,
    const float* __restrict__ prm /*attPrm*/, const int* __restrict__ idx,
    const ushort* __restrict__ vb, const ushort* __restrict__ nfb, ushort* __restrict__ outb)
{
  __shared__ ushort xs[64*128];
  int tid = threadIdx.x;
  int l = tid & 63, wid = tid >> 6;
  int lm = l & 15, lh = l >> 4;
  int p0 = blockIdx.x * 64;
  int b = p0 >> 17;

  s16x8 afr[2][4];
  load_afr(afr, W, wid, lm, lh);
  stage_x<ST_GN>(xs, Xb, prm, nullptr, nullptr, p0, b);
  __syncthreads();

  f32x4 acc[2][4];
  mfma_tile(acc, afr, xs, bias, wid, lm, lh);

  // softmax over k (lm) + PV + residual
  #pragma unroll
  for (int t = 0; t < 2; t++){
    int o0 = (wid*2+t)*16 + lh*4;
    #pragma unroll
    for (int ps = 0; ps < 4; ps++){
      int p = p0 + ps*16 + lm;
      int j = idx[p];
      s16x4 v4 = *(const s16x4*)(vb + ((size_t)(b<<13)+j)*C_ + o0);
      f32x4 e, pv;
      #pragma unroll
      for (int r = 0; r < 4; r++){
        float ev = __expf(acc[t][ps][r]);
        e[r] = ev;
        pv[r] = ev * b2f(v4[r]);
      }
      #pragma unroll
      for (int mk = 1; mk < 16; mk <<= 1){
        #pragma unroll
        for (int r = 0; r < 4; r++){
          e[r]  += __shfl_xor(e[r], mk, 64);
          pv[r] += __shfl_xor(pv[r], mk, 64);
        }
      }
      if (lm == 0){
        int n = p >> 4;
        s16x4 n4 = *(const s16x4*)(nfb + (size_t)n*C_ + o0);
        s16x4 o4;
        #pragma unroll
        for (int r = 0; r < 4; r++) o4[r] = f2b(pv[r]/e[r] + b2f(n4[r]));
        *(s16x4*)(outb + (size_t)n*C_ + o0) = o4;
      }
    }
  }
}

// ---------------- final: inline post-finalize + GN + leaky (out1 col-major [C][BN]) ----------------
__global__ __launch_bounds__(256) void final_kernel(const float* __restrict__ out1,
    const float* __restrict__ gsum, const float* __restrict__ gssq,
    const float* __restrict__ g, const float* __restrict__ be, float* __restrict__ out){
  int e = blockIdx.x*256 + threadIdx.x;
  int b = e >> 20;
  int c = (e >> 13) & (C_-1);
  int n = e & (N_-1);
  int gi = b*G_ + (c >> 4);
  const float invcnt = 1.0f/(float)(16*N_);
  float m = gsum[gi]*invcnt;
  float var = gssq[gi]*invcnt - m*m;
  var = fmaxf(var, 0.f);
  float r = rsqrtf(var + EPSV);
  float v = (out1[(size_t)c*BN_ + b*N_ + n] - m) * r;
  v = v*g[c] + be[c];
  out[e] = leakyf(v);
}

extern "C" void kernel_launch(void* const* d_in, const int* in_sizes, int n_in,
                              void* d_out, int out_size, void* d_ws, size_t ws_size,
                              hipStream_t stream) {
  const float* xyz    = (const float*)d_in[0];
  const float* feat   = (const float*)d_in[1];
  const float* W_pre  = (const float*)d_in[2];
  const float* b_pre  = (const float*)d_in[3];
  const float* W_pos1 = (const float*)d_in[4];
  const float* b_pos1 = (const float*)d_in[5];
  const float* g_pos1 = (const float*)d_in[6];
  const float* be_pos1= (const float*)d_in[7];
  const float* W_pos2 = (const float*)d_in[8];
  const float* b_pos2 = (const float*)d_in[9];
  const float* W_q    = (const float*)d_in[10];
  const float* b_q    = (const float*)d_in[11];
  const float* W_k    = (const float*)d_in[12];
  const float* b_k    = (const float*)d_in[13];
  const float* W_v    = (const float*)d_in[14];
  const float* b_v    = (const float*)d_in[15];
  const float* W_att1 = (const float*)d_in[16];
  const float* b_att1 = (const float*)d_in[17];
  const float* g_att1 = (const float*)d_in[18];
  const float* be_att1= (const float*)d_in[19];
  const float* W_att2 = (const float*)d_in[20];
  const float* b_att2 = (const float*)d_in[21];
  const float* W_post = (const float*)d_in[22];
  const float* b_post = (const float*)d_in[23];
  const float* g_post = (const float*)d_in[24];
  const float* be_post= (const float*)d_in[25];

  char* w = (char*)d_ws;
  float4* pt4 = (float4*)w;            w += sizeof(float4)*BN_;
  int* idx = (int*)w;                  w += sizeof(int)*BNK_;
  ushort* fb   = (ushort*)w;           w += (size_t)2*BN_*C_;
  ushort* nfb  = (ushort*)w;           w += (size_t)2*BN_*C_;
  ushort* vb   = (ushort*)w;           w += (size_t)2*BN_*C_;
  ushort* Aqb  = (ushort*)w;           w += (size_t)2*BN_*C_;
  ushort* Akb  = (ushort*)w;           w += (size_t)2*BN_*C_;
  ushort* outb = (ushort*)w;           w += (size_t)2*BN_*C_;
  float* out1  = (float*)w;            w += (size_t)4*BN_*C_;
  ushort* bufA = (ushort*)w;           w += (size_t)2*BNK_*C_;           // att1 PM
  float* Wf    = (float*)w;            w += sizeof(float)*C_*C_;
  float* Wqa   = (float*)w;            w += sizeof(float)*C_*C_;
  float* Wka   = (float*)w;            w += sizeof(float)*C_*C_;
  float* bG1   = (float*)w;            w += 512;
  float* bqa   = (float*)w;            w += 512;
  float* bka   = (float*)w;            w += 512;
  float* posPrm= (float*)w;            w += sizeof(float)*1024;
  float* attPrm= (float*)w;            w += sizeof(float)*512;
  float* stats = (float*)w;            w += 1024;

  float* pos_sum = stats +  0, *pos_ssq = stats + 16;
  float* att_sum = stats + 64, *att_ssq = stats + 80;
  float* post_sum= stats +128, *post_ssq= stats +144;

  hipMemsetAsync(stats, 0, 1024, stream);

  pack_kernel<<<BN_/256, 256, 0, stream>>>(xyz, pt4);
  knn_kernel<<<BN_/(KNN_TPB/64), KNN_TPB, 0, stream>>>(pt4, idx);
  featb_kernel<<<BN_/256, 256, 0, stream>>>(feat, fb);

  // fused weights / biases (one launch)
  setup_kernel<<<193, 256, 0, stream>>>(W_att1, W_pos2, W_q, W_k, b_pos2, b_att1, b_q, b_k,
      Wf, Wqa, Wka, bG1, bqa, bka);

  // nf = W_pre*feat + b
  mgemm_kernel<ST_COPY,EP_PM><<<BN_/64, 256, 0, stream>>>(fb, W_pre, b_pre, nullptr, nullptr, nullptr,
      nullptr, nullptr, nfb, nullptr, nullptr, 13);
  // v, Aq, Ak (one launch)
  qkv_kernel<<<dim3(BN_/64, 3), 256, 0, stream>>>(nfb, W_v, b_v, Wqa, bqa, Wka, bka, vb, Aqb, Akb);

  // pos GN stats -> folded params
  pos_stats_kernel<<<BNK_/256, 256, 0, stream>>>(pt4, idx, W_pos1, b_pos1, pos_sum, pos_ssq);
  posfin_kernel<<<1, 256, 0, stream>>>(pos_sum, pos_ssq, W_pos1, b_pos1, g_pos1, be_pos1, posPrm,
      1.0f/(float)(16.0*NK_));

  // G1: att1 = Wf*posn + bG1 + Aq[n] - Ak[j]  (+ stats)  -> bufA
  mgemm_kernel<ST_POS,EP_QKS><<<BNK_/64, 256, 0, stream>>>(nullptr, Wf, bG1, posPrm, pt4, idx,
      Aqb, Akb, bufA, att_sum, att_ssq, 17);
  attfin_kernel<<<1, 256, 0, stream>>>(att_sum, att_ssq, g_att1, be_att1, attPrm, 1.0f/(float)(16.0*NK_));

  // fused G2 + softmax + PV + residual
  fatt_kernel<<<BNK_/64, 256, 0, stream>>>(bufA, W_att2, b_att2, attPrm, idx, vb, nfb, outb);

  // post conv + stats (f32 col-major)
  mgemm_kernel<ST_COPY,EP_F32CM><<<BN_/64, 256, 0, stream>>>(outb, W_post, b_post, nullptr, nullptr, nullptr,
      nullptr, nullptr, out1, post_sum, post_ssq, 13);
  final_kernel<<<(B_*CN_)/256, 256, 0, stream>>>(out1, post_sum, post_ssq, g_post, be_post, (float*)d_out);
}

// Round 9
// 351.503 us; speedup vs baseline: 7.1590x; 1.0481x over previous
//
#include <hip/hip_runtime.h>
#include <hip/hip_bf16.h>
#include <float.h>

#define B_ 2
#define N_ 8192
#define C_ 128
#define K_ 16
#define G_ 8
#define NK_ (N_*K_)     // 131072
#define BN_ (B_*N_)     // 16384
#define BNK_ (B_*NK_)   // 262144
#define CN_ (C_*N_)
#define NEG 0.1f
#define EPSV 1e-5f

typedef __attribute__((ext_vector_type(4))) float f32x4;
typedef __attribute__((ext_vector_type(8))) short s16x8;
typedef __attribute__((ext_vector_type(4))) short s16x4;

__device__ __forceinline__ float leakyf(float x){ return x >= 0.f ? x : NEG*x; }
__device__ __forceinline__ short f2b(float x){
  union { __hip_bfloat16 b; short s; } u; u.b = __float2bfloat16(x); return u.s;
}
__device__ __forceinline__ float b2f(short s){
  union { __hip_bfloat16 b; short s; } u; u.s = s; return __bfloat162float(u.b);
}

// row_shr:1 within 16-lane rows (list lives in lanes 0..15 -> row-local)
__device__ __forceinline__ int dpp_shr1_i(int x){
  return __builtin_amdgcn_update_dpp(x, x, 0x111, 0xF, 0xF, false);
}
__device__ __forceinline__ unsigned long long dpp_shr1_u64(unsigned long long x){
  union { unsigned long long q; int i[2]; } u; u.q = x;
  u.i[0] = dpp_shr1_i(u.i[0]);
  u.i[1] = dpp_shr1_i(u.i[1]);
  return u.q;
}
__device__ __forceinline__ unsigned long long readlane_u64(unsigned long long x, int l){
  union { unsigned long long q; int i[2]; } u; u.q = x;
  union { unsigned long long q; int i[2]; } r;
  r.i[0] = __builtin_amdgcn_readlane(u.i[0], l);
  r.i[1] = __builtin_amdgcn_readlane(u.i[1], l);
  return r.q;
}
// sort key: d2 (clamped >=0) bits, low 13 mantissa bits replaced by idx.
// u64 compare == (d2, idx) lex order at 2^-40 relative granularity (<< fp32 ref noise).
__device__ __forceinline__ unsigned long long d2key(double d2, int idx){
  d2 = fmax(d2, 0.0);
  union { double d; unsigned long long q; } u; u.d = d2;
  return (u.q & ~0x1FFFull) | (unsigned long long)idx;
}
__device__ __forceinline__ double key_upper_d2(unsigned long long k){
  union { unsigned long long q; double d; } u; u.q = k | 0x1FFFull;   // round up: conservative
  return u.d;
}

// ---------------- pack xyz -> float4 (w = |p|^2 fp32) + feat -> bf16 PM ----------------
__global__ __launch_bounds__(256) void pack_featb_kernel(const float* __restrict__ xyz,
    const float* __restrict__ feat, float4* __restrict__ pt4, ushort* __restrict__ fb){
  int e = blockIdx.x*256 + threadIdx.x;
  int b = e >> 13, n = e & (N_-1);
  const float* xb = xyz + b*3*N_;
  float x = xb[n], y = xb[N_+n], z = xb[2*N_+n];
  pt4[e] = make_float4(x, y, z, x*x + y*y + z*z);
  const float* xin = feat + b*CN_ + n;
  #pragma unroll
  for (int c0 = 0; c0 < C_; c0 += 8){
    s16x8 o8;
    #pragma unroll
    for (int i = 0; i < 8; i++) o8[i] = f2b(xin[(size_t)(c0+i)*N_]);
    *(s16x8*)(fb + (size_t)e*C_ + c0) = o8;
  }
}

// ---------------- KNN: wave per query, fp32 prefilter + u64-key exact refine ----------------
// Filter fp32 abs error bound < 7.5e-5; margin 2e-4 = ~2.7x safety.
#define KNN_TPB 512
#define KNN_CHUNK 2048
#define KNN_MARGIN 2e-4f
__global__ __launch_bounds__(KNN_TPB) void knn_kernel(const float4* __restrict__ pt4, int* __restrict__ idxo){
  __shared__ float4 sp[KNN_CHUNK];
  int lane = threadIdx.x & 63, wid = threadIdx.x >> 6;
  int qg = blockIdx.x*(KNN_TPB/64) + wid;
  int b = qg >> 13, n = qg & (N_-1);
  const float4* pts = pt4 + b*N_;
  float4 qp = pts[n];
  double qx = qp.x, qy = qp.y, qz = qp.z;
  double qsq = qx*qx + qy*qy + qz*qz;
  float qx2 = -2.f*qp.x, qy2 = -2.f*qp.y, qz2 = -2.f*qp.z;
  unsigned long long mykey;          // lanes 0..15: sorted top-16 keys
  float cmpv;

  // ---- warmup: exact top-16 of first 64 candidates via 64-lane bitonic sort on keys ----
  {
    float4 pp = pts[lane];
    double px = pp.x, py = pp.y, pz = pp.z;
    double psq = px*px + py*py + pz*pz;
    double dot = qx*px + qy*py + qz*pz;
    unsigned long long kl = d2key(qsq + psq - 2.0*dot, lane);
    #pragma unroll
    for (int k2 = 2; k2 <= 64; k2 <<= 1){
      #pragma unroll
      for (int mm = k2>>1; mm > 0; mm >>= 1){
        unsigned long long pk = __shfl_xor(kl, mm, 64);
        bool up = ((lane & k2) == 0);
        bool lower = ((lane & mm) == 0);
        bool myLess = kl < pk;
        bool keep = lower ? (up ? myLess : !myLess) : (up ? !myLess : myLess);
        if (!keep) kl = pk;
      }
    }
    mykey = kl;
    cmpv = (float)(key_upper_d2(readlane_u64(mykey, 15)) - qsq) + KNN_MARGIN;
  }

  // Insertion ballot bm==0 <=> candidate does not beat current 16th (lane 15).
  auto process = [&](unsigned long long m, unsigned long long keyv){
    while (m){
      int src = __ffsll(m) - 1; m &= m - 1;
      unsigned long long kn = readlane_u64(keyv, src);
      bool less = kn < mykey;
      unsigned long long bm = __ballot(less) & 0xFFFFull;
      if (bm){
        int pos = __ffsll(bm) - 1;
        unsigned long long pk = dpp_shr1_u64(mykey);
        if (lane < 16){
          if (lane > pos) mykey = pk;
          else if (lane == pos) mykey = kn;
        }
      }
    }
  };

  for (int c0 = 0; c0 < N_; c0 += KNN_CHUNK){
    __syncthreads();
    #pragma unroll
    for (int t = 0; t < KNN_CHUNK/KNN_TPB; t++){
      int i = t*KNN_TPB + threadIdx.x;
      sp[i] = pts[c0 + i];
    }
    __syncthreads();
    for (int j0 = 0; j0 < KNN_CHUNK; j0 += 128){
      float4 pA = sp[j0 + lane];
      float4 pB = sp[j0 + 64 + lane];
      float fA = fmaf(pA.x, qx2, fmaf(pA.y, qy2, fmaf(pA.z, qz2, pA.w)));
      float fB = fmaf(pB.x, qx2, fmaf(pB.y, qy2, fmaf(pB.z, qz2, pB.w)));
      unsigned long long mA = __ballot(fA < cmpv);
      unsigned long long mB = __ballot(fB < cmpv);
      if (c0 == 0 && j0 == 0) mA = 0;     // first 64 handled in warmup
      if (mA | mB){
        if (mA){
          double px = pA.x, py = pA.y, pz = pA.z;
          double psq = px*px + py*py + pz*pz;
          double dot = qx*px + qy*py + qz*pz;
          process(mA, d2key(qsq + psq - 2.0*dot, c0 + j0 + lane));
        }
        if (mB){
          double px = pB.x, py = pB.y, pz = pB.z;
          double psq = px*px + py*py + pz*pz;
          double dot = qx*px + qy*py + qz*pz;
          process(mB, d2key(qsq + psq - 2.0*dot, c0 + j0 + 64 + lane));
        }
        cmpv = (float)(key_upper_d2(readlane_u64(mykey, 15)) - qsq) + KNN_MARGIN;
      }
    }
  }
  if (lane < 16) idxo[qg*K_ + lane] = (int)(mykey & 0x1FFFull);
}

// ---------------- setup: fused weights (3 x 128^3) + fused biases ----------------
__global__ __launch_bounds__(256) void setup_kernel(const float* __restrict__ W_att1,
    const float* __restrict__ W_pos2, const float* __restrict__ W_q, const float* __restrict__ W_k,
    const float* __restrict__ b_pos2, const float* __restrict__ b_att1,
    const float* __restrict__ b_q, const float* __restrict__ b_k,
    float* __restrict__ Wf, float* __restrict__ Wqa, float* __restrict__ Wka,
    float* __restrict__ bG1, float* __restrict__ bqa, float* __restrict__ bka){
  int bx = blockIdx.x;
  if (bx < 192){
    int which = bx >> 6;
    const float* Bm = which==0 ? W_pos2 : (which==1 ? W_q : W_k);
    float* Cm = which==0 ? Wf : (which==1 ? Wqa : Wka);
    int e = (bx & 63)*256 + threadIdx.x;
    int o = e >> 7, c = e & 127;
    float s = 0.f;
    #pragma unroll 8
    for (int m = 0; m < 128; m++) s += W_att1[o*128+m]*Bm[m*128+c];
    Cm[e] = s;
  } else {
    for (int t = threadIdx.x; t < 384; t += 256){
      int which = t >> 7, o = t & 127;
      const float* v = which==0 ? b_pos2 : (which==1 ? b_q : b_k);
      float* out = which==0 ? bG1 : (which==1 ? bqa : bka);
      float s = which==0 ? b_att1[o] : 0.f;
      for (int m = 0; m < 128; m++) s += W_att1[o*128+m]*v[m];
      out[o] = s;
    }
  }
}

// ---------------- pos_pre group stats (raw conv1 output) ----------------
__global__ __launch_bounds__(256) void pos_stats_kernel(const float4* __restrict__ pt4,
    const int* __restrict__ idx, const float* __restrict__ W1, const float* __restrict__ b1,
    float* __restrict__ gsum, float* __restrict__ gssq){
  __shared__ float ls[G_], lss[G_];
  if (threadIdx.x < G_){ ls[threadIdx.x] = 0.f; lss[threadIdx.x] = 0.f; }
  __syncthreads();
  int p = blockIdx.x*256 + threadIdx.x;
  int b = p >> 17;
  int n = p >> 4;             // global n
  int j = idx[p];
  float4 pj = pt4[(b<<13) + j], pn = pt4[n];
  float rx = pj.x - pn.x, ry = pj.y - pn.y, rz = pj.z - pn.z;
  #pragma unroll
  for (int g = 0; g < G_; g++){
    float s = 0.f, ss = 0.f;
    #pragma unroll
    for (int ci = 0; ci < 16; ci++){
      int c = g*16 + ci;
      float v = b1[c] + W1[3*c]*rx + W1[3*c+1]*ry + W1[3*c+2]*rz;
      s += v; ss += v*v;
    }
    #pragma unroll
    for (int mk = 32; mk; mk >>= 1){ s += __shfl_xor(s, mk, 64); ss += __shfl_xor(ss, mk, 64); }
    if ((threadIdx.x & 63) == 0){ atomicAdd(&ls[g], s); atomicAdd(&lss[g], ss); }
  }
  __syncthreads();
  if (threadIdx.x < G_){
    atomicAdd(&gsum[b*G_ + threadIdx.x], ls[threadIdx.x]);
    atomicAdd(&gssq[b*G_ + threadIdx.x], lss[threadIdx.x]);
  }
}

// ---------------- pos finalize + folded GN params (interleaved float4: sx,sy,sz,so) ----------------
__global__ void posfin_kernel(const float* __restrict__ gsum, const float* __restrict__ gssq,
    const float* __restrict__ W1, const float* __restrict__ b1,
    const float* __restrict__ g1, const float* __restrict__ be1, float* __restrict__ prm, float invcnt){
  __shared__ float sm[16], sr[16];
  int i = threadIdx.x;
  if (i < 16){
    float m = gsum[i]*invcnt;
    float v = gssq[i]*invcnt - m*m;
    v = fmaxf(v, 0.f);
    sm[i] = m; sr[i] = rsqrtf(v + EPSV);
  }
  __syncthreads();
  int b = i >> 7, c = i & 127, g = c >> 4;
  float rs = sr[b*G_+g]*g1[c];
  float4* p4 = (float4*)prm;
  p4[b*128 + c] = make_float4(W1[3*c]*rs, W1[3*c+1]*rs, W1[3*c+2]*rs,
                              (b1[c]-sm[b*G_+g])*rs + be1[c]);
}

// ---------------- att finalize + folded scale/shift (interleaved float2: sc,sh) ----------------
__global__ void attfin_kernel(const float* __restrict__ gsum, const float* __restrict__ gssq,
    const float* __restrict__ ga, const float* __restrict__ bea, float* __restrict__ prm, float invcnt){
  __shared__ float sm[16], sr[16];
  int i = threadIdx.x;
  if (i < 16){
    float m = gsum[i]*invcnt;
    float v = gssq[i]*invcnt - m*m;
    v = fmaxf(v, 0.f);
    sm[i] = m; sr[i] = rsqrtf(v + EPSV);
  }
  __syncthreads();
  int b = i >> 7, c = i & 127, g = c >> 4;
  float sc = ga[c]*sr[b*G_+g];
  float2* p2 = (float2*)prm;
  p2[b*128 + c] = make_float2(sc, bea[c] - sm[b*G_+g]*sc);
}

// ---------------- unified MFMA GEMM body: Y[o][p] = W*X + bias, 64 pts x 128 out ----------------
#define ST_COPY 0
#define ST_GN   1
#define ST_POS  2
#define EP_PM    0
#define EP_QKS   1
#define EP_F32CM 2

template<int STAGE>
__device__ __forceinline__ void stage_x(ushort* xs,
    const ushort* __restrict__ Xb, const float* __restrict__ prm,
    const float4* __restrict__ pt4, const int* __restrict__ idx, int p0, int b)
{
  int tid = threadIdx.x;
  int row = tid & 63, cc = tid >> 6;
  if constexpr (STAGE == ST_COPY){
    const ushort* src = Xb + (size_t)(p0+row)*C_ + cc*32;
    #pragma unroll
    for (int q = 0; q < 4; q++){
      s16x8 v8 = *(const s16x8*)(src + q*8);
      int sl = (cc*4+q) ^ (row&7);
      *(s16x8*)(xs + row*C_ + sl*8) = v8;
    }
  } else if constexpr (STAGE == ST_GN){
    const ushort* src = Xb + (size_t)(p0+row)*C_ + cc*32;
    const float2* pr = (const float2*)prm + b*128;
    #pragma unroll
    for (int q = 0; q < 4; q++){
      s16x8 v8 = *(const s16x8*)(src + q*8);
      s16x8 o8;
      #pragma unroll
      for (int i = 0; i < 8; i++){
        int c = cc*32 + q*8 + i;
        float2 s2 = pr[c];
        o8[i] = f2b(leakyf(b2f(v8[i])*s2.x + s2.y));
      }
      int sl = (cc*4+q) ^ (row&7);
      *(s16x8*)(xs + row*C_ + sl*8) = o8;
    }
  } else { // ST_POS
    int p = p0 + row;
    int ng = p >> 4;
    int j = idx[p];
    float4 pj = pt4[(b<<13) + j], pn = pt4[ng];
    float rx = pj.x - pn.x, ry = pj.y - pn.y, rz = pj.z - pn.z;
    const float4* pr = (const float4*)prm + b*128;
    #pragma unroll
    for (int q = 0; q < 4; q++){
      s16x8 o8;
      #pragma unroll
      for (int i = 0; i < 8; i++){
        int c = cc*32 + q*8 + i;
        float4 s4 = pr[c];
        o8[i] = f2b(leakyf(fmaf(s4.x, rx, fmaf(s4.y, ry, fmaf(s4.z, rz, s4.w)))));
      }
      int sl = (cc*4+q) ^ (row&7);
      *(s16x8*)(xs + row*C_ + sl*8) = o8;
    }
  }
}

__device__ __forceinline__ void load_afr(s16x8 afr[2][4], const float* __restrict__ W, int wid, int lm, int lh){
  #pragma unroll
  for (int t = 0; t < 2; t++){
    int T = wid*2 + t;
    #pragma unroll
    for (int ks = 0; ks < 4; ks++){
      const float* wr = W + (size_t)(T*16 + lm)*C_ + ks*32 + lh*8;
      float4 w0 = *(const float4*)wr;
      float4 w1 = *(const float4*)(wr+4);
      s16x8 a;
      a[0]=f2b(w0.x); a[1]=f2b(w0.y); a[2]=f2b(w0.z); a[3]=f2b(w0.w);
      a[4]=f2b(w1.x); a[5]=f2b(w1.y); a[6]=f2b(w1.z); a[7]=f2b(w1.w);
      afr[t][ks] = a;
    }
  }
}

__device__ __forceinline__ void mfma_tile(f32x4 acc[2][4], const s16x8 afr[2][4],
    const ushort* xs, const float* __restrict__ bias, int wid, int lm, int lh)
{
  #pragma unroll
  for (int t = 0; t < 2; t++){
    f32x4 bs = *(const f32x4*)(bias + (wid*2+t)*16 + lh*4);
    #pragma unroll
    for (int ps = 0; ps < 4; ps++) acc[t][ps] = bs;
  }
  #pragma unroll
  for (int ps = 0; ps < 4; ps++){
    int row = ps*16 + lm;
    s16x8 bf[4];
    #pragma unroll
    for (int ks = 0; ks < 4; ks++){
      int sl = (ks*4+lh) ^ (row&7);
      bf[ks] = *(const s16x8*)(xs + row*C_ + sl*8);
    }
    #pragma unroll
    for (int ks = 0; ks < 4; ks++){
      #pragma unroll
      for (int t = 0; t < 2; t++)
        acc[t][ps] = __builtin_amdgcn_mfma_f32_16x16x32_bf16(afr[t][ks], bf[ks], acc[t][ps], 0,0,0);
    }
  }
}

template<int STAGE, int EPI>
__device__ __forceinline__ void mgemm_body(ushort* xs, float* sblk,
    const ushort* __restrict__ Xb, const float* __restrict__ W, const float* __restrict__ bias,
    const float* __restrict__ prm, const float4* __restrict__ pt4, const int* __restrict__ idx,
    const ushort* __restrict__ Aq, const ushort* __restrict__ Ak,
    void* __restrict__ Y, float* __restrict__ gsum, float* __restrict__ gssq, int bsh, int bx)
{
  int tid = threadIdx.x;
  int l = tid & 63, wid = tid >> 6;
  int lm = l & 15, lh = l >> 4;
  int p0 = bx * 64;
  int b = p0 >> bsh;

  if (tid < 16) sblk[tid] = 0.f;

  s16x8 afr[2][4];
  load_afr(afr, W, wid, lm, lh);
  stage_x<STAGE>(xs, Xb, prm, pt4, idx, p0, b);
  __syncthreads();

  f32x4 acc[2][4];
  mfma_tile(acc, afr, xs, bias, wid, lm, lh);

  // ---- epilogue ----
  float gs[2] = {0.f,0.f}, gq[2] = {0.f,0.f};
  #pragma unroll
  for (int t = 0; t < 2; t++){
    int T = wid*2 + t;
    int o0 = T*16 + lh*4;
    #pragma unroll
    for (int ps = 0; ps < 4; ps++){
      int p = p0 + ps*16 + lm;
      if constexpr (EPI == EP_PM){
        s16x4 r4;
        #pragma unroll
        for (int r = 0; r < 4; r++) r4[r] = f2b(acc[t][ps][r]);
        *(s16x4*)((ushort*)Y + (size_t)p*C_ + o0) = r4;
      } else if constexpr (EPI == EP_QKS){
        int ng = p >> 4;
        int j = idx[p];
        s16x4 aq4 = *(const s16x4*)(Aq + (size_t)ng*C_ + o0);
        s16x4 ak4 = *(const s16x4*)(Ak + ((size_t)(b<<13)+j)*C_ + o0);
        s16x4 r4;
        #pragma unroll
        for (int r = 0; r < 4; r++){
          float v = acc[t][ps][r] + b2f(aq4[r]) - b2f(ak4[r]);
          r4[r] = f2b(v);
          gs[t] += v; gq[t] += v*v;
        }
        *(s16x4*)((ushort*)Y + (size_t)p*C_ + o0) = r4;
      } else { // EP_F32CM
        float* yf = (float*)Y;
        #pragma unroll
        for (int r = 0; r < 4; r++){
          float v = acc[t][ps][r];
          yf[(size_t)(o0+r)*BN_ + p] = v;
          gs[t] += v; gq[t] += v*v;
        }
      }
    }
  }

  if constexpr (EPI == EP_QKS || EPI == EP_F32CM){
    #pragma unroll
    for (int t = 0; t < 2; t++){
      float s = gs[t], q = gq[t];
      #pragma unroll
      for (int mk = 32; mk; mk >>= 1){ s += __shfl_xor(s, mk, 64); q += __shfl_xor(q, mk, 64); }
      if (l == 0){
        int T = wid*2 + t;
        atomicAdd(&sblk[T], s); atomicAdd(&sblk[8+T], q);
      }
    }
    __syncthreads();
    if (tid < 8){
      atomicAdd(&gsum[b*G_ + tid], sblk[tid]);
      atomicAdd(&gssq[b*G_ + tid], sblk[8+tid]);
    }
  }
}

template<int STAGE, int EPI>
__global__ __launch_bounds__(256) void mgemm_kernel(
    const ushort* __restrict__ Xb, const float* __restrict__ W, const float* __restrict__ bias,
    const float* __restrict__ prm, const float4* __restrict__ pt4, const int* __restrict__ idx,
    const ushort* __restrict__ Aq, const ushort* __restrict__ Ak,
    void* __restrict__ Y, float* __restrict__ gsum, float* __restrict__ gssq, int bsh)
{
  __shared__ ushort xs[64*128];
  __shared__ float sblk[16];
  mgemm_body<STAGE,EPI>(xs, sblk, Xb, W, bias, prm, pt4, idx, Aq, Ak, Y, gsum, gssq, bsh, blockIdx.x);
}

// v / Aq / Ak in one launch (gridDim.y = 3)
__global__ __launch_bounds__(256) void qkv_kernel(const ushort* __restrict__ nfb,
    const float* __restrict__ Wv, const float* __restrict__ bv,
    const float* __restrict__ Wqa, const float* __restrict__ bqa,
    const float* __restrict__ Wka, const float* __restrict__ bka,
    ushort* __restrict__ vb, ushort* __restrict__ Aqb, ushort* __restrict__ Akb)
{
  __shared__ ushort xs[64*128];
  __shared__ float sblk[16];
  if (blockIdx.y == 0)
    mgemm_body<ST_COPY,EP_PM>(xs, sblk, nfb, Wv, bv, nullptr, nullptr, nullptr, nullptr, nullptr, vb, nullptr, nullptr, 13, blockIdx.x);
  else if (blockIdx.y == 1)
    mgemm_body<ST_COPY,EP_PM>(xs, sblk, nfb, Wqa, bqa, nullptr, nullptr, nullptr, nullptr, nullptr, Aqb, nullptr, nullptr, 13, blockIdx.x);
  else
    mgemm_body<ST_COPY,EP_PM>(xs, sblk, nfb, Wka, bka, nullptr, nullptr, nullptr, nullptr, nullptr, Akb, nullptr, nullptr, 13, blockIdx.x);
}

// ---------------- fused: GN(att1) -> W_att2 GEMM -> softmax(k) -> PV + residual ----------------
__global__ __launch_bounds__(256) void fatt_kernel(const ushort* __restrict__ Xb /*att1 PM*/,
    const float* __restrict__ W /*W_att2*/, const float* __restrict__ bias /*b_att2*/,
    const float* __restrict__ prm /*attPrm*/, const int* __restrict__ idx,
    const ushort* __restrict__ vb, const ushort* __restrict__ nfb, ushort* __restrict__ outb)
{
  __shared__ ushort xs[64*128];
  int tid = threadIdx.x;
  int l = tid & 63, wid = tid >> 6;
  int lm = l & 15, lh = l >> 4;
  int p0 = blockIdx.x * 64;
  int b = p0 >> 17;

  s16x8 afr[2][4];
  load_afr(afr, W, wid, lm, lh);
  stage_x<ST_GN>(xs, Xb, prm, nullptr, nullptr, p0, b);
  __syncthreads();

  f32x4 acc[2][4];
  mfma_tile(acc, afr, xs, bias, wid, lm, lh);

  // softmax over k (lm) + PV + residual
  #pragma unroll
  for (int t = 0; t < 2; t++){
    int o0 = (wid*2+t)*16 + lh*4;
    #pragma unroll
    for (int ps = 0; ps < 4; ps++){
      int p = p0 + ps*16 + lm;
      int j = idx[p];
      s16x4 v4 = *(const s16x4*)(vb + ((size_t)(b<<13)+j)*C_ + o0);
      f32x4 e, pv;
      #pragma unroll
      for (int r = 0; r < 4; r++){
        float ev = __expf(acc[t][ps][r]);
        e[r] = ev;
        pv[r] = ev * b2f(v4[r]);
      }
      #pragma unroll
      for (int mk = 1; mk < 16; mk <<= 1){
        #pragma unroll
        for (int r = 0; r < 4; r++){
          e[r]  += __shfl_xor(e[r], mk, 64);
          pv[r] += __shfl_xor(pv[r], mk, 64);
        }
      }
      if (lm == 0){
        int n = p >> 4;
        s16x4 n4 = *(const s16x4*)(nfb + (size_t)n*C_ + o0);
        s16x4 o4;
        #pragma unroll
        for (int r = 0; r < 4; r++) o4[r] = f2b(pv[r]/e[r] + b2f(n4[r]));
        *(s16x4*)(outb + (size_t)n*C_ + o0) = o4;
      }
    }
  }
}

// ---------------- final: inline post-finalize + GN + leaky (out1 col-major [C][BN]) ----------------
__global__ __launch_bounds__(256) void final_kernel(const float* __restrict__ out1,
    const float* __restrict__ gsum, const float* __restrict__ gssq,
    const float* __restrict__ g, const float* __restrict__ be, float* __restrict__ out){
  int e = blockIdx.x*256 + threadIdx.x;
  int b = e >> 20;
  int c = (e >> 13) & (C_-1);
  int n = e & (N_-1);
  int gi = b*G_ + (c >> 4);
  const float invcnt = 1.0f/(float)(16*N_);
  float m = gsum[gi]*invcnt;
  float var = gssq[gi]*invcnt - m*m;
  var = fmaxf(var, 0.f);
  float r = rsqrtf(var + EPSV);
  float v = (out1[(size_t)c*BN_ + b*N_ + n] - m) * r;
  v = v*g[c] + be[c];
  out[e] = leakyf(v);
}

extern "C" void kernel_launch(void* const* d_in, const int* in_sizes, int n_in,
                              void* d_out, int out_size, void* d_ws, size_t ws_size,
                              hipStream_t stream) {
  const float* xyz    = (const float*)d_in[0];
  const float* feat   = (const float*)d_in[1];
  const float* W_pre  = (const float*)d_in[2];
  const float* b_pre  = (const float*)d_in[3];
  const float* W_pos1 = (const float*)d_in[4];
  const float* b_pos1 = (const float*)d_in[5];
  const float* g_pos1 = (const float*)d_in[6];
  const float* be_pos1= (const float*)d_in[7];
  const float* W_pos2 = (const float*)d_in[8];
  const float* b_pos2 = (const float*)d_in[9];
  const float* W_q    = (const float*)d_in[10];
  const float* b_q    = (const float*)d_in[11];
  const float* W_k    = (const float*)d_in[12];
  const float* b_k    = (const float*)d_in[13];
  const float* W_v    = (const float*)d_in[14];
  const float* b_v    = (const float*)d_in[15];
  const float* W_att1 = (const float*)d_in[16];
  const float* b_att1 = (const float*)d_in[17];
  const float* g_att1 = (const float*)d_in[18];
  const float* be_att1= (const float*)d_in[19];
  const float* W_att2 = (const float*)d_in[20];
  const float* b_att2 = (const float*)d_in[21];
  const float* W_post = (const float*)d_in[22];
  const float* b_post = (const float*)d_in[23];
  const float* g_post = (const float*)d_in[24];
  const float* be_post= (const float*)d_in[25];

  char* w = (char*)d_ws;
  float4* pt4 = (float4*)w;            w += sizeof(float4)*BN_;
  int* idx = (int*)w;                  w += sizeof(int)*BNK_;
  ushort* fb   = (ushort*)w;           w += (size_t)2*BN_*C_;
  ushort* nfb  = (ushort*)w;           w += (size_t)2*BN_*C_;
  ushort* vb   = (ushort*)w;           w += (size_t)2*BN_*C_;
  ushort* Aqb  = (ushort*)w;           w += (size_t)2*BN_*C_;
  ushort* Akb  = (ushort*)w;           w += (size_t)2*BN_*C_;
  ushort* outb = (ushort*)w;           w += (size_t)2*BN_*C_;
  float* out1  = (float*)w;            w += (size_t)4*BN_*C_;
  ushort* bufA = (ushort*)w;           w += (size_t)2*BNK_*C_;           // att1 PM
  float* Wf    = (float*)w;            w += sizeof(float)*C_*C_;
  float* Wqa   = (float*)w;            w += sizeof(float)*C_*C_;
  float* Wka   = (float*)w;            w += sizeof(float)*C_*C_;
  float* bG1   = (float*)w;            w += 512;
  float* bqa   = (float*)w;            w += 512;
  float* bka   = (float*)w;            w += 512;
  float* posPrm= (float*)w;            w += sizeof(float)*1024;
  float* attPrm= (float*)w;            w += sizeof(float)*512;
  float* stats = (float*)w;            w += 1024;

  float* pos_sum = stats +  0, *pos_ssq = stats + 16;
  float* att_sum = stats + 64, *att_ssq = stats + 80;
  float* post_sum= stats +128, *post_ssq= stats +144;

  hipMemsetAsync(stats, 0, 1024, stream);

  pack_featb_kernel<<<BN_/256, 256, 0, stream>>>(xyz, feat, pt4, fb);
  knn_kernel<<<BN_/(KNN_TPB/64), KNN_TPB, 0, stream>>>(pt4, idx);

  // fused weights / biases (one launch)
  setup_kernel<<<193, 256, 0, stream>>>(W_att1, W_pos2, W_q, W_k, b_pos2, b_att1, b_q, b_k,
      Wf, Wqa, Wka, bG1, bqa, bka);

  // nf = W_pre*feat + b
  mgemm_kernel<ST_COPY,EP_PM><<<BN_/64, 256, 0, stream>>>(fb, W_pre, b_pre, nullptr, nullptr, nullptr,
      nullptr, nullptr, nfb, nullptr, nullptr, 13);
  // v, Aq, Ak (one launch)
  qkv_kernel<<<dim3(BN_/64, 3), 256, 0, stream>>>(nfb, W_v, b_v, Wqa, bqa, Wka, bka, vb, Aqb, Akb);

  // pos GN stats -> folded params
  pos_stats_kernel<<<BNK_/256, 256, 0, stream>>>(pt4, idx, W_pos1, b_pos1, pos_sum, pos_ssq);
  posfin_kernel<<<1, 256, 0, stream>>>(pos_sum, pos_ssq, W_pos1, b_pos1, g_pos1, be_pos1, posPrm,
      1.0f/(float)(16.0*NK_));

  // G1: att1 = Wf*posn + bG1 + Aq[n] - Ak[j]  (+ stats)  -> bufA
  mgemm_kernel<ST_POS,EP_QKS><<<BNK_/64, 256, 0, stream>>>(nullptr, Wf, bG1, posPrm, pt4, idx,
      Aqb, Akb, bufA, att_sum, att_ssq, 17);
  attfin_kernel<<<1, 256, 0, stream>>>(att_sum, att_ssq, g_att1, be_att1, attPrm, 1.0f/(float)(16.0*NK_));

  // fused G2 + softmax + PV + residual
  fatt_kernel<<<BNK_/64, 256, 0, stream>>>(bufA, W_att2, b_att2, attPrm, idx, vb, nfb, outb);

  // post conv + stats (f32 col-major)
  mgemm_kernel<ST_COPY,EP_F32CM><<<BN_/64, 256, 0, stream>>>(outb, W_post, b_post, nullptr, nullptr, nullptr,
      nullptr, nullptr, out1, post_sum, post_ssq, 13);
  final_kernel<<<(B_*CN_)/256, 256, 0, stream>>>(out1, post_sum, post_ssq, g_post, be_post, (float*)d_out);
}